// Round 1
// baseline (805.079 us; speedup 1.0000x reference)
//
#include <hip/hip_runtime.h>
#include <math.h>

#define H 8
#define QB 16
#define NS 512
#define D 64
#define DIM 512
#define INNER 512
#define HQ (H*QB)        // 128
#define ROWS (QB*NS)     // 8192

// ---- workspace layout (float element offsets) ----
constexpr size_t F1      = (size_t)H*QB*NS*D;        // 4194304
constexpr size_t XN_OFF  = 0;                        // [3][8192][512]
constexpr size_t FQ_OFF  = (size_t)3*ROWS*DIM;       // 12582912
constexpr size_t FK_OFF  = FQ_OFF + F1;
constexpr size_t FV_OFF  = FK_OFF + F1;
constexpr size_t OH_OFF  = FV_OFF + F1;              // [8192][512]
constexpr size_t V0_OFF  = OH_OFF + (size_t)ROWS*INNER;  // 29360128
constexpr size_t NV      = (size_t)HQ*NS;            // 65536
constexpr size_t RI1_OFF  = V0_OFF;          // 1/(||fq||+1e-6)
constexpr size_t RMX1_OFF = V0_OFF + NV;     // 1/max(||fq||,1e-6)
constexpr size_t MQ_OFF   = V0_OFF + 2*NV;   // mean_d fq
constexpr size_t QDM_OFF  = V0_OFF + 3*NV;   // fq . mkbar
constexpr size_t RI2_OFF  = V0_OFF + 4*NV;
constexpr size_t RMX2_OFF = V0_OFF + 5*NV;
constexpr size_t SK_OFF   = V0_OFF + 6*NV;   // sum_d fk
constexpr size_t VM_OFF   = V0_OFF + 7*NV;
constexpr size_t MKB_OFF  = V0_OFF + 8*NV;   // [HQ][64]
constexpr size_t SMK_OFF  = MKB_OFF + (size_t)HQ*D;
constexpr size_t COEF_OFF = SMK_OFF + HQ;    // A'[8], B'[8], temp...
constexpr size_t DBL_OFF  = (COEF_OFF + 32 + 1) & ~(size_t)1;
// doubles at DBL_OFF: headsum[8][9], featd[8][128]
constexpr size_t NDBL = 72 + 1024;

#define CS2 ((1e-3f/512.f)/(8.f+1e-6f))

static __device__ __forceinline__ float wred64(float v){
  #pragma unroll
  for(int m=32; m>0; m>>=1) v += __shfl_xor(v, m, 64);
  return v;
}

// ---------------- LayerNorm: one wave per row ----------------
__global__ __launch_bounds__(64) void k_ln(const float* __restrict__ q,
    const float* __restrict__ k, const float* __restrict__ v,
    const float* __restrict__ g, const float* __restrict__ b,
    float* __restrict__ xn){
  int row = blockIdx.x; int t = threadIdx.x;
  const float* src = (row < 8192) ? q : ((row < 16384) ? k : v);
  int r = row & 8191;
  const float4* sp = (const float4*)(src + (size_t)r*512);
  float4 v1 = sp[t*2], v2 = sp[t*2+1];
  float s  = v1.x+v1.y+v1.z+v1.w + v2.x+v2.y+v2.z+v2.w;
  float ss = v1.x*v1.x+v1.y*v1.y+v1.z*v1.z+v1.w*v1.w
           + v2.x*v2.x+v2.y*v2.y+v2.z*v2.z+v2.w*v2.w;
  s = wred64(s); ss = wred64(ss);
  float mu = s*(1.f/512.f);
  float var = ss*(1.f/512.f) - mu*mu;
  float rstd = rsqrtf(var + 1e-5f);
  const float4* gp = (const float4*)g; const float4* bp = (const float4*)b;
  float4 g1 = gp[t*2], g2 = gp[t*2+1], b1 = bp[t*2], b2 = bp[t*2+1];
  float4 o1, o2;
  o1.x=(v1.x-mu)*rstd*g1.x+b1.x; o1.y=(v1.y-mu)*rstd*g1.y+b1.y;
  o1.z=(v1.z-mu)*rstd*g1.z+b1.z; o1.w=(v1.w-mu)*rstd*g1.w+b1.w;
  o2.x=(v2.x-mu)*rstd*g2.x+b2.x; o2.y=(v2.y-mu)*rstd*g2.y+b2.y;
  o2.z=(v2.z-mu)*rstd*g2.z+b2.z; o2.w=(v2.w-mu)*rstd*g2.w+b2.w;
  float4* op = (float4*)(xn + (size_t)row*512);
  op[t*2] = o1; op[t*2+1] = o2;
}

// ---------------- generic 128x128 fp32 GEMM, K=512 ----------------
// MODE 0: proj -> remap into f[h][q][n][d] (three tensors contiguous)
// MODE 1: out  -> C = A@B + bias, straight [M][512]
template<int MODE>
__global__ __launch_bounds__(256) void k_gemm(const float* __restrict__ A,
    const float* __restrict__ B, const float* __restrict__ bias,
    float* __restrict__ Cout){
  __shared__ __align__(16) float As[128][17];
  __shared__ __align__(16) float Bs[16][132];
  int t = threadIdx.x; int tr = t>>4, tc = t&15;
  int Rb = blockIdx.x*128, cb = blockIdx.y*128;
  float acc[8][8];
  #pragma unroll
  for(int i=0;i<8;i++)
    #pragma unroll
    for(int j=0;j<8;j++) acc[i][j]=0.f;
  for(int k0=0; k0<512; k0+=16){
    {
      int r = t>>1, kg = t&1;
      const float* ap = A + (size_t)(Rb+r)*512 + k0 + kg*8;
      float4 x0 = *(const float4*)ap; float4 x1 = *(const float4*)(ap+4);
      int kb = kg*8;
      As[r][kb+0]=x0.x; As[r][kb+1]=x0.y; As[r][kb+2]=x0.z; As[r][kb+3]=x0.w;
      As[r][kb+4]=x1.x; As[r][kb+5]=x1.y; As[r][kb+6]=x1.z; As[r][kb+7]=x1.w;
    }
    {
      int kk = t>>4, cg = t&15;
      const float* bp = B + (size_t)(k0+kk)*512 + cb + cg*8;
      float4 x0 = *(const float4*)bp; float4 x1 = *(const float4*)(bp+4);
      *(float4*)&Bs[kk][cg*8] = x0; *(float4*)&Bs[kk][cg*8+4] = x1;
    }
    __syncthreads();
    #pragma unroll
    for(int kk=0;kk<16;kk++){
      float ar[8], br[8];
      #pragma unroll
      for(int i=0;i<8;i++) ar[i] = As[tr*8+i][kk];
      float4 q0 = *(const float4*)&Bs[kk][tc*8];
      float4 q1 = *(const float4*)&Bs[kk][tc*8+4];
      br[0]=q0.x; br[1]=q0.y; br[2]=q0.z; br[3]=q0.w;
      br[4]=q1.x; br[5]=q1.y; br[6]=q1.z; br[7]=q1.w;
      #pragma unroll
      for(int i=0;i<8;i++)
        #pragma unroll
        for(int j=0;j<8;j++) acc[i][j] += ar[i]*br[j];
    }
    __syncthreads();
  }
  if(MODE==0){
    int c0 = cb + tc*8; int hh = c0>>6; int d0 = c0&63;
    #pragma unroll
    for(int i=0;i<8;i++){
      int R = Rb + tr*8 + i;
      int tsel = R>>13; int r = R&8191; int qq = r>>9; int n = r&511;
      float* dst = Cout + (size_t)tsel*F1 + ((size_t)(hh*QB+qq)*NS + n)*D + d0;
      float4 o0 = {acc[i][0],acc[i][1],acc[i][2],acc[i][3]};
      float4 o1 = {acc[i][4],acc[i][5],acc[i][6],acc[i][7]};
      *(float4*)dst = o0; *(float4*)(dst+4) = o1;
    }
  } else {
    int c0 = cb + tc*8;
    float4 bv0 = *(const float4*)&bias[c0];
    float4 bv1 = *(const float4*)&bias[c0+4];
    #pragma unroll
    for(int i=0;i<8;i++){
      int R = Rb + tr*8 + i;
      float* dst = Cout + (size_t)R*512 + c0;
      float4 o0 = {acc[i][0]+bv0.x, acc[i][1]+bv0.y, acc[i][2]+bv0.z, acc[i][3]+bv0.w};
      float4 o1 = {acc[i][4]+bv1.x, acc[i][5]+bv1.y, acc[i][6]+bv1.z, acc[i][7]+bv1.w};
      *(float4*)dst = o0; *(float4*)(dst+4) = o1;
    }
  }
}

// ---------------- per-(h,q) row/col stats ----------------
__global__ __launch_bounds__(256) void k_stats(const float* __restrict__ fqa,
    const float* __restrict__ fka,
    float* ri1, float* rmx1, float* mq, float* qdm,
    float* ri2, float* rmx2, float* sk, float* mkb, float* smk,
    double* featd){
  int hq = blockIdx.x; int h = hq>>4;
  const float* fq = fqa + (size_t)hq*NS*D;
  const float* fk = fka + (size_t)hq*NS*D;
  int t = threadIdx.x; int d = t&63; int ng = t>>6;
  __shared__ float cs_q[4][64], cs_k[4][64], mkb_s[64];
  float cq = 0.f, ck = 0.f;
  for(int n = ng; n < NS; n += 4){
    float vq = fq[(size_t)n*D + d];
    float s  = wred64(vq);
    float ss = wred64(vq*vq);
    if(d==0){
      float nrm = sqrtf(ss);
      ri1[hq*NS+n]  = 1.f/(nrm+1e-6f);
      rmx1[hq*NS+n] = 1.f/fmaxf(nrm,1e-6f);
      mq[hq*NS+n]   = s*(1.f/64.f);
    }
    cq += vq;
    float vk = fk[(size_t)n*D + d];
    float s2  = wred64(vk);
    float ss2 = wred64(vk*vk);
    if(d==0){
      float nrm = sqrtf(ss2);
      ri2[hq*NS+n]  = 1.f/(nrm+1e-6f);
      rmx2[hq*NS+n] = 1.f/fmaxf(nrm,1e-6f);
      sk[hq*NS+n]   = s2;
    }
    ck += vk;
  }
  cs_q[ng][d] = cq; cs_k[ng][d] = ck;
  __syncthreads();
  if(t < 64){
    float sq  = cs_q[0][t]+cs_q[1][t]+cs_q[2][t]+cs_q[3][t];
    float skk = cs_k[0][t]+cs_k[1][t]+cs_k[2][t]+cs_k[3][t];
    atomicAdd(&featd[h*128 + t], (double)sq);
    atomicAdd(&featd[h*128 + 64 + t], (double)skk);
    float mk = skk * (1.f/(float)NS);
    mkb[hq*D + t] = mk; mkb_s[t] = mk;
  }
  __syncthreads();
  if(t < 64){
    float s = wred64(mkb_s[t]);
    if(t==0) smk[hq] = s;
  }
  __syncthreads();
  float mkd = mkb_s[d];
  for(int n = ng; n < NS; n += 4){
    float vq = fq[(size_t)n*D + d];
    float s = wred64(vq*mkd);
    if(d==0) qdm[hq*NS+n] = s;
  }
}

// ---------------- component sums pass (recompute QK tiles) ----------------
__global__ __launch_bounds__(256) void k_comp(const float* __restrict__ fqa,
    const float* __restrict__ fka,
    const float* __restrict__ ri1, const float* __restrict__ rmx1,
    const float* __restrict__ mq, const float* __restrict__ qdm,
    const float* __restrict__ ri2, const float* __restrict__ rmx2,
    const float* __restrict__ sk, const float* __restrict__ smk,
    float* __restrict__ vm, double* headsum){
  int bx = blockIdx.x; int hq = bx>>3; int rt = bx&7; int h = hq>>4; int r0 = rt*64;
  const float* fq = fqa + (size_t)hq*NS*D + (size_t)r0*D;
  const float* fk = fka + (size_t)hq*NS*D;
  __shared__ __align__(16) float AsT[64][68];
  __shared__ __align__(16) float Bs[64][65];
  int t = threadIdx.x, tr = t>>4, tc = t&15;
  {
    int r = t>>2, dg = t&3;
    const float* ap = fq + (size_t)r*D + dg*16;
    #pragma unroll
    for(int ii=0; ii<4; ii++){
      float4 x = *(const float4*)(ap + ii*4);
      int dd = dg*16 + ii*4;
      AsT[dd+0][r]=x.x; AsT[dd+1][r]=x.y; AsT[dd+2][r]=x.z; AsT[dd+3][r]=x.w;
    }
  }
  float ri1r[4], rmx1r[4], mqr[4], qdmr[4];
  #pragma unroll
  for(int i=0;i<4;i++){
    int n = hq*NS + r0 + tr*4 + i;
    ri1r[i]=ri1[n]; rmx1r[i]=rmx1[n]; mqr[i]=mq[n]; qdmr[i]=qdm[n];
  }
  float smkv = smk[hq];
  float p0=0,p1=0,p2=0,p3=0,p4=0;
  float rm_m[4]={0,0,0,0}, rm_c[4]={0,0,0,0}, rm_v[4]={0,0,0,0};
  for(int ch=0; ch<8; ch++){
    __syncthreads();
    {
      int m = t>>2, dg = t&3;
      const float* bp = fk + (size_t)(ch*64+m)*D + dg*16;
      #pragma unroll
      for(int ii=0; ii<4; ii++){
        float4 x = *(const float4*)(bp + ii*4);
        int dd = dg*16+ii*4;
        Bs[m][dd+0]=x.x; Bs[m][dd+1]=x.y; Bs[m][dd+2]=x.z; Bs[m][dd+3]=x.w;
      }
    }
    __syncthreads();
    float dot[4][4] = {{0.f}};
    #pragma unroll 4
    for(int kk=0; kk<64; kk++){
      float4 a = *(const float4*)&AsT[kk][tr*4];
      float av[4] = {a.x,a.y,a.z,a.w};
      float bv[4];
      #pragma unroll
      for(int j=0;j<4;j++) bv[j] = Bs[tc*4+j][kk];
      #pragma unroll
      for(int i=0;i<4;i++)
        #pragma unroll
        for(int j=0;j<4;j++) dot[i][j] += av[i]*bv[j];
    }
    float ri2c[4], rmx2c[4], skc[4];
    #pragma unroll
    for(int j=0;j<4;j++){
      int m = hq*NS + ch*64 + tc*4 + j;
      ri2c[j]=ri2[m]; rmx2c[j]=rmx2[m]; skc[j]=sk[m];
    }
    #pragma unroll
    for(int i=0;i<4;i++){
      #pragma unroll
      for(int j=0;j<4;j++){
        float dv = dot[i][j];
        float cosv = fminf(fmaxf(dv*ri1r[i]*ri2c[j], -0.9f), 0.9f);
        float inner = dv - qdmr[i] - mqr[i]*skc[j] + mqr[i]*smkv;
        float covv = fminf(fmaxf(CS2*inner, -10.f), 10.f);
        float csv = fminf(fmaxf(dv*rmx1r[i]*rmx2c[j], -0.9f), 0.9f);
        float marg = fminf(fmaxf(0.01f - csv, 0.f), 5.f);
        p0 += cosv; p1 += cosv*cosv; p2 += covv; p3 += covv*covv; p4 += cosv*covv;
        rm_m[i]+=marg; rm_c[i]+=cosv; rm_v[i]+=covv;
      }
    }
  }
  #pragma unroll
  for(int i=0;i<4;i++){
    #pragma unroll
    for(int off=8; off>=1; off>>=1){
      rm_m[i]+=__shfl_xor(rm_m[i],off,64);
      rm_c[i]+=__shfl_xor(rm_c[i],off,64);
      rm_v[i]+=__shfl_xor(rm_v[i],off,64);
    }
  }
  float q0=0,q1=0,q2=0,q3=0;
  if(tc==0){
    #pragma unroll
    for(int i=0;i<4;i++){
      float vmv = rm_m[i]*(1.f/512.f);
      vm[hq*NS + r0 + tr*4 + i] = vmv;
      q0+=vmv; q1+=vmv*vmv; q2+=vmv*rm_c[i]; q3+=vmv*rm_v[i];
    }
  }
  float all9[9] = {p0,p1,p2,p3,p4,q0,q1,q2,q3};
  __shared__ float redl[4][9];
  int lane = t&63, wv = t>>6;
  #pragma unroll
  for(int j=0;j<9;j++){
    float vv = wred64(all9[j]);
    if(lane==0) redl[wv][j]=vv;
  }
  __syncthreads();
  if(t<9){
    double s = (double)redl[0][t]+(double)redl[1][t]+(double)redl[2][t]+(double)redl[3][t];
    atomicAdd(&headsum[h*9+t], s);
  }
}

// ---------------- finalize: stds, MLP weights, temperature, coefficients ----------------
__global__ __launch_bounds__(256) void k_finalize(const double* headsum, const double* featd,
    const float* __restrict__ w1, const float* __restrict__ b1,
    const float* __restrict__ lng, const float* __restrict__ lnb,
    const float* __restrict__ w2, const float* __restrict__ b2,
    const float* __restrict__ w3, const float* __restrict__ b3,
    const float* __restrict__ wtemp, float* coef){
  __shared__ float feat[128], x1[128], x2[64];
  __shared__ float wh[8][3];
  __shared__ float mrs[2];
  int t = threadIdx.x;
  for(int h=0; h<8; h++){
    if(t<128) feat[t] = (float)(featd[h*128+t] * (1.0/8192.0));
    __syncthreads();
    if(t<128){
      float a=0.f;
      for(int i=0;i<128;i++) a += feat[i]*w1[(size_t)i*128+t];
      x1[t] = a + b1[t];
    }
    __syncthreads();
    if(t==0){
      float s=0.f, ss=0.f;
      for(int i=0;i<128;i++){ s+=x1[i]; ss+=x1[i]*x1[i]; }
      float mu=s*(1.f/128.f); float var=ss*(1.f/128.f)-mu*mu;
      mrs[0]=mu; mrs[1]=rsqrtf(var+1e-5f);
    }
    __syncthreads();
    if(t<128){
      float vv=(x1[t]-mrs[0])*mrs[1]*lng[t]+lnb[t];
      x1[t]=fmaxf(vv,0.f);
    }
    __syncthreads();
    if(t<64){
      float s=0.f;
      for(int i=0;i<128;i++) s += x1[i]*w2[(size_t)i*64+t];
      x2[t]=fmaxf(s+b2[t],0.f);
    }
    __syncthreads();
    if(t==0){
      float o[3];
      for(int j=0;j<3;j++){ float s=0.f; for(int i=0;i<64;i++) s+=x2[i]*w3[i*3+j]; o[j]=s+b3[j]; }
      float mx=fmaxf(o[0],fmaxf(o[1],o[2]));
      float e0=expf(o[0]-mx), e1=expf(o[1]-mx), e2=expf(o[2]-mx), se=e0+e1+e2;
      float l0=e0/se, l1=e1/se, l2=e2/se;
      float wt=fminf(fmaxf(wtemp[0],0.1f),2.0f);
      l0/=wt; l1/=wt; l2/=wt;
      mx=fmaxf(l0,fmaxf(l1,l2));
      e0=expf(l0-mx); e1=expf(l1-mx); e2=expf(l2-mx); se=e0+e1+e2;
      float u0=fminf(fmaxf(e0/se,0.05f),0.8f);
      float u1=fminf(fmaxf(e1/se,0.05f),0.8f);
      float u2=fminf(fmaxf(e2/se,0.05f),0.8f);
      float su=u0+u1+u2;
      wh[h][0]=u0/su; wh[h][1]=u1/su; wh[h][2]=u2/su;
    }
    __syncthreads();
  }
  if(t==0){
    const double N = 33554432.0;
    double gs[9];
    for(int j=0;j<9;j++){ double s=0; for(int hh=0;hh<8;hh++) s+=headsum[hh*9+j]; gs[j]=s; }
    auto sd = [&](double s, double ss)->double{
      double v=(ss - s*s/N)/(N-1.0); return v>0.0 ? sqrt(v) : 0.0;
    };
    double std_cos = sd(gs[0],gs[1]);
    double std_cov = sd(gs[2],gs[3]);
    double std_vm  = sd(512.0*gs[5], 512.0*gs[6]);
    double sdot=0.0, sdot2=0.0;
    double Af[8], Bf[8];
    for(int hh=0;hh<8;hh++){
      const double* hs = headsum + hh*9;
      double A = (double)wh[hh][0]/(std_cos+1e-6);
      double B = (double)wh[hh][1]/(std_cov+1e-6)*0.5;
      double C = (double)wh[hh][2]/(std_vm +1e-6)*0.5;
      sdot  += A*hs[0] + B*hs[2] + C*512.0*hs[5];
      sdot2 += A*A*hs[1] + B*B*hs[3] + C*C*512.0*hs[6]
             + 2.0*A*B*hs[4] + 2.0*A*C*hs[7] + 2.0*B*C*hs[8];
      Af[hh]=A; Bf[hh]=B;
    }
    double dstd = sd(sdot, sdot2);
    double temp = dstd < 1e-4 ? 0.1 : (dstd < 0.01 ? 0.3 : 0.5 + dstd);
    temp = fmin(fmax(temp, 0.1), 3.0);
    for(int hh=0;hh<8;hh++){
      coef[hh]   = (float)(Af[hh]/temp);
      coef[8+hh] = (float)(Bf[hh]/temp);
    }
    coef[16] = (float)temp;
  }
}

// ---------------- flash softmax + PV ----------------
__global__ __launch_bounds__(256) void k_flash(const float* __restrict__ fqa,
    const float* __restrict__ fka, const float* __restrict__ fva,
    const float* __restrict__ ri1, const float* __restrict__ mq,
    const float* __restrict__ qdm, const float* __restrict__ ri2,
    const float* __restrict__ sk, const float* __restrict__ smk,
    const float* __restrict__ coef, float* __restrict__ oh){
  int bx=blockIdx.x; int hq=bx>>3; int rt=bx&7; int h=hq>>4; int qq=hq&15; int r0=rt*64;
  const float* fq = fqa + (size_t)hq*NS*D + (size_t)r0*D;
  const float* fk = fka + (size_t)hq*NS*D;
  const float* fv = fva + (size_t)hq*NS*D;
  __shared__ __align__(16) float AsT[64][68];
  __shared__ __align__(16) float Ks[64][65];
  __shared__ __align__(16) float Vs[64][65];
  __shared__ __align__(16) float Ps[64][65];
  int t=threadIdx.x, tr=t>>4, tc=t&15;
  {
    int r = t>>2, dg = t&3;
    const float* ap = fq + (size_t)r*D + dg*16;
    #pragma unroll
    for(int ii=0; ii<4; ii++){
      float4 x = *(const float4*)(ap + ii*4);
      int dd = dg*16 + ii*4;
      AsT[dd+0][r]=x.x; AsT[dd+1][r]=x.y; AsT[dd+2][r]=x.z; AsT[dd+3][r]=x.w;
    }
  }
  float ri1r[4], mqr[4], qdmr[4];
  #pragma unroll
  for(int i=0;i<4;i++){
    int n = hq*NS + r0 + tr*4 + i;
    ri1r[i]=ri1[n]; mqr[i]=mq[n]; qdmr[i]=qdm[n];
  }
  float smkv = smk[hq]; float Ah = coef[h], Bh = coef[8+h];
  float acc[4][4]={{0.f}};
  float mrow[4]={-1e30f,-1e30f,-1e30f,-1e30f};
  float lrow[4]={0.f,0.f,0.f,0.f};
  for(int ch=0; ch<8; ch++){
    __syncthreads();
    {
      int m = t>>2, dg = t&3;
      const float* kp = fk + (size_t)(ch*64+m)*D + dg*16;
      const float* vp = fv + (size_t)(ch*64+m)*D + dg*16;
      #pragma unroll
      for(int ii=0; ii<4; ii++){
        float4 x = *(const float4*)(kp + ii*4);
        float4 y = *(const float4*)(vp + ii*4);
        int dd = dg*16+ii*4;
        Ks[m][dd+0]=x.x; Ks[m][dd+1]=x.y; Ks[m][dd+2]=x.z; Ks[m][dd+3]=x.w;
        Vs[m][dd+0]=y.x; Vs[m][dd+1]=y.y; Vs[m][dd+2]=y.z; Vs[m][dd+3]=y.w;
      }
    }
    __syncthreads();
    float s[4][4] = {{0.f}};
    #pragma unroll 4
    for(int kk=0; kk<64; kk++){
      float4 a = *(const float4*)&AsT[kk][tr*4];
      float av[4] = {a.x,a.y,a.z,a.w};
      float bv[4];
      #pragma unroll
      for(int j=0;j<4;j++) bv[j] = Ks[tc*4+j][kk];
      #pragma unroll
      for(int i=0;i<4;i++)
        #pragma unroll
        for(int j=0;j<4;j++) s[i][j] += av[i]*bv[j];
    }
    float ri2c[4], skc[4];
    #pragma unroll
    for(int j=0;j<4;j++){
      int m = hq*NS + ch*64 + tc*4 + j;
      ri2c[j]=ri2[m]; skc[j]=sk[m];
    }
    #pragma unroll
    for(int i=0;i<4;i++){
      #pragma unroll
      for(int j=0;j<4;j++){
        float dv = s[i][j];
        float cosv = fminf(fmaxf(dv*ri1r[i]*ri2c[j], -0.9f), 0.9f);
        float inner = dv - qdmr[i] - mqr[i]*skc[j] + mqr[i]*smkv;
        float covv = fminf(fmaxf(CS2*inner, -10.f), 10.f);
        s[i][j] = Ah*cosv + Bh*covv;
      }
    }
    #pragma unroll
    for(int i=0;i<4;i++){
      float cm = fmaxf(fmaxf(s[i][0],s[i][1]),fmaxf(s[i][2],s[i][3]));
      #pragma unroll
      for(int off=8; off>=1; off>>=1) cm = fmaxf(cm, __shfl_xor(cm,off,64));
      float mnew = fmaxf(mrow[i], cm);
      float sc = expf(mrow[i]-mnew);
      float ps = 0.f;
      #pragma unroll
      for(int j=0;j<4;j++){
        float pe = expf(s[i][j]-mnew);
        Ps[tr*4+i][tc*4+j] = pe;
        ps += pe;
      }
      #pragma unroll
      for(int off=8; off>=1; off>>=1) ps += __shfl_xor(ps,off,64);
      lrow[i] = lrow[i]*sc + ps;
      mrow[i] = mnew;
      #pragma unroll
      for(int j=0;j<4;j++) acc[i][j] *= sc;
    }
    __syncthreads();
    #pragma unroll 4
    for(int mm=0; mm<64; mm++){
      float pvv[4], vvv[4];
      #pragma unroll
      for(int i=0;i<4;i++) pvv[i] = Ps[tr*4+i][mm];
      #pragma unroll
      for(int j=0;j<4;j++) vvv[j] = Vs[mm][tc*4+j];
      #pragma unroll
      for(int i=0;i<4;i++)
        #pragma unroll
        for(int j=0;j<4;j++) acc[i][j] += pvv[i]*vvv[j];
    }
    __syncthreads();
  }
  #pragma unroll
  for(int i=0;i<4;i++){
    float inv = 1.f/lrow[i];
    float4 o = {acc[i][0]*inv, acc[i][1]*inv, acc[i][2]*inv, acc[i][3]*inv};
    *(float4*)&oh[(size_t)(qq*NS + r0 + tr*4 + i)*INNER + h*64 + tc*4] = o;
  }
}

extern "C" void kernel_launch(void* const* d_in, const int* in_sizes, int n_in,
                              void* d_out, int out_size, void* d_ws, size_t ws_size,
                              hipStream_t stream){
  const float* q    = (const float*)d_in[0];
  const float* k    = (const float*)d_in[1];
  const float* v    = (const float*)d_in[2];
  const float* ln1g = (const float*)d_in[3];
  const float* ln1b = (const float*)d_in[4];
  const float* Win  = (const float*)d_in[5];
  const float* w1   = (const float*)d_in[6];
  const float* b1   = (const float*)d_in[7];
  const float* lng  = (const float*)d_in[8];
  const float* lnb  = (const float*)d_in[9];
  const float* w2   = (const float*)d_in[10];
  const float* b2   = (const float*)d_in[11];
  const float* w3   = (const float*)d_in[12];
  const float* b3   = (const float*)d_in[13];
  const float* wtemp= (const float*)d_in[14];
  const float* Wout = (const float*)d_in[15];
  const float* bout = (const float*)d_in[16];

  float* w    = (float*)d_ws;
  float* xn   = w + XN_OFF;
  float* fq   = w + FQ_OFF;
  float* fk   = w + FK_OFF;
  float* fv   = w + FV_OFF;
  float* oh   = w + OH_OFF;
  float* ri1  = w + RI1_OFF;
  float* rmx1 = w + RMX1_OFF;
  float* mq_  = w + MQ_OFF;
  float* qdm  = w + QDM_OFF;
  float* ri2  = w + RI2_OFF;
  float* rmx2 = w + RMX2_OFF;
  float* sk_  = w + SK_OFF;
  float* vm_  = w + VM_OFF;
  float* mkb  = w + MKB_OFF;
  float* smk_ = w + SMK_OFF;
  float* coef = w + COEF_OFF;
  double* dbl = (double*)(w + DBL_OFF);
  double* headsum = dbl;
  double* featd   = dbl + 72;

  hipMemsetAsync(dbl, 0, NDBL*sizeof(double), stream);
  k_ln<<<24576, 64, 0, stream>>>(q, k, v, ln1g, ln1b, xn);
  k_gemm<0><<<dim3(192,4), 256, 0, stream>>>(xn, Win, nullptr, fq);
  k_stats<<<128, 256, 0, stream>>>(fq, fk, ri1, rmx1, mq_, qdm, ri2, rmx2, sk_, mkb, smk_, featd);
  k_comp<<<1024, 256, 0, stream>>>(fq, fk, ri1, rmx1, mq_, qdm, ri2, rmx2, sk_, smk_, vm_, headsum);
  k_finalize<<<1, 256, 0, stream>>>(headsum, featd, w1, b1, lng, lnb, w2, b2, w3, b3, wtemp, coef);
  k_flash<<<1024, 256, 0, stream>>>(fq, fk, fv, ri1, mq_, qdm, ri2, sk_, smk_, coef, oh);
  k_gemm<1><<<dim3(64,4), 256, 0, stream>>>(oh, Wout, bout, (float*)d_out);
}

// Round 2
// 433.056 us; speedup vs baseline: 1.8591x; 1.8591x over previous
//
#include <hip/hip_runtime.h>
#include <math.h>

#define H 8
#define NS 512
#define D 64

typedef __bf16 bf16x8 __attribute__((ext_vector_type(8)));
typedef float f32x4 __attribute__((ext_vector_type(4)));
typedef short s16x8 __attribute__((ext_vector_type(8)));
typedef short s16x4 __attribute__((ext_vector_type(4)));

#define CS2 ((1e-3f/512.f)/(8.f+1e-6f))

static __device__ __forceinline__ f32x4 mfma16(bf16x8 a, bf16x8 b, f32x4 c){
  return __builtin_amdgcn_mfma_f32_16x16x32_bf16(a,b,c,0,0,0);
}
static __device__ __forceinline__ float b2f(unsigned short s){
  union { unsigned u; float f; } v; v.u = ((unsigned)s)<<16; return v.f;
}
static __device__ __forceinline__ unsigned short f2b(float f){
  union { float f; unsigned u; } v; v.f = f;
  unsigned r = v.u + 0x7FFFu + ((v.u>>16)&1u);
  return (unsigned short)(r>>16);
}
static __device__ __forceinline__ float wred64(float v){
  #pragma unroll
  for(int m=32; m>0; m>>=1) v += __shfl_xor(v, m, 64);
  return v;
}

// ---- workspace layout (float element offsets) ----
constexpr size_t OFF_XNB = 0;                       // 24576x512 bf16
constexpr size_t OFF_FQB = 6291456;                 // 8192x512 bf16
constexpr size_t OFF_FKB = 8388608;
constexpr size_t OFF_FVB = 10485760;
constexpr size_t OFF_FVT = 12582912;                // [128][64][512] bf16
constexpr size_t OFF_WT  = 14680064;                // 512x512 bf16 (WinT)
constexpr size_t OFF_OH  = 14811136;                // 8192x512 f32
constexpr size_t OFF_ARR = 19005440;                // 9 arrays x 65536 f32
constexpr size_t OFF_MKB = OFF_ARR + 9*65536;
constexpr size_t OFF_SMK = OFF_MKB + 8192;
constexpr size_t OFF_COEF= OFF_SMK + 128;
constexpr size_t OFF_DBL = OFF_COEF + 32;           // even -> 8B aligned
constexpr size_t NDBL    = 72 + 1024;               // headsum[8][9], featd[8][128]

// ---------------- W_in transpose -> bf16 [n][k] ----------------
__global__ __launch_bounds__(256) void k_tw(const float* __restrict__ W, unsigned short* __restrict__ WT){
  int bx = blockIdx.x; int kt = bx>>3, nt = bx&7;
  __shared__ float tile[64][65];
  int t = threadIdx.x;
  #pragma unroll
  for(int i=0;i<4;i++){
    int row = (t>>4) + i*16; int col = (t&15)*4;
    float4 v = *(const float4*)(W + (size_t)(kt*64+row)*512 + nt*64 + col);
    tile[row][col]=v.x; tile[row][col+1]=v.y; tile[row][col+2]=v.z; tile[row][col+3]=v.w;
  }
  __syncthreads();
  #pragma unroll
  for(int i=0;i<4;i++){
    int n = (t>>4) + i*16; int ck = (t&15)*4;
    s16x4 o;
    #pragma unroll
    for(int j=0;j<4;j++) o[j] = (short)f2b(tile[ck+j][n]);
    *(s16x4*)(WT + (size_t)(nt*64+n)*512 + kt*64 + ck) = o;
  }
}

// ---------------- LayerNorm -> bf16 ----------------
__global__ __launch_bounds__(64) void k_ln(const float* __restrict__ q,
    const float* __restrict__ k, const float* __restrict__ v,
    const float* __restrict__ g, const float* __restrict__ b,
    unsigned short* __restrict__ xnb){
  int row = blockIdx.x; int t = threadIdx.x;
  const float* src = (row < 8192) ? q : ((row < 16384) ? k : v);
  int r = row & 8191;
  const float4* sp = (const float4*)(src + (size_t)r*512);
  float4 v1 = sp[t*2], v2 = sp[t*2+1];
  float s  = v1.x+v1.y+v1.z+v1.w + v2.x+v2.y+v2.z+v2.w;
  float ss = v1.x*v1.x+v1.y*v1.y+v1.z*v1.z+v1.w*v1.w
           + v2.x*v2.x+v2.y*v2.y+v2.z*v2.z+v2.w*v2.w;
  s = wred64(s); ss = wred64(ss);
  float mu = s*(1.f/512.f);
  float var = ss*(1.f/512.f) - mu*mu;
  float rstd = rsqrtf(var + 1e-5f);
  const float4* gp = (const float4*)g; const float4* bp = (const float4*)b;
  float4 g1 = gp[t*2], g2 = gp[t*2+1], b1 = bp[t*2], b2 = bp[t*2+1];
  s16x8 o;
  o[0]=(short)f2b((v1.x-mu)*rstd*g1.x+b1.x); o[1]=(short)f2b((v1.y-mu)*rstd*g1.y+b1.y);
  o[2]=(short)f2b((v1.z-mu)*rstd*g1.z+b1.z); o[3]=(short)f2b((v1.w-mu)*rstd*g1.w+b1.w);
  o[4]=(short)f2b((v2.x-mu)*rstd*g2.x+b2.x); o[5]=(short)f2b((v2.y-mu)*rstd*g2.y+b2.y);
  o[6]=(short)f2b((v2.z-mu)*rstd*g2.z+b2.z); o[7]=(short)f2b((v2.w-mu)*rstd*g2.w+b2.w);
  *(s16x8*)(xnb + (size_t)row*512 + t*8) = o;
}

// ---------------- proj GEMM bf16 MFMA: [24576][512] @ WinT -> fq/fk/fv bf16 ----------------
__global__ __launch_bounds__(256) void k_mm1(const unsigned short* __restrict__ xnb,
    const unsigned short* __restrict__ WT,
    unsigned short* __restrict__ fqb, unsigned short* __restrict__ fkb,
    unsigned short* __restrict__ fvb){
  __shared__ __align__(16) unsigned short As[128*64];
  __shared__ __align__(16) unsigned short Bs[128*64];
  int t = threadIdx.x; int w = t>>6; int l = t&63; int g = l>>4, lc = l&15;
  int Rb = blockIdx.x*128, cb = blockIdx.y*128;
  int wr = (w>>1)*64, wc = (w&1)*64;
  f32x4 acc[4][4];
  #pragma unroll
  for(int i=0;i<4;i++)
    #pragma unroll
    for(int j=0;j<4;j++) acc[i][j] = (f32x4){0.f,0.f,0.f,0.f};
  for(int k0=0; k0<512; k0+=64){
    __syncthreads();
    #pragma unroll
    for(int i=0;i<4;i++){
      int c = t + i*256; int row = c>>3, k8 = c&7;
      s16x8 va = *(const s16x8*)(xnb + (size_t)(Rb+row)*512 + k0 + k8*8);
      *(s16x8*)((char*)As + row*128 + ((k8*16) ^ ((row&7)<<4))) = va;
      s16x8 vb = *(const s16x8*)(WT + (size_t)(cb+row)*512 + k0 + k8*8);
      *(s16x8*)((char*)Bs + row*128 + ((k8*16) ^ ((row&7)<<4))) = vb;
    }
    __syncthreads();
    #pragma unroll
    for(int ks=0; ks<2; ks++){
      bf16x8 ar[4], br[4];
      #pragma unroll
      for(int rt=0; rt<4; rt++){
        int row = wr + rt*16 + lc;
        ar[rt] = *(const bf16x8*)((const char*)As + row*128 + (((ks*4+g)*16) ^ ((row&7)<<4)));
      }
      #pragma unroll
      for(int ct=0; ct<4; ct++){
        int row = wc + ct*16 + lc;
        br[ct] = *(const bf16x8*)((const char*)Bs + row*128 + (((ks*4+g)*16) ^ ((row&7)<<4)));
      }
      #pragma unroll
      for(int rt=0; rt<4; rt++)
        #pragma unroll
        for(int ct=0; ct<4; ct++)
          acc[rt][ct] = mfma16(ar[rt], br[ct], acc[rt][ct]);
    }
  }
  #pragma unroll
  for(int rt=0; rt<4; rt++){
    #pragma unroll
    for(int r=0; r<4; r++){
      int R = Rb + wr + rt*16 + g*4 + r;
      int tsel = R>>13; int rr = R&8191;
      unsigned short* dst = (tsel==0)?fqb:((tsel==1)?fkb:fvb);
      #pragma unroll
      for(int ct=0; ct<4; ct++){
        int c = cb + wc + ct*16 + lc;
        dst[(size_t)rr*512 + c] = f2b(acc[rt][ct][r]);
      }
    }
  }
}

// ---------------- per-(h,q) row/col stats (bf16 reads) ----------------
__global__ __launch_bounds__(256) void k_stats(const unsigned short* __restrict__ fqb,
    const unsigned short* __restrict__ fkb,
    float* ri1, float* rmx1, float* mq, float* qdm,
    float* ri2, float* rmx2, float* sk, float* mkb, float* smk,
    double* featd){
  int hq = blockIdx.x; int h = hq>>4, q = hq&15;
  int t = threadIdx.x; int d = t&63; int ng = t>>6;
  __shared__ float cs_q[4][64], cs_k[4][64], mkb_s[64];
  float cq = 0.f, ck = 0.f;
  for(int n = ng; n < NS; n += 4){
    size_t base = (size_t)(q*512+n)*512 + h*64 + d;
    float vq = b2f(fqb[base]);
    float s  = wred64(vq);
    float ss = wred64(vq*vq);
    if(d==0){
      float nrm = sqrtf(ss);
      ri1[hq*NS+n]  = 1.f/(nrm+1e-6f);
      rmx1[hq*NS+n] = 1.f/fmaxf(nrm,1e-6f);
      mq[hq*NS+n]   = s*(1.f/64.f);
    }
    cq += vq;
    float vk = b2f(fkb[base]);
    float s2  = wred64(vk);
    float ss2 = wred64(vk*vk);
    if(d==0){
      float nrm = sqrtf(ss2);
      ri2[hq*NS+n]  = 1.f/(nrm+1e-6f);
      rmx2[hq*NS+n] = 1.f/fmaxf(nrm,1e-6f);
      sk[hq*NS+n]   = s2;
    }
    ck += vk;
  }
  cs_q[ng][d] = cq; cs_k[ng][d] = ck;
  __syncthreads();
  if(t < 64){
    float sq  = cs_q[0][t]+cs_q[1][t]+cs_q[2][t]+cs_q[3][t];
    float skk = cs_k[0][t]+cs_k[1][t]+cs_k[2][t]+cs_k[3][t];
    atomicAdd(&featd[h*128 + t], (double)sq);
    atomicAdd(&featd[h*128 + 64 + t], (double)skk);
    float mk = skk * (1.f/(float)NS);
    mkb[hq*D + t] = mk; mkb_s[t] = mk;
  }
  __syncthreads();
  if(t < 64){
    float s = wred64(mkb_s[t]);
    if(t==0) smk[hq] = s;
  }
  __syncthreads();
  float mkd = mkb_s[d];
  for(int n = ng; n < NS; n += 4){
    float vq = b2f(fqb[(size_t)(q*512+n)*512 + h*64 + d]);
    float s = wred64(vq*mkd);
    if(d==0) qdm[hq*NS+n] = s;
  }
}

// ---------------- fv transpose -> fvT[hq][d][n] bf16 ----------------
__global__ __launch_bounds__(256) void k_vt(const unsigned short* __restrict__ fvb,
    unsigned short* __restrict__ fvT){
  int bx = blockIdx.x; int hq = bx>>2, nc = bx&3;
  int h = hq>>4, q = hq&15; int n0 = nc*128;
  __shared__ float tile[128][65];
  int t = threadIdx.x;
  #pragma unroll
  for(int i=0;i<4;i++){
    int c = t + i*256; int row = c>>3, k8 = c&7;
    s16x8 v = *(const s16x8*)(fvb + (size_t)(q*512 + n0 + row)*512 + h*64 + k8*8);
    #pragma unroll
    for(int j=0;j<8;j++) tile[row][k8*8+j] = b2f((unsigned short)v[j]);
  }
  __syncthreads();
  #pragma unroll
  for(int i=0;i<4;i++){
    int c = t + i*256; int d = c>>4, n8 = c&15;
    s16x8 o;
    #pragma unroll
    for(int j=0;j<8;j++) o[j] = (short)f2b(tile[n8*8+j][d]);
    *(s16x8*)(fvT + (size_t)(hq*64 + d)*512 + n0 + n8*8) = o;
  }
}

// ---------------- component sums pass (MFMA QK) ----------------
__global__ __launch_bounds__(256) void k_comp(const unsigned short* __restrict__ fqb,
    const unsigned short* __restrict__ fkb,
    const float* __restrict__ ri1, const float* __restrict__ rmx1,
    const float* __restrict__ mq, const float* __restrict__ qdm,
    const float* __restrict__ ri2, const float* __restrict__ rmx2,
    const float* __restrict__ sk, const float* __restrict__ smk,
    float* __restrict__ mxcg, float* __restrict__ mxvg, double* headsum){
  int bx = blockIdx.x; int hq = bx>>3; int rt = bx&7;
  int h = hq>>4, q = hq&15; int n0 = rt*64;
  __shared__ __align__(16) unsigned short Qs[64*64];
  __shared__ __align__(16) unsigned short Ks[128*64];
  __shared__ float ri2f[512], rmx2f[512], skf[512];
  __shared__ float red[4][9];
  int t = threadIdx.x; int w = t>>6; int l = t&63; int g = l>>4, lc = l&15;
  for(int i=t; i<512; i+=256){
    ri2f[i]=ri2[hq*NS+i]; rmx2f[i]=rmx2[hq*NS+i]; skf[i]=sk[hq*NS+i];
  }
  #pragma unroll
  for(int i=0;i<2;i++){
    int c = t + i*256; int row = c>>3, k8 = c&7;
    s16x8 v = *(const s16x8*)(fqb + (size_t)(q*512 + n0 + row)*512 + h*64 + k8*8);
    *(s16x8*)((char*)Qs + row*128 + ((k8*16) ^ ((row&7)<<4))) = v;
  }
  float ri1r[4], rmx1r[4], mqr[4], qdmr[4];
  #pragma unroll
  for(int r=0;r<4;r++){
    int n = hq*NS + n0 + w*16 + g*4 + r;
    ri1r[r]=ri1[n]; rmx1r[r]=rmx1[n]; mqr[r]=mq[n]; qdmr[r]=qdm[n];
  }
  float smkv = smk[hq];
  __syncthreads();
  bf16x8 aq[2];
  #pragma unroll
  for(int ks=0;ks<2;ks++){
    int row = 16*w + lc;
    aq[ks] = *(const bf16x8*)((const char*)Qs + row*128 + (((ks*4+g)*16) ^ ((row&7)<<4)));
  }
  float p0=0,p1=0,p2=0,p3=0,p4=0;
  float rm_m[4]={0,0,0,0}, rm_c[4]={0,0,0,0}, rm_v[4]={0,0,0,0};
  float mxc[4]={-1e30f,-1e30f,-1e30f,-1e30f}, mxv[4]={-1e30f,-1e30f,-1e30f,-1e30f};
  for(int mc=0; mc<4; mc++){
    __syncthreads();
    #pragma unroll
    for(int i=0;i<4;i++){
      int c = t + i*256; int row = c>>3, k8 = c&7;
      s16x8 v = *(const s16x8*)(fkb + (size_t)(q*512 + mc*128 + row)*512 + h*64 + k8*8);
      *(s16x8*)((char*)Ks + row*128 + ((k8*16) ^ ((row&7)<<4))) = v;
    }
    __syncthreads();
    #pragma unroll 2
    for(int mt=0; mt<8; mt++){
      f32x4 dacc = (f32x4){0.f,0.f,0.f,0.f};
      #pragma unroll
      for(int ks=0;ks<2;ks++){
        int row = mt*16 + lc;
        bf16x8 bk = *(const bf16x8*)((const char*)Ks + row*128 + (((ks*4+g)*16) ^ ((row&7)<<4)));
        dacc = mfma16(aq[ks], bk, dacc);
      }
      int m = mc*128 + mt*16 + lc;
      float r2 = ri2f[m], rx2 = rmx2f[m], skc = skf[m];
      #pragma unroll
      for(int r=0;r<4;r++){
        float dv = dacc[r];
        float cosv = fminf(fmaxf(dv*ri1r[r]*r2, -0.9f), 0.9f);
        float inner = dv - qdmr[r] - mqr[r]*skc + mqr[r]*smkv;
        float covv = fminf(fmaxf(CS2*inner, -10.f), 10.f);
        float csv = fminf(fmaxf(dv*rmx1r[r]*rx2, -0.9f), 0.9f);
        float marg = fminf(fmaxf(0.01f - csv, 0.f), 5.f);
        p0 += cosv; p1 += cosv*cosv; p2 += covv; p3 += covv*covv; p4 += cosv*covv;
        rm_m[r]+=marg; rm_c[r]+=cosv; rm_v[r]+=covv;
        mxc[r]=fmaxf(mxc[r],cosv); mxv[r]=fmaxf(mxv[r],covv);
      }
    }
  }
  #pragma unroll
  for(int off=1; off<16; off<<=1){
    #pragma unroll
    for(int r=0;r<4;r++){
      rm_m[r]+=__shfl_xor(rm_m[r],off,64);
      rm_c[r]+=__shfl_xor(rm_c[r],off,64);
      rm_v[r]+=__shfl_xor(rm_v[r],off,64);
      mxc[r]=fmaxf(mxc[r],__shfl_xor(mxc[r],off,64));
      mxv[r]=fmaxf(mxv[r],__shfl_xor(mxv[r],off,64));
    }
  }
  float q0=0,q1=0,q2=0,q3=0;
  if(lc==0){
    #pragma unroll
    for(int r=0;r<4;r++){
      float vmv = rm_m[r]*(1.f/512.f);
      q0+=vmv; q1+=vmv*vmv; q2+=vmv*rm_c[r]; q3+=vmv*rm_v[r];
      int n = n0 + w*16 + g*4 + r;
      mxcg[hq*NS+n]=mxc[r]; mxvg[hq*NS+n]=mxv[r];
    }
  }
  float all9[9] = {p0,p1,p2,p3,p4,q0,q1,q2,q3};
  #pragma unroll
  for(int j=0;j<9;j++){
    float vv = wred64(all9[j]);
    if(l==0) red[w][j]=vv;
  }
  __syncthreads();
  if(t<9){
    double s = (double)red[0][t]+(double)red[1][t]+(double)red[2][t]+(double)red[3][t];
    atomicAdd(&headsum[h*9+t], s);
  }
}

// ---------------- finalize ----------------
__global__ __launch_bounds__(256) void k_finalize(const double* headsum, const double* featd,
    const float* __restrict__ w1, const float* __restrict__ b1,
    const float* __restrict__ lng, const float* __restrict__ lnb,
    const float* __restrict__ w2, const float* __restrict__ b2,
    const float* __restrict__ w3, const float* __restrict__ b3,
    const float* __restrict__ wtemp, float* coef){
  __shared__ float feat[128], x1[128], x2[64];
  __shared__ float wh[8][3];
  __shared__ float mrs[2];
  int t = threadIdx.x;
  for(int h=0; h<8; h++){
    if(t<128) feat[t] = (float)(featd[h*128+t] * (1.0/8192.0));
    __syncthreads();
    if(t<128){
      float a=0.f;
      for(int i=0;i<128;i++) a += feat[i]*w1[(size_t)i*128+t];
      x1[t] = a + b1[t];
    }
    __syncthreads();
    if(t==0){
      float s=0.f, ss=0.f;
      for(int i=0;i<128;i++){ s+=x1[i]; ss+=x1[i]*x1[i]; }
      float mu=s*(1.f/128.f); float var=ss*(1.f/128.f)-mu*mu;
      mrs[0]=mu; mrs[1]=rsqrtf(var+1e-5f);
    }
    __syncthreads();
    if(t<128){
      float vv=(x1[t]-mrs[0])*mrs[1]*lng[t]+lnb[t];
      x1[t]=fmaxf(vv,0.f);
    }
    __syncthreads();
    if(t<64){
      float s=0.f;
      for(int i=0;i<128;i++) s += x1[i]*w2[(size_t)i*64+t];
      x2[t]=fmaxf(s+b2[t],0.f);
    }
    __syncthreads();
    if(t==0){
      float o[3];
      for(int j=0;j<3;j++){ float s=0.f; for(int i=0;i<64;i++) s+=x2[i]*w3[i*3+j]; o[j]=s+b3[j]; }
      float mx=fmaxf(o[0],fmaxf(o[1],o[2]));
      float e0=expf(o[0]-mx), e1=expf(o[1]-mx), e2=expf(o[2]-mx), se=e0+e1+e2;
      float l0=e0/se, l1=e1/se, l2=e2/se;
      float wt=fminf(fmaxf(wtemp[0],0.1f),2.0f);
      l0/=wt; l1/=wt; l2/=wt;
      mx=fmaxf(l0,fmaxf(l1,l2));
      e0=expf(l0-mx); e1=expf(l1-mx); e2=expf(l2-mx); se=e0+e1+e2;
      float u0=fminf(fmaxf(e0/se,0.05f),0.8f);
      float u1=fminf(fmaxf(e1/se,0.05f),0.8f);
      float u2=fminf(fmaxf(e2/se,0.05f),0.8f);
      float su=u0+u1+u2;
      wh[h][0]=u0/su; wh[h][1]=u1/su; wh[h][2]=u2/su;
    }
    __syncthreads();
  }
  if(t==0){
    const double N = 33554432.0;
    double gs[9];
    for(int j=0;j<9;j++){ double s=0; for(int hh=0;hh<8;hh++) s+=headsum[hh*9+j]; gs[j]=s; }
    auto sd = [&](double s, double ss)->double{
      double v=(ss - s*s/N)/(N-1.0); return v>0.0 ? sqrt(v) : 0.0;
    };
    double std_cos = sd(gs[0],gs[1]);
    double std_cov = sd(gs[2],gs[3]);
    double std_vm  = sd(512.0*gs[5], 512.0*gs[6]);
    double sdot=0.0, sdot2=0.0;
    double Af[8], Bf[8];
    for(int hh=0;hh<8;hh++){
      const double* hs = headsum + hh*9;
      double A = (double)wh[hh][0]/(std_cos+1e-6);
      double B = (double)wh[hh][1]/(std_cov+1e-6)*0.5;
      double C = (double)wh[hh][2]/(std_vm +1e-6)*0.5;
      sdot  += A*hs[0] + B*hs[2] + C*512.0*hs[5];
      sdot2 += A*A*hs[1] + B*B*hs[3] + C*C*512.0*hs[6]
             + 2.0*A*B*hs[4] + 2.0*A*C*hs[7] + 2.0*B*C*hs[8];
      Af[hh]=A; Bf[hh]=B;
    }
    double dstd = sd(sdot, sdot2);
    double temp = dstd < 1e-4 ? 0.1 : (dstd < 0.01 ? 0.3 : 0.5 + dstd);
    temp = fmin(fmax(temp, 0.1), 3.0);
    for(int hh=0;hh<8;hh++){
      coef[hh]   = (float)(Af[hh]/temp);
      coef[8+hh] = (float)(Bf[hh]/temp);
    }
    coef[16] = (float)temp;
  }
}

// ---------------- flash softmax + PV (MFMA) ----------------
__global__ __launch_bounds__(256) void k_flash(const unsigned short* __restrict__ fqb,
    const unsigned short* __restrict__ fkb, const unsigned short* __restrict__ fvT,
    const float* __restrict__ ri1, const float* __restrict__ mq,
    const float* __restrict__ qdm, const float* __restrict__ ri2,
    const float* __restrict__ sk, const float* __restrict__ smk,
    const float* __restrict__ mxcg, const float* __restrict__ mxvg,
    const float* __restrict__ coef, float* __restrict__ oh){
  int bx = blockIdx.x; int hq = bx>>3; int rt = bx&7;
  int h = hq>>4, q = hq&15; int n0 = rt*64;
  __shared__ __align__(16) unsigned short Qs[64*64];
  __shared__ __align__(16) unsigned short Ks[128*64];
  __shared__ __align__(16) unsigned short Vt[64*128];
  __shared__ __align__(16) unsigned short Ps[4][16*40];
  __shared__ float ri2f[512], skf[512];
  int t = threadIdx.x; int w = t>>6; int l = t&63; int g = l>>4, lc = l&15;
  for(int i=t; i<512; i+=256){ ri2f[i]=ri2[hq*NS+i]; skf[i]=sk[hq*NS+i]; }
  #pragma unroll
  for(int i=0;i<2;i++){
    int c = t + i*256; int row = c>>3, k8 = c&7;
    s16x8 v = *(const s16x8*)(fqb + (size_t)(q*512 + n0 + row)*512 + h*64 + k8*8);
    *(s16x8*)((char*)Qs + row*128 + ((k8*16) ^ ((row&7)<<4))) = v;
  }
  float Ah = coef[h], Bh = coef[8+h];
  float ri1r[4], mqr[4], qdmr[4], Mr[4];
  #pragma unroll
  for(int r=0;r<4;r++){
    int n = hq*NS + n0 + w*16 + g*4 + r;
    ri1r[r]=ri1[n]; mqr[r]=mq[n]; qdmr[r]=qdm[n];
    Mr[r] = Ah*mxcg[n] + Bh*mxvg[n];
  }
  float smkv = smk[hq];
  __syncthreads();
  bf16x8 aq[2];
  #pragma unroll
  for(int ks=0;ks<2;ks++){
    int row = 16*w + lc;
    aq[ks] = *(const bf16x8*)((const char*)Qs + row*128 + (((ks*4+g)*16) ^ ((row&7)<<4)));
  }
  f32x4 acc[4];
  #pragma unroll
  for(int dt=0;dt<4;dt++) acc[dt] = (f32x4){0.f,0.f,0.f,0.f};
  float lsum[4]={0.f,0.f,0.f,0.f};
  unsigned short* Pw = &Ps[w][0];
  for(int mc=0; mc<4; mc++){
    __syncthreads();
    #pragma unroll
    for(int i=0;i<4;i++){
      int c = t + i*256; int row = c>>3, k8 = c&7;
      s16x8 v = *(const s16x8*)(fkb + (size_t)(q*512 + mc*128 + row)*512 + h*64 + k8*8);
      *(s16x8*)((char*)Ks + row*128 + ((k8*16) ^ ((row&7)<<4))) = v;
    }
    #pragma unroll
    for(int i=0;i<4;i++){
      int c = t + i*256; int d = c>>4, m8 = c&15;
      s16x8 v = *(const s16x8*)(fvT + (size_t)(hq*64 + d)*512 + mc*128 + m8*8);
      *(s16x8*)((char*)Vt + d*256 + ((m8*16) ^ ((d&7)<<4))) = v;
    }
    __syncthreads();
    #pragma unroll 1
    for(int mt2=0; mt2<4; mt2++){
      #pragma unroll
      for(int half=0; half<2; half++){
        int mt = mt2*2 + half;
        f32x4 dacc = (f32x4){0.f,0.f,0.f,0.f};
        #pragma unroll
        for(int ks=0;ks<2;ks++){
          int row = mt*16 + lc;
          bf16x8 bk = *(const bf16x8*)((const char*)Ks + row*128 + (((ks*4+g)*16) ^ ((row&7)<<4)));
          dacc = mfma16(aq[ks], bk, dacc);
        }
        int m = mc*128 + mt*16 + lc;
        float r2 = ri2f[m], skc = skf[m];
        #pragma unroll
        for(int r=0;r<4;r++){
          float dv = dacc[r];
          float cosv = fminf(fmaxf(dv*ri1r[r]*r2, -0.9f), 0.9f);
          float inner = dv - qdmr[r] - mqr[r]*skc + mqr[r]*smkv;
          float covv = fminf(fmaxf(CS2*inner, -10.f), 10.f);
          float sv = Ah*cosv + Bh*covv;
          float pe = __expf(fmaxf(sv - Mr[r], -60.f));
          lsum[r] += pe;
          Pw[(g*4+r)*40 + lc + half*16] = f2b(pe);
        }
      }
      asm volatile("s_waitcnt lgkmcnt(0)" ::: "memory");
      bf16x8 ap = *(const bf16x8*)((const char*)Pw + lc*80 + g*16);
      #pragma unroll
      for(int dt=0;dt<4;dt++){
        int drow = dt*16 + lc;
        bf16x8 bv = *(const bf16x8*)((const char*)Vt + drow*256 + (((mt2*4+g)*16) ^ ((drow&7)<<4)));
        acc[dt] = mfma16(ap, bv, acc[dt]);
      }
    }
  }
  #pragma unroll
  for(int off=1; off<16; off<<=1){
    #pragma unroll
    for(int r=0;r<4;r++) lsum[r] += __shfl_xor(lsum[r], off, 64);
  }
  #pragma unroll
  for(int r=0;r<4;r++){
    float inv = 1.f/lsum[r];
    int n = n0 + w*16 + g*4 + r;
    #pragma unroll
    for(int dt=0;dt<4;dt++){
      oh[(size_t)(q*512 + n)*512 + h*64 + dt*16 + lc] = acc[dt][r]*inv;
    }
  }
}

// ---------------- output GEMM fp32 (oh @ W_out + b) ----------------
__global__ __launch_bounds__(256) void k_gout(const float* __restrict__ A,
    const float* __restrict__ B, const float* __restrict__ bias,
    float* __restrict__ Cout){
  __shared__ __align__(16) float As[128][17];
  __shared__ __align__(16) float Bs[16][132];
  int t = threadIdx.x; int tr = t>>4, tc = t&15;
  int Rb = blockIdx.x*128, cb = blockIdx.y*128;
  float acc[8][8];
  #pragma unroll
  for(int i=0;i<8;i++)
    #pragma unroll
    for(int j=0;j<8;j++) acc[i][j]=0.f;
  for(int k0=0; k0<512; k0+=16){
    {
      int r = t>>1, kg = t&1;
      const float* ap = A + (size_t)(Rb+r)*512 + k0 + kg*8;
      float4 x0 = *(const float4*)ap; float4 x1 = *(const float4*)(ap+4);
      int kb = kg*8;
      As[r][kb+0]=x0.x; As[r][kb+1]=x0.y; As[r][kb+2]=x0.z; As[r][kb+3]=x0.w;
      As[r][kb+4]=x1.x; As[r][kb+5]=x1.y; As[r][kb+6]=x1.z; As[r][kb+7]=x1.w;
    }
    {
      int kk = t>>4, cg = t&15;
      const float* bp = B + (size_t)(k0+kk)*512 + cb + cg*8;
      float4 x0 = *(const float4*)bp; float4 x1 = *(const float4*)(bp+4);
      *(float4*)&Bs[kk][cg*8] = x0; *(float4*)&Bs[kk][cg*8+4] = x1;
    }
    __syncthreads();
    #pragma unroll
    for(int kk=0;kk<16;kk++){
      float ar[8], br[8];
      #pragma unroll
      for(int i=0;i<8;i++) ar[i] = As[tr*8+i][kk];
      float4 q0 = *(const float4*)&Bs[kk][tc*8];
      float4 q1 = *(const float4*)&Bs[kk][tc*8+4];
      br[0]=q0.x; br[1]=q0.y; br[2]=q0.z; br[3]=q0.w;
      br[4]=q1.x; br[5]=q1.y; br[6]=q1.z; br[7]=q1.w;
      #pragma unroll
      for(int i=0;i<8;i++)
        #pragma unroll
        for(int j=0;j<8;j++) acc[i][j] += ar[i]*br[j];
    }
    __syncthreads();
  }
  int c0 = cb + tc*8;
  float4 bv0 = *(const float4*)&bias[c0];
  float4 bv1 = *(const float4*)&bias[c0+4];
  #pragma unroll
  for(int i=0;i<8;i++){
    int R = Rb + tr*8 + i;
    float* dst = Cout + (size_t)R*512 + c0;
    float4 o0 = {acc[i][0]+bv0.x, acc[i][1]+bv0.y, acc[i][2]+bv0.z, acc[i][3]+bv0.w};
    float4 o1 = {acc[i][4]+bv1.x, acc[i][5]+bv1.y, acc[i][6]+bv1.z, acc[i][7]+bv1.w};
    *(float4*)dst = o0; *(float4*)(dst+4) = o1;
  }
}

extern "C" void kernel_launch(void* const* d_in, const int* in_sizes, int n_in,
                              void* d_out, int out_size, void* d_ws, size_t ws_size,
                              hipStream_t stream){
  const float* q    = (const float*)d_in[0];
  const float* k    = (const float*)d_in[1];
  const float* v    = (const float*)d_in[2];
  const float* ln1g = (const float*)d_in[3];
  const float* ln1b = (const float*)d_in[4];
  const float* Win  = (const float*)d_in[5];
  const float* w1   = (const float*)d_in[6];
  const float* b1   = (const float*)d_in[7];
  const float* lng  = (const float*)d_in[8];
  const float* lnb  = (const float*)d_in[9];
  const float* w2   = (const float*)d_in[10];
  const float* b2   = (const float*)d_in[11];
  const float* w3   = (const float*)d_in[12];
  const float* b3   = (const float*)d_in[13];
  const float* wtemp= (const float*)d_in[14];
  const float* Wout = (const float*)d_in[15];
  const float* bout = (const float*)d_in[16];

  float* w = (float*)d_ws;
  unsigned short* xnb = (unsigned short*)(w + OFF_XNB);
  unsigned short* fqb = (unsigned short*)(w + OFF_FQB);
  unsigned short* fkb = (unsigned short*)(w + OFF_FKB);
  unsigned short* fvb = (unsigned short*)(w + OFF_FVB);
  unsigned short* fvT = (unsigned short*)(w + OFF_FVT);
  unsigned short* wtb = (unsigned short*)(w + OFF_WT);
  float* oh   = w + OFF_OH;
  float* ri1  = w + OFF_ARR + 0*65536;
  float* rmx1 = w + OFF_ARR + 1*65536;
  float* mq_  = w + OFF_ARR + 2*65536;
  float* qdm  = w + OFF_ARR + 3*65536;
  float* ri2  = w + OFF_ARR + 4*65536;
  float* rmx2 = w + OFF_ARR + 5*65536;
  float* sk_  = w + OFF_ARR + 6*65536;
  float* mxc  = w + OFF_ARR + 7*65536;
  float* mxv  = w + OFF_ARR + 8*65536;
  float* mkb  = w + OFF_MKB;
  float* smk_ = w + OFF_SMK;
  float* coef = w + OFF_COEF;
  double* dbl = (double*)(w + OFF_DBL);
  double* headsum = dbl;
  double* featd   = dbl + 72;

  hipMemsetAsync(dbl, 0, NDBL*sizeof(double), stream);
  k_tw<<<64, 256, 0, stream>>>(Win, wtb);
  k_ln<<<24576, 64, 0, stream>>>(q, k, v, ln1g, ln1b, xnb);
  k_mm1<<<dim3(192,4), 256, 0, stream>>>(xnb, wtb, fqb, fkb, fvb);
  k_stats<<<128, 256, 0, stream>>>(fqb, fkb, ri1, rmx1, mq_, qdm, ri2, rmx2, sk_, mkb, smk_, featd);
  k_vt<<<512, 256, 0, stream>>>(fvb, fvT);
  k_comp<<<1024, 256, 0, stream>>>(fqb, fkb, ri1, rmx1, mq_, qdm, ri2, rmx2, sk_, smk_, mxc, mxv, headsum);
  k_finalize<<<1, 256, 0, stream>>>(headsum, featd, w1, b1, lng, lnb, w2, b2, w3, b3, wtemp, coef);
  k_flash<<<1024, 256, 0, stream>>>(fqb, fkb, fvT, ri1, mq_, qdm, ri2, sk_, smk_, mxc, mxv, coef, oh);
  k_gout<<<dim3(64,4), 256, 0, stream>>>(oh, Wout, bout, (float*)d_out);
}

// Round 3
// 219.838 us; speedup vs baseline: 3.6622x; 1.9699x over previous
//
#include <hip/hip_runtime.h>
#include <math.h>

#define H 8
#define NS 512
#define D 64

typedef __bf16 bf16x8 __attribute__((ext_vector_type(8)));
typedef float f32x4 __attribute__((ext_vector_type(4)));
typedef short s16x8 __attribute__((ext_vector_type(8)));
typedef short s16x4 __attribute__((ext_vector_type(4)));

#define CS2 ((1e-3f/512.f)/(8.f+1e-6f))

static __device__ __forceinline__ f32x4 mfma16(bf16x8 a, bf16x8 b, f32x4 c){
  return __builtin_amdgcn_mfma_f32_16x16x32_bf16(a,b,c,0,0,0);
}
static __device__ __forceinline__ float b2f(unsigned short s){
  union { unsigned u; float f; } v; v.u = ((unsigned)s)<<16; return v.f;
}
static __device__ __forceinline__ unsigned short f2b(float f){
  union { float f; unsigned u; } v; v.f = f;
  unsigned r = v.u + 0x7FFFu + ((v.u>>16)&1u);
  return (unsigned short)(r>>16);
}
static __device__ __forceinline__ float wred64(float v){
  #pragma unroll
  for(int m=32; m>0; m>>=1) v += __shfl_xor(v, m, 64);
  return v;
}

// ---- workspace layout (float element offsets) ----
constexpr size_t OFF_XNB = 0;                       // 24576x512 bf16
constexpr size_t OFF_FQB = 6291456;                 // 8192x512 bf16
constexpr size_t OFF_FKB = 8388608;
constexpr size_t OFF_FVB = 10485760;
constexpr size_t OFF_FVT = 12582912;                // [128][64][512] bf16
constexpr size_t OFF_WT  = 14680064;                // 512x512 bf16 (WinT)
constexpr size_t OFF_WOH = 14811136;                // 512x512 bf16 WoutT hi
constexpr size_t OFF_WOL = 14942208;                // 512x512 bf16 WoutT lo
constexpr size_t OFF_OHH = 15073280;                // 8192x512 bf16 oh hi
constexpr size_t OFF_OHL = 17170432;                // 8192x512 bf16 oh lo
constexpr size_t OFF_ARR = 19267584;                // 9 arrays x 65536 f32
constexpr size_t OFF_MKB = OFF_ARR + 9*65536;       // [128][64]
constexpr size_t OFF_SMK = OFF_MKB + 8192;
constexpr size_t OFF_COEF= OFF_SMK + 128;
constexpr size_t OFF_DBL = OFF_COEF + 32;           // 8B aligned (even)
constexpr size_t NDBL    = 72 + 1024;               // headsum[8][9], featd[8][128]

// ---------------- W_in transpose -> bf16 [n][k] ----------------
__global__ __launch_bounds__(256) void k_tw(const float* __restrict__ W, unsigned short* __restrict__ WT){
  int bx = blockIdx.x; int kt = bx>>3, nt = bx&7;
  __shared__ float tile[64][65];
  int t = threadIdx.x;
  #pragma unroll
  for(int i=0;i<4;i++){
    int row = (t>>4) + i*16; int col = (t&15)*4;
    float4 v = *(const float4*)(W + (size_t)(kt*64+row)*512 + nt*64 + col);
    tile[row][col]=v.x; tile[row][col+1]=v.y; tile[row][col+2]=v.z; tile[row][col+3]=v.w;
  }
  __syncthreads();
  #pragma unroll
  for(int i=0;i<4;i++){
    int n = (t>>4) + i*16; int ck = (t&15)*4;
    s16x4 o;
    #pragma unroll
    for(int j=0;j<4;j++) o[j] = (short)f2b(tile[ck+j][n]);
    *(s16x4*)(WT + (size_t)(nt*64+n)*512 + kt*64 + ck) = o;
  }
}

// ---------------- W_out transpose -> bf16 hi/lo [c][k] ----------------
__global__ __launch_bounds__(256) void k_two(const float* __restrict__ W,
    unsigned short* __restrict__ WTh, unsigned short* __restrict__ WTl){
  int bx = blockIdx.x; int kt = bx>>3, nt = bx&7;
  __shared__ float tile[64][65];
  int t = threadIdx.x;
  #pragma unroll
  for(int i=0;i<4;i++){
    int row = (t>>4) + i*16; int col = (t&15)*4;
    float4 v = *(const float4*)(W + (size_t)(kt*64+row)*512 + nt*64 + col);
    tile[row][col]=v.x; tile[row][col+1]=v.y; tile[row][col+2]=v.z; tile[row][col+3]=v.w;
  }
  __syncthreads();
  #pragma unroll
  for(int i=0;i<4;i++){
    int n = (t>>4) + i*16; int ck = (t&15)*4;
    s16x4 oh_, ol_;
    #pragma unroll
    for(int j=0;j<4;j++){
      float x = tile[ck+j][n];
      unsigned short hi = f2b(x);
      oh_[j] = (short)hi;
      ol_[j] = (short)f2b(x - b2f(hi));
    }
    *(s16x4*)(WTh + (size_t)(nt*64+n)*512 + kt*64 + ck) = oh_;
    *(s16x4*)(WTl + (size_t)(nt*64+n)*512 + kt*64 + ck) = ol_;
  }
}

// ---------------- LayerNorm -> bf16 (4 rows / block) ----------------
__global__ __launch_bounds__(256) void k_ln(const float* __restrict__ q,
    const float* __restrict__ k, const float* __restrict__ v,
    const float* __restrict__ g, const float* __restrict__ b,
    unsigned short* __restrict__ xnb){
  int row = blockIdx.x*4 + (threadIdx.x>>6); int t = threadIdx.x & 63;
  const float* src = (row < 8192) ? q : ((row < 16384) ? k : v);
  int r = row & 8191;
  const float4* sp = (const float4*)(src + (size_t)r*512);
  float4 v1 = sp[t*2], v2 = sp[t*2+1];
  float s  = v1.x+v1.y+v1.z+v1.w + v2.x+v2.y+v2.z+v2.w;
  float ss = v1.x*v1.x+v1.y*v1.y+v1.z*v1.z+v1.w*v1.w
           + v2.x*v2.x+v2.y*v2.y+v2.z*v2.z+v2.w*v2.w;
  s = wred64(s); ss = wred64(ss);
  float mu = s*(1.f/512.f);
  float var = ss*(1.f/512.f) - mu*mu;
  float rstd = rsqrtf(var + 1e-5f);
  const float4* gp = (const float4*)g; const float4* bp = (const float4*)b;
  float4 g1 = gp[t*2], g2 = gp[t*2+1], b1 = bp[t*2], b2 = bp[t*2+1];
  s16x8 o;
  o[0]=(short)f2b((v1.x-mu)*rstd*g1.x+b1.x); o[1]=(short)f2b((v1.y-mu)*rstd*g1.y+b1.y);
  o[2]=(short)f2b((v1.z-mu)*rstd*g1.z+b1.z); o[3]=(short)f2b((v1.w-mu)*rstd*g1.w+b1.w);
  o[4]=(short)f2b((v2.x-mu)*rstd*g2.x+b2.x); o[5]=(short)f2b((v2.y-mu)*rstd*g2.y+b2.y);
  o[6]=(short)f2b((v2.z-mu)*rstd*g2.z+b2.z); o[7]=(short)f2b((v2.w-mu)*rstd*g2.w+b2.w);
  *(s16x8*)(xnb + (size_t)row*512 + t*8) = o;
}

// ---------------- proj GEMM bf16 MFMA ----------------
__global__ __launch_bounds__(256) void k_mm1(const unsigned short* __restrict__ xnb,
    const unsigned short* __restrict__ WT,
    unsigned short* __restrict__ fqb, unsigned short* __restrict__ fkb,
    unsigned short* __restrict__ fvb){
  __shared__ __align__(16) unsigned short As[128*64];
  __shared__ __align__(16) unsigned short Bs[128*64];
  int t = threadIdx.x; int w = t>>6; int l = t&63; int g = l>>4, lc = l&15;
  int Rb = blockIdx.x*128, cb = blockIdx.y*128;
  int wr = (w>>1)*64, wc = (w&1)*64;
  f32x4 acc[4][4];
  #pragma unroll
  for(int i=0;i<4;i++)
    #pragma unroll
    for(int j=0;j<4;j++) acc[i][j] = (f32x4){0.f,0.f,0.f,0.f};
  for(int k0=0; k0<512; k0+=64){
    __syncthreads();
    #pragma unroll
    for(int i=0;i<4;i++){
      int c = t + i*256; int row = c>>3, k8 = c&7;
      s16x8 va = *(const s16x8*)(xnb + (size_t)(Rb+row)*512 + k0 + k8*8);
      *(s16x8*)((char*)As + row*128 + ((k8*16) ^ ((row&7)<<4))) = va;
      s16x8 vb = *(const s16x8*)(WT + (size_t)(cb+row)*512 + k0 + k8*8);
      *(s16x8*)((char*)Bs + row*128 + ((k8*16) ^ ((row&7)<<4))) = vb;
    }
    __syncthreads();
    #pragma unroll
    for(int ks=0; ks<2; ks++){
      bf16x8 ar[4], br[4];
      #pragma unroll
      for(int rt=0; rt<4; rt++){
        int row = wr + rt*16 + lc;
        ar[rt] = *(const bf16x8*)((const char*)As + row*128 + (((ks*4+g)*16) ^ ((row&7)<<4)));
      }
      #pragma unroll
      for(int ct=0; ct<4; ct++){
        int row = wc + ct*16 + lc;
        br[ct] = *(const bf16x8*)((const char*)Bs + row*128 + (((ks*4+g)*16) ^ ((row&7)<<4)));
      }
      #pragma unroll
      for(int rt=0; rt<4; rt++)
        #pragma unroll
        for(int ct=0; ct<4; ct++)
          acc[rt][ct] = mfma16(ar[rt], br[ct], acc[rt][ct]);
    }
  }
  #pragma unroll
  for(int rt=0; rt<4; rt++){
    #pragma unroll
    for(int r=0; r<4; r++){
      int R = Rb + wr + rt*16 + g*4 + r;
      int tsel = R>>13; int rr = R&8191;
      unsigned short* dst = (tsel==0)?fqb:((tsel==1)?fkb:fvb);
      #pragma unroll
      for(int ct=0; ct<4; ct++){
        int c = cb + wc + ct*16 + lc;
        dst[(size_t)rr*512 + c] = f2b(acc[rt][ct][r]);
      }
    }
  }
}

// ---------------- column stats: mkb, smk, featd ----------------
__global__ __launch_bounds__(1024) void k_colstats(const unsigned short* __restrict__ fqb,
    const unsigned short* __restrict__ fkb,
    float* __restrict__ mkb, float* __restrict__ smk, double* featd){
  int hq = blockIdx.x; int h = hq>>4, q = hq&15;
  int t = threadIdx.x; int d = t&63; int g = t>>6;  // 16 n-groups
  __shared__ float cq[16][64], ck[16][64];
  float aq=0.f, ak=0.f;
  for(int n=g; n<512; n+=16){
    size_t base = (size_t)(q*512+n)*512 + h*64 + d;
    aq += b2f(fqb[base]);
    ak += b2f(fkb[base]);
  }
  cq[g][d]=aq; ck[g][d]=ak;
  __syncthreads();
  if(t<64){
    float sq=0.f, sk2=0.f;
    #pragma unroll
    for(int i=0;i<16;i++){ sq+=cq[i][t]; sk2+=ck[i][t]; }
    atomicAdd(&featd[h*128+t], (double)sq);
    atomicAdd(&featd[h*128+64+t], (double)sk2);
    float mk = sk2*(1.f/512.f);
    mkb[hq*64+t]=mk;
    cq[0][t]=mk;
  }
  __syncthreads();
  if(t<64){
    float s = wred64(cq[0][t]);
    if(t==0) smk[hq]=s;
  }
}

// ---------------- row stats: one thread per row ----------------
__global__ __launch_bounds__(256) void k_rowstats(const unsigned short* __restrict__ fqb,
    const unsigned short* __restrict__ fkb, const float* __restrict__ mkb,
    float* __restrict__ ri1, float* __restrict__ rmx1, float* __restrict__ mq,
    float* __restrict__ qdm, float* __restrict__ ri2, float* __restrict__ rmx2,
    float* __restrict__ sk){
  int b = blockIdx.x; int hq = b>>1; int h = hq>>4, q = hq&15;
  int n = (b&1)*256 + threadIdx.x;
  __shared__ float mk[64];
  if(threadIdx.x<64) mk[threadIdx.x] = mkb[hq*64+threadIdx.x];
  __syncthreads();
  const unsigned short* fr = fqb + (size_t)(q*512+n)*512 + h*64;
  const unsigned short* kr = fkb + (size_t)(q*512+n)*512 + h*64;
  float sq=0.f, ssq=0.f, dq=0.f, sks=0.f, ssk=0.f;
  #pragma unroll
  for(int j=0;j<8;j++){
    s16x8 vq = *(const s16x8*)(fr + j*8);
    s16x8 vk = *(const s16x8*)(kr + j*8);
    #pragma unroll
    for(int e=0;e<8;e++){
      float a = b2f((unsigned short)vq[e]);
      float c = b2f((unsigned short)vk[e]);
      sq += a; ssq += a*a; dq += a*mk[j*8+e];
      sks += c; ssk += c*c;
    }
  }
  int idx = hq*512 + n;
  float nq = sqrtf(ssq);
  ri1[idx]  = 1.f/(nq+1e-6f);
  rmx1[idx] = 1.f/fmaxf(nq,1e-6f);
  mq[idx]   = sq*(1.f/64.f);
  qdm[idx]  = dq;
  float nk = sqrtf(ssk);
  ri2[idx]  = 1.f/(nk+1e-6f);
  rmx2[idx] = 1.f/fmaxf(nk,1e-6f);
  sk[idx]   = sks;
}

// ---------------- fv transpose -> fvT[hq][d][n] bf16 ----------------
__global__ __launch_bounds__(256) void k_vt(const unsigned short* __restrict__ fvb,
    unsigned short* __restrict__ fvT){
  int bx = blockIdx.x; int hq = bx>>2, nc = bx&3;
  int h = hq>>4, q = hq&15; int n0 = nc*128;
  __shared__ float tile[128][65];
  int t = threadIdx.x;
  #pragma unroll
  for(int i=0;i<4;i++){
    int c = t + i*256; int row = c>>3, k8 = c&7;
    s16x8 v = *(const s16x8*)(fvb + (size_t)(q*512 + n0 + row)*512 + h*64 + k8*8);
    #pragma unroll
    for(int j=0;j<8;j++) tile[row][k8*8+j] = b2f((unsigned short)v[j]);
  }
  __syncthreads();
  #pragma unroll
  for(int i=0;i<4;i++){
    int c = t + i*256; int d = c>>4, n8 = c&15;
    s16x8 o;
    #pragma unroll
    for(int j=0;j<8;j++) o[j] = (short)f2b(tile[n8*8+j][d]);
    *(s16x8*)(fvT + (size_t)(hq*64 + d)*512 + n0 + n8*8) = o;
  }
}

// ---------------- component sums pass (MFMA QK) ----------------
__global__ __launch_bounds__(256) void k_comp(const unsigned short* __restrict__ fqb,
    const unsigned short* __restrict__ fkb,
    const float* __restrict__ ri1, const float* __restrict__ rmx1,
    const float* __restrict__ mq, const float* __restrict__ qdm,
    const float* __restrict__ ri2, const float* __restrict__ rmx2,
    const float* __restrict__ sk, const float* __restrict__ smk,
    float* __restrict__ mxcg, float* __restrict__ mxvg, double* headsum){
  int bx = blockIdx.x; int hq = bx>>3; int rt = bx&7;
  int h = hq>>4, q = hq&15; int n0 = rt*64;
  __shared__ __align__(16) unsigned short Qs[64*64];
  __shared__ __align__(16) unsigned short Ks[128*64];
  __shared__ float ri2f[512], rmx2f[512], skf[512];
  __shared__ float red[4][9];
  int t = threadIdx.x; int w = t>>6; int l = t&63; int g = l>>4, lc = l&15;
  for(int i=t; i<512; i+=256){
    ri2f[i]=ri2[hq*NS+i]; rmx2f[i]=rmx2[hq*NS+i]; skf[i]=sk[hq*NS+i];
  }
  #pragma unroll
  for(int i=0;i<2;i++){
    int c = t + i*256; int row = c>>3, k8 = c&7;
    s16x8 v = *(const s16x8*)(fqb + (size_t)(q*512 + n0 + row)*512 + h*64 + k8*8);
    *(s16x8*)((char*)Qs + row*128 + ((k8*16) ^ ((row&7)<<4))) = v;
  }
  float ri1r[4], rmx1r[4], mqr[4], qdmr[4];
  #pragma unroll
  for(int r=0;r<4;r++){
    int n = hq*NS + n0 + w*16 + g*4 + r;
    ri1r[r]=ri1[n]; rmx1r[r]=rmx1[n]; mqr[r]=mq[n]; qdmr[r]=qdm[n];
  }
  float smkv = smk[hq];
  __syncthreads();
  bf16x8 aq[2];
  #pragma unroll
  for(int ks=0;ks<2;ks++){
    int row = 16*w + lc;
    aq[ks] = *(const bf16x8*)((const char*)Qs + row*128 + (((ks*4+g)*16) ^ ((row&7)<<4)));
  }
  float p0=0,p1=0,p2=0,p3=0,p4=0;
  float rm_m[4]={0,0,0,0}, rm_c[4]={0,0,0,0}, rm_v[4]={0,0,0,0};
  float mxc[4]={-1e30f,-1e30f,-1e30f,-1e30f}, mxv[4]={-1e30f,-1e30f,-1e30f,-1e30f};
  for(int mc=0; mc<4; mc++){
    __syncthreads();
    #pragma unroll
    for(int i=0;i<4;i++){
      int c = t + i*256; int row = c>>3, k8 = c&7;
      s16x8 v = *(const s16x8*)(fkb + (size_t)(q*512 + mc*128 + row)*512 + h*64 + k8*8);
      *(s16x8*)((char*)Ks + row*128 + ((k8*16) ^ ((row&7)<<4))) = v;
    }
    __syncthreads();
    #pragma unroll 2
    for(int mt=0; mt<8; mt++){
      f32x4 dacc = (f32x4){0.f,0.f,0.f,0.f};
      #pragma unroll
      for(int ks=0;ks<2;ks++){
        int row = mt*16 + lc;
        bf16x8 bk = *(const bf16x8*)((const char*)Ks + row*128 + (((ks*4+g)*16) ^ ((row&7)<<4)));
        dacc = mfma16(aq[ks], bk, dacc);
      }
      int m = mc*128 + mt*16 + lc;
      float r2 = ri2f[m], rx2 = rmx2f[m], skc = skf[m];
      #pragma unroll
      for(int r=0;r<4;r++){
        float dv = dacc[r];
        float cosv = fminf(fmaxf(dv*ri1r[r]*r2, -0.9f), 0.9f);
        float inner = dv - qdmr[r] - mqr[r]*skc + mqr[r]*smkv;
        float covv = fminf(fmaxf(CS2*inner, -10.f), 10.f);
        float csv = fminf(fmaxf(dv*rmx1r[r]*rx2, -0.9f), 0.9f);
        float marg = fminf(fmaxf(0.01f - csv, 0.f), 5.f);
        p0 += cosv; p1 += cosv*cosv; p2 += covv; p3 += covv*covv; p4 += cosv*covv;
        rm_m[r]+=marg; rm_c[r]+=cosv; rm_v[r]+=covv;
        mxc[r]=fmaxf(mxc[r],cosv); mxv[r]=fmaxf(mxv[r],covv);
      }
    }
  }
  #pragma unroll
  for(int off=1; off<16; off<<=1){
    #pragma unroll
    for(int r=0;r<4;r++){
      rm_m[r]+=__shfl_xor(rm_m[r],off,64);
      rm_c[r]+=__shfl_xor(rm_c[r],off,64);
      rm_v[r]+=__shfl_xor(rm_v[r],off,64);
      mxc[r]=fmaxf(mxc[r],__shfl_xor(mxc[r],off,64));
      mxv[r]=fmaxf(mxv[r],__shfl_xor(mxv[r],off,64));
    }
  }
  float q0=0,q1=0,q2=0,q3=0;
  if(lc==0){
    #pragma unroll
    for(int r=0;r<4;r++){
      float vmv = rm_m[r]*(1.f/512.f);
      q0+=vmv; q1+=vmv*vmv; q2+=vmv*rm_c[r]; q3+=vmv*rm_v[r];
      int n = n0 + w*16 + g*4 + r;
      mxcg[hq*NS+n]=mxc[r]; mxvg[hq*NS+n]=mxv[r];
    }
  }
  float all9[9] = {p0,p1,p2,p3,p4,q0,q1,q2,q3};
  #pragma unroll
  for(int j=0;j<9;j++){
    float vv = wred64(all9[j]);
    if(l==0) red[w][j]=vv;
  }
  __syncthreads();
  if(t<9){
    double s = (double)red[0][t]+(double)red[1][t]+(double)red[2][t]+(double)red[3][t];
    atomicAdd(&headsum[h*9+t], s);
  }
}

// ---------------- finalize ----------------
__global__ __launch_bounds__(256) void k_finalize(const double* headsum, const double* featd,
    const float* __restrict__ w1, const float* __restrict__ b1,
    const float* __restrict__ lng, const float* __restrict__ lnb,
    const float* __restrict__ w2, const float* __restrict__ b2,
    const float* __restrict__ w3, const float* __restrict__ b3,
    const float* __restrict__ wtemp, float* coef){
  __shared__ float feat[128], x1[128], x2[64];
  __shared__ float wh[8][3];
  __shared__ float mrs[2];
  int t = threadIdx.x;
  for(int h=0; h<8; h++){
    if(t<128) feat[t] = (float)(featd[h*128+t] * (1.0/8192.0));
    __syncthreads();
    if(t<128){
      float a=0.f;
      for(int i=0;i<128;i++) a += feat[i]*w1[(size_t)i*128+t];
      x1[t] = a + b1[t];
    }
    __syncthreads();
    if(t==0){
      float s=0.f, ss=0.f;
      for(int i=0;i<128;i++){ s+=x1[i]; ss+=x1[i]*x1[i]; }
      float mu=s*(1.f/128.f); float var=ss*(1.f/128.f)-mu*mu;
      mrs[0]=mu; mrs[1]=rsqrtf(var+1e-5f);
    }
    __syncthreads();
    if(t<128){
      float vv=(x1[t]-mrs[0])*mrs[1]*lng[t]+lnb[t];
      x1[t]=fmaxf(vv,0.f);
    }
    __syncthreads();
    if(t<64){
      float s=0.f;
      for(int i=0;i<128;i++) s += x1[i]*w2[(size_t)i*64+t];
      x2[t]=fmaxf(s+b2[t],0.f);
    }
    __syncthreads();
    if(t==0){
      float o[3];
      for(int j=0;j<3;j++){ float s=0.f; for(int i=0;i<64;i++) s+=x2[i]*w3[i*3+j]; o[j]=s+b3[j]; }
      float mx=fmaxf(o[0],fmaxf(o[1],o[2]));
      float e0=expf(o[0]-mx), e1=expf(o[1]-mx), e2=expf(o[2]-mx), se=e0+e1+e2;
      float l0=e0/se, l1=e1/se, l2=e2/se;
      float wt=fminf(fmaxf(wtemp[0],0.1f),2.0f);
      l0/=wt; l1/=wt; l2/=wt;
      mx=fmaxf(l0,fmaxf(l1,l2));
      e0=expf(l0-mx); e1=expf(l1-mx); e2=expf(l2-mx); se=e0+e1+e2;
      float u0=fminf(fmaxf(e0/se,0.05f),0.8f);
      float u1=fminf(fmaxf(e1/se,0.05f),0.8f);
      float u2=fminf(fmaxf(e2/se,0.05f),0.8f);
      float su=u0+u1+u2;
      wh[h][0]=u0/su; wh[h][1]=u1/su; wh[h][2]=u2/su;
    }
    __syncthreads();
  }
  if(t==0){
    const double N = 33554432.0;
    double gs[9];
    for(int j=0;j<9;j++){ double s=0; for(int hh=0;hh<8;hh++) s+=headsum[hh*9+j]; gs[j]=s; }
    auto sd = [&](double s, double ss)->double{
      double v=(ss - s*s/N)/(N-1.0); return v>0.0 ? sqrt(v) : 0.0;
    };
    double std_cos = sd(gs[0],gs[1]);
    double std_cov = sd(gs[2],gs[3]);
    double std_vm  = sd(512.0*gs[5], 512.0*gs[6]);
    double sdot=0.0, sdot2=0.0;
    double Af[8], Bf[8];
    for(int hh=0;hh<8;hh++){
      const double* hs = headsum + hh*9;
      double A = (double)wh[hh][0]/(std_cos+1e-6);
      double B = (double)wh[hh][1]/(std_cov+1e-6)*0.5;
      double C = (double)wh[hh][2]/(std_vm +1e-6)*0.5;
      sdot  += A*hs[0] + B*hs[2] + C*512.0*hs[5];
      sdot2 += A*A*hs[1] + B*B*hs[3] + C*C*512.0*hs[6]
             + 2.0*A*B*hs[4] + 2.0*A*C*hs[7] + 2.0*B*C*hs[8];
      Af[hh]=A; Bf[hh]=B;
    }
    double dstd = sd(sdot, sdot2);
    double temp = dstd < 1e-4 ? 0.1 : (dstd < 0.01 ? 0.3 : 0.5 + dstd);
    temp = fmin(fmax(temp, 0.1), 3.0);
    for(int hh=0;hh<8;hh++){
      coef[hh]   = (float)(Af[hh]/temp);
      coef[8+hh] = (float)(Bf[hh]/temp);
    }
    coef[16] = (float)temp;
  }
}

// ---------------- flash softmax + PV (MFMA), oh -> bf16 hi/lo ----------------
__global__ __launch_bounds__(256) void k_flash(const unsigned short* __restrict__ fqb,
    const unsigned short* __restrict__ fkb, const unsigned short* __restrict__ fvT,
    const float* __restrict__ ri1, const float* __restrict__ mq,
    const float* __restrict__ qdm, const float* __restrict__ ri2,
    const float* __restrict__ sk, const float* __restrict__ smk,
    const float* __restrict__ mxcg, const float* __restrict__ mxvg,
    const float* __restrict__ coef,
    unsigned short* __restrict__ ohh, unsigned short* __restrict__ ohl){
  int bx = blockIdx.x; int hq = bx>>3; int rt = bx&7;
  int h = hq>>4, q = hq&15; int n0 = rt*64;
  __shared__ __align__(16) unsigned short Qs[64*64];
  __shared__ __align__(16) unsigned short Ks[128*64];
  __shared__ __align__(16) unsigned short Vt[64*128];
  __shared__ __align__(16) unsigned short Ps[4][16*40];
  __shared__ float ri2f[512], skf[512];
  int t = threadIdx.x; int w = t>>6; int l = t&63; int g = l>>4, lc = l&15;
  for(int i=t; i<512; i+=256){ ri2f[i]=ri2[hq*NS+i]; skf[i]=sk[hq*NS+i]; }
  #pragma unroll
  for(int i=0;i<2;i++){
    int c = t + i*256; int row = c>>3, k8 = c&7;
    s16x8 v = *(const s16x8*)(fqb + (size_t)(q*512 + n0 + row)*512 + h*64 + k8*8);
    *(s16x8*)((char*)Qs + row*128 + ((k8*16) ^ ((row&7)<<4))) = v;
  }
  float Ah = coef[h], Bh = coef[8+h];
  float ri1r[4], mqr[4], qdmr[4], Mr[4];
  #pragma unroll
  for(int r=0;r<4;r++){
    int n = hq*NS + n0 + w*16 + g*4 + r;
    ri1r[r]=ri1[n]; mqr[r]=mq[n]; qdmr[r]=qdm[n];
    Mr[r] = Ah*mxcg[n] + Bh*mxvg[n];
  }
  float smkv = smk[hq];
  __syncthreads();
  bf16x8 aq[2];
  #pragma unroll
  for(int ks=0;ks<2;ks++){
    int row = 16*w + lc;
    aq[ks] = *(const bf16x8*)((const char*)Qs + row*128 + (((ks*4+g)*16) ^ ((row&7)<<4)));
  }
  f32x4 acc[4];
  #pragma unroll
  for(int dt=0;dt<4;dt++) acc[dt] = (f32x4){0.f,0.f,0.f,0.f};
  float lsum[4]={0.f,0.f,0.f,0.f};
  unsigned short* Pw = &Ps[w][0];
  for(int mc=0; mc<4; mc++){
    __syncthreads();
    #pragma unroll
    for(int i=0;i<4;i++){
      int c = t + i*256; int row = c>>3, k8 = c&7;
      s16x8 v = *(const s16x8*)(fkb + (size_t)(q*512 + mc*128 + row)*512 + h*64 + k8*8);
      *(s16x8*)((char*)Ks + row*128 + ((k8*16) ^ ((row&7)<<4))) = v;
    }
    #pragma unroll
    for(int i=0;i<4;i++){
      int c = t + i*256; int d = c>>4, m8 = c&15;
      s16x8 v = *(const s16x8*)(fvT + (size_t)(hq*64 + d)*512 + mc*128 + m8*8);
      *(s16x8*)((char*)Vt + d*256 + ((m8*16) ^ ((d&7)<<4))) = v;
    }
    __syncthreads();
    #pragma unroll 1
    for(int mt2=0; mt2<4; mt2++){
      #pragma unroll
      for(int half=0; half<2; half++){
        int mt = mt2*2 + half;
        f32x4 dacc = (f32x4){0.f,0.f,0.f,0.f};
        #pragma unroll
        for(int ks=0;ks<2;ks++){
          int row = mt*16 + lc;
          bf16x8 bk = *(const bf16x8*)((const char*)Ks + row*128 + (((ks*4+g)*16) ^ ((row&7)<<4)));
          dacc = mfma16(aq[ks], bk, dacc);
        }
        int m = mc*128 + mt*16 + lc;
        float r2 = ri2f[m], skc = skf[m];
        #pragma unroll
        for(int r=0;r<4;r++){
          float dv = dacc[r];
          float cosv = fminf(fmaxf(dv*ri1r[r]*r2, -0.9f), 0.9f);
          float inner = dv - qdmr[r] - mqr[r]*skc + mqr[r]*smkv;
          float covv = fminf(fmaxf(CS2*inner, -10.f), 10.f);
          float sv = Ah*cosv + Bh*covv;
          float pe = __expf(fmaxf(sv - Mr[r], -60.f));
          lsum[r] += pe;
          Pw[(g*4+r)*40 + lc + half*16] = f2b(pe);
        }
      }
      asm volatile("s_waitcnt lgkmcnt(0)" ::: "memory");
      bf16x8 ap = *(const bf16x8*)((const char*)Pw + lc*80 + g*16);
      #pragma unroll
      for(int dt=0;dt<4;dt++){
        int drow = dt*16 + lc;
        bf16x8 bv = *(const bf16x8*)((const char*)Vt + drow*256 + (((mt2*4+g)*16) ^ ((drow&7)<<4)));
        acc[dt] = mfma16(ap, bv, acc[dt]);
      }
    }
  }
  #pragma unroll
  for(int off=1; off<16; off<<=1){
    #pragma unroll
    for(int r=0;r<4;r++) lsum[r] += __shfl_xor(lsum[r], off, 64);
  }
  #pragma unroll
  for(int r=0;r<4;r++){
    float inv = 1.f/lsum[r];
    int n = n0 + w*16 + g*4 + r;
    #pragma unroll
    for(int dt=0;dt<4;dt++){
      size_t idx = (size_t)(q*512 + n)*512 + h*64 + dt*16 + lc;
      float val = acc[dt][r]*inv;
      unsigned short hi = f2b(val);
      ohh[idx] = hi;
      ohl[idx] = f2b(val - b2f(hi));
    }
  }
}

// ---------------- output GEMM: split-bf16 3-term MFMA + bias ----------------
__global__ __launch_bounds__(256) void k_gout2(const unsigned short* __restrict__ Ahp,
    const unsigned short* __restrict__ Alp,
    const unsigned short* __restrict__ Bhp, const unsigned short* __restrict__ Blp,
    const float* __restrict__ bias, float* __restrict__ Cout){
  __shared__ __align__(16) unsigned short AsH[128*64];
  __shared__ __align__(16) unsigned short AsL[128*64];
  __shared__ __align__(16) unsigned short BsH[128*64];
  __shared__ __align__(16) unsigned short BsL[128*64];
  int t = threadIdx.x; int w = t>>6; int l = t&63; int g = l>>4, lc = l&15;
  int Rb = blockIdx.x*128, cb = blockIdx.y*128;
  int wr = (w>>1)*64, wc = (w&1)*64;
  f32x4 acc[4][4];
  #pragma unroll
  for(int i=0;i<4;i++)
    #pragma unroll
    for(int j=0;j<4;j++) acc[i][j] = (f32x4){0.f,0.f,0.f,0.f};
  for(int k0=0; k0<512; k0+=64){
    __syncthreads();
    #pragma unroll
    for(int i=0;i<4;i++){
      int c = t + i*256; int row = c>>3, k8 = c&7;
      int sw = (k8*16) ^ ((row&7)<<4);
      *(s16x8*)((char*)AsH + row*128 + sw) = *(const s16x8*)(Ahp + (size_t)(Rb+row)*512 + k0 + k8*8);
      *(s16x8*)((char*)AsL + row*128 + sw) = *(const s16x8*)(Alp + (size_t)(Rb+row)*512 + k0 + k8*8);
      *(s16x8*)((char*)BsH + row*128 + sw) = *(const s16x8*)(Bhp + (size_t)(cb+row)*512 + k0 + k8*8);
      *(s16x8*)((char*)BsL + row*128 + sw) = *(const s16x8*)(Blp + (size_t)(cb+row)*512 + k0 + k8*8);
    }
    __syncthreads();
    #pragma unroll
    for(int ks=0; ks<2; ks++){
      bf16x8 arh[4], arl[4], brh[4], brl[4];
      #pragma unroll
      for(int rt=0; rt<4; rt++){
        int row = wr + rt*16 + lc;
        int off = row*128 + (((ks*4+g)*16) ^ ((row&7)<<4));
        arh[rt] = *(const bf16x8*)((const char*)AsH + off);
        arl[rt] = *(const bf16x8*)((const char*)AsL + off);
      }
      #pragma unroll
      for(int ct=0; ct<4; ct++){
        int row = wc + ct*16 + lc;
        int off = row*128 + (((ks*4+g)*16) ^ ((row&7)<<4));
        brh[ct] = *(const bf16x8*)((const char*)BsH + off);
        brl[ct] = *(const bf16x8*)((const char*)BsL + off);
      }
      #pragma unroll
      for(int rt=0; rt<4; rt++)
        #pragma unroll
        for(int ct=0; ct<4; ct++){
          acc[rt][ct] = mfma16(arh[rt], brh[ct], acc[rt][ct]);
          acc[rt][ct] = mfma16(arh[rt], brl[ct], acc[rt][ct]);
          acc[rt][ct] = mfma16(arl[rt], brh[ct], acc[rt][ct]);
        }
    }
  }
  #pragma unroll
  for(int rt=0; rt<4; rt++){
    #pragma unroll
    for(int r=0; r<4; r++){
      int R = Rb + wr + rt*16 + g*4 + r;
      #pragma unroll
      for(int ct=0; ct<4; ct++){
        int c = cb + wc + ct*16 + lc;
        Cout[(size_t)R*512 + c] = acc[rt][ct][r] + bias[c];
      }
    }
  }
}

extern "C" void kernel_launch(void* const* d_in, const int* in_sizes, int n_in,
                              void* d_out, int out_size, void* d_ws, size_t ws_size,
                              hipStream_t stream){
  const float* q    = (const float*)d_in[0];
  const float* k    = (const float*)d_in[1];
  const float* v    = (const float*)d_in[2];
  const float* ln1g = (const float*)d_in[3];
  const float* ln1b = (const float*)d_in[4];
  const float* Win  = (const float*)d_in[5];
  const float* w1   = (const float*)d_in[6];
  const float* b1   = (const float*)d_in[7];
  const float* lng  = (const float*)d_in[8];
  const float* lnb  = (const float*)d_in[9];
  const float* w2   = (const float*)d_in[10];
  const float* b2   = (const float*)d_in[11];
  const float* w3   = (const float*)d_in[12];
  const float* b3   = (const float*)d_in[13];
  const float* wtemp= (const float*)d_in[14];
  const float* Wout = (const float*)d_in[15];
  const float* bout = (const float*)d_in[16];

  float* w = (float*)d_ws;
  unsigned short* xnb = (unsigned short*)(w + OFF_XNB);
  unsigned short* fqb = (unsigned short*)(w + OFF_FQB);
  unsigned short* fkb = (unsigned short*)(w + OFF_FKB);
  unsigned short* fvb = (unsigned short*)(w + OFF_FVB);
  unsigned short* fvT = (unsigned short*)(w + OFF_FVT);
  unsigned short* wtb = (unsigned short*)(w + OFF_WT);
  unsigned short* woh = (unsigned short*)(w + OFF_WOH);
  unsigned short* wol = (unsigned short*)(w + OFF_WOL);
  unsigned short* ohh = (unsigned short*)(w + OFF_OHH);
  unsigned short* ohl = (unsigned short*)(w + OFF_OHL);
  float* ri1  = w + OFF_ARR + 0*65536;
  float* rmx1 = w + OFF_ARR + 1*65536;
  float* mq_  = w + OFF_ARR + 2*65536;
  float* qdm  = w + OFF_ARR + 3*65536;
  float* ri2  = w + OFF_ARR + 4*65536;
  float* rmx2 = w + OFF_ARR + 5*65536;
  float* sk_  = w + OFF_ARR + 6*65536;
  float* mxc  = w + OFF_ARR + 7*65536;
  float* mxv  = w + OFF_ARR + 8*65536;
  float* mkb  = w + OFF_MKB;
  float* smk_ = w + OFF_SMK;
  float* coef = w + OFF_COEF;
  double* dbl = (double*)(w + OFF_DBL);
  double* headsum = dbl;
  double* featd   = dbl + 72;

  hipMemsetAsync(dbl, 0, NDBL*sizeof(double), stream);
  k_tw<<<64, 256, 0, stream>>>(Win, wtb);
  k_two<<<64, 256, 0, stream>>>(Wout, woh, wol);
  k_ln<<<6144, 256, 0, stream>>>(q, k, v, ln1g, ln1b, xnb);
  k_mm1<<<dim3(192,4), 256, 0, stream>>>(xnb, wtb, fqb, fkb, fvb);
  k_colstats<<<128, 1024, 0, stream>>>(fqb, fkb, mkb, smk_, featd);
  k_rowstats<<<256, 256, 0, stream>>>(fqb, fkb, mkb, ri1, rmx1, mq_, qdm, ri2, rmx2, sk_);
  k_vt<<<512, 256, 0, stream>>>(fvb, fvT);
  k_comp<<<1024, 256, 0, stream>>>(fqb, fkb, ri1, rmx1, mq_, qdm, ri2, rmx2, sk_, smk_, mxc, mxv, headsum);
  k_finalize<<<1, 256, 0, stream>>>(headsum, featd, w1, b1, lng, lnb, w2, b2, w3, b3, wtemp, coef);
  k_flash<<<1024, 256, 0, stream>>>(fqb, fkb, fvT, ri1, mq_, qdm, ri2, sk_, smk_, mxc, mxv, coef, ohh, ohl);
  k_gout2<<<dim3(64,4), 256, 0, stream>>>(ohh, ohl, woh, wol, bout, (float*)d_out);
}

// Round 4
// 178.958 us; speedup vs baseline: 4.4987x; 1.2284x over previous
//
#include <hip/hip_runtime.h>
#include <math.h>

#define H 8
#define NS 512
#define D 64

typedef __bf16 bf16x8 __attribute__((ext_vector_type(8)));
typedef float f32x4 __attribute__((ext_vector_type(4)));
typedef short s16x8 __attribute__((ext_vector_type(8)));
typedef short s16x4 __attribute__((ext_vector_type(4)));

#define CS2 ((1e-3f/512.f)/(8.f+1e-6f))

static __device__ __forceinline__ f32x4 mfma16(bf16x8 a, bf16x8 b, f32x4 c){
  return __builtin_amdgcn_mfma_f32_16x16x32_bf16(a,b,c,0,0,0);
}
static __device__ __forceinline__ float b2f(unsigned short s){
  union { unsigned u; float f; } v; v.u = ((unsigned)s)<<16; return v.f;
}
static __device__ __forceinline__ unsigned short f2b(float f){
  union { float f; unsigned u; } v; v.f = f;
  unsigned r = v.u + 0x7FFFu + ((v.u>>16)&1u);
  return (unsigned short)(r>>16);
}
static __device__ __forceinline__ float wred64(float v){
  #pragma unroll
  for(int m=32; m>0; m>>=1) v += __shfl_xor(v, m, 64);
  return v;
}

// ---- workspace layout (float element offsets) ----
constexpr size_t OFF_XNB = 0;                       // 24576x512 bf16
constexpr size_t OFF_FQB = 6291456;                 // 8192x512 bf16
constexpr size_t OFF_FKB = 8388608;
constexpr size_t OFF_FVB = 10485760;
constexpr size_t OFF_FVT = 12582912;                // [128][64][512] bf16
constexpr size_t OFF_WT  = 14680064;                // 512x512 bf16 (WinT)
constexpr size_t OFF_WOH = 14811136;                // 512x512 bf16 WoutT hi
constexpr size_t OFF_WOL = 14942208;                // 512x512 bf16 WoutT lo
constexpr size_t OFF_OHH = 15073280;                // 8192x512 bf16 oh hi
constexpr size_t OFF_OHL = 17170432;                // 8192x512 bf16 oh lo
constexpr size_t OFF_ARR = 19267584;                // 9 arrays x 65536 f32
constexpr size_t OFF_MKB = OFF_ARR + 9*65536;       // [128][64]
constexpr size_t OFF_SMK = OFF_MKB + 8192;
constexpr size_t OFF_COEF= OFF_SMK + 128;
constexpr size_t OFF_DBL = OFF_COEF + 32;           // 8B aligned (even)
constexpr size_t NDBL    = 72 + 1024;               // headsum[8][9], featd[8][128]

// ---------------- W_in transpose -> bf16 [n][k] ----------------
__global__ __launch_bounds__(256) void k_tw(const float* __restrict__ W, unsigned short* __restrict__ WT){
  int bx = blockIdx.x; int kt = bx>>3, nt = bx&7;
  __shared__ float tile[64][65];
  int t = threadIdx.x;
  #pragma unroll
  for(int i=0;i<4;i++){
    int row = (t>>4) + i*16; int col = (t&15)*4;
    float4 v = *(const float4*)(W + (size_t)(kt*64+row)*512 + nt*64 + col);
    tile[row][col]=v.x; tile[row][col+1]=v.y; tile[row][col+2]=v.z; tile[row][col+3]=v.w;
  }
  __syncthreads();
  #pragma unroll
  for(int i=0;i<4;i++){
    int n = (t>>4) + i*16; int ck = (t&15)*4;
    s16x4 o;
    #pragma unroll
    for(int j=0;j<4;j++) o[j] = (short)f2b(tile[ck+j][n]);
    *(s16x4*)(WT + (size_t)(nt*64+n)*512 + kt*64 + ck) = o;
  }
}

// ---------------- W_out transpose -> bf16 hi/lo [c][k] ----------------
__global__ __launch_bounds__(256) void k_two(const float* __restrict__ W,
    unsigned short* __restrict__ WTh, unsigned short* __restrict__ WTl){
  int bx = blockIdx.x; int kt = bx>>3, nt = bx&7;
  __shared__ float tile[64][65];
  int t = threadIdx.x;
  #pragma unroll
  for(int i=0;i<4;i++){
    int row = (t>>4) + i*16; int col = (t&15)*4;
    float4 v = *(const float4*)(W + (size_t)(kt*64+row)*512 + nt*64 + col);
    tile[row][col]=v.x; tile[row][col+1]=v.y; tile[row][col+2]=v.z; tile[row][col+3]=v.w;
  }
  __syncthreads();
  #pragma unroll
  for(int i=0;i<4;i++){
    int n = (t>>4) + i*16; int ck = (t&15)*4;
    s16x4 oh_, ol_;
    #pragma unroll
    for(int j=0;j<4;j++){
      float x = tile[ck+j][n];
      unsigned short hi = f2b(x);
      oh_[j] = (short)hi;
      ol_[j] = (short)f2b(x - b2f(hi));
    }
    *(s16x4*)(WTh + (size_t)(nt*64+n)*512 + kt*64 + ck) = oh_;
    *(s16x4*)(WTl + (size_t)(nt*64+n)*512 + kt*64 + ck) = ol_;
  }
}

// ---------------- LayerNorm -> bf16 (4 rows / block) ----------------
__global__ __launch_bounds__(256) void k_ln(const float* __restrict__ q,
    const float* __restrict__ k, const float* __restrict__ v,
    const float* __restrict__ g, const float* __restrict__ b,
    unsigned short* __restrict__ xnb){
  int row = blockIdx.x*4 + (threadIdx.x>>6); int t = threadIdx.x & 63;
  const float* src = (row < 8192) ? q : ((row < 16384) ? k : v);
  int r = row & 8191;
  const float4* sp = (const float4*)(src + (size_t)r*512);
  float4 v1 = sp[t*2], v2 = sp[t*2+1];
  float s  = v1.x+v1.y+v1.z+v1.w + v2.x+v2.y+v2.z+v2.w;
  float ss = v1.x*v1.x+v1.y*v1.y+v1.z*v1.z+v1.w*v1.w
           + v2.x*v2.x+v2.y*v2.y+v2.z*v2.z+v2.w*v2.w;
  s = wred64(s); ss = wred64(ss);
  float mu = s*(1.f/512.f);
  float var = ss*(1.f/512.f) - mu*mu;
  float rstd = rsqrtf(var + 1e-5f);
  const float4* gp = (const float4*)g; const float4* bp = (const float4*)b;
  float4 g1 = gp[t*2], g2 = gp[t*2+1], b1 = bp[t*2], b2 = bp[t*2+1];
  s16x8 o;
  o[0]=(short)f2b((v1.x-mu)*rstd*g1.x+b1.x); o[1]=(short)f2b((v1.y-mu)*rstd*g1.y+b1.y);
  o[2]=(short)f2b((v1.z-mu)*rstd*g1.z+b1.z); o[3]=(short)f2b((v1.w-mu)*rstd*g1.w+b1.w);
  o[4]=(short)f2b((v2.x-mu)*rstd*g2.x+b2.x); o[5]=(short)f2b((v2.y-mu)*rstd*g2.y+b2.y);
  o[6]=(short)f2b((v2.z-mu)*rstd*g2.z+b2.z); o[7]=(short)f2b((v2.w-mu)*rstd*g2.w+b2.w);
  *(s16x8*)(xnb + (size_t)row*512 + t*8) = o;
}

// ---------------- proj GEMM bf16 MFMA ----------------
__global__ __launch_bounds__(256) void k_mm1(const unsigned short* __restrict__ xnb,
    const unsigned short* __restrict__ WT,
    unsigned short* __restrict__ fqb, unsigned short* __restrict__ fkb,
    unsigned short* __restrict__ fvb){
  __shared__ __align__(16) unsigned short As[128*64];
  __shared__ __align__(16) unsigned short Bs[128*64];
  int t = threadIdx.x; int w = t>>6; int l = t&63; int g = l>>4, lc = l&15;
  int Rb = blockIdx.x*128, cb = blockIdx.y*128;
  int wr = (w>>1)*64, wc = (w&1)*64;
  f32x4 acc[4][4];
  #pragma unroll
  for(int i=0;i<4;i++)
    #pragma unroll
    for(int j=0;j<4;j++) acc[i][j] = (f32x4){0.f,0.f,0.f,0.f};
  for(int k0=0; k0<512; k0+=64){
    __syncthreads();
    #pragma unroll
    for(int i=0;i<4;i++){
      int c = t + i*256; int row = c>>3, k8 = c&7;
      s16x8 va = *(const s16x8*)(xnb + (size_t)(Rb+row)*512 + k0 + k8*8);
      *(s16x8*)((char*)As + row*128 + ((k8*16) ^ ((row&7)<<4))) = va;
      s16x8 vb = *(const s16x8*)(WT + (size_t)(cb+row)*512 + k0 + k8*8);
      *(s16x8*)((char*)Bs + row*128 + ((k8*16) ^ ((row&7)<<4))) = vb;
    }
    __syncthreads();
    #pragma unroll
    for(int ks=0; ks<2; ks++){
      bf16x8 ar[4], br[4];
      #pragma unroll
      for(int rt=0; rt<4; rt++){
        int row = wr + rt*16 + lc;
        ar[rt] = *(const bf16x8*)((const char*)As + row*128 + (((ks*4+g)*16) ^ ((row&7)<<4)));
      }
      #pragma unroll
      for(int ct=0; ct<4; ct++){
        int row = wc + ct*16 + lc;
        br[ct] = *(const bf16x8*)((const char*)Bs + row*128 + (((ks*4+g)*16) ^ ((row&7)<<4)));
      }
      #pragma unroll
      for(int rt=0; rt<4; rt++)
        #pragma unroll
        for(int ct=0; ct<4; ct++)
          acc[rt][ct] = mfma16(ar[rt], br[ct], acc[rt][ct]);
    }
  }
  #pragma unroll
  for(int rt=0; rt<4; rt++){
    #pragma unroll
    for(int r=0; r<4; r++){
      int R = Rb + wr + rt*16 + g*4 + r;
      int tsel = R>>13; int rr = R&8191;
      unsigned short* dst = (tsel==0)?fqb:((tsel==1)?fkb:fvb);
      #pragma unroll
      for(int ct=0; ct<4; ct++){
        int c = cb + wc + ct*16 + lc;
        dst[(size_t)rr*512 + c] = f2b(acc[rt][ct][r]);
      }
    }
  }
}

// ---------------- column stats: mkb, smk, featd ----------------
__global__ __launch_bounds__(1024) void k_colstats(const unsigned short* __restrict__ fqb,
    const unsigned short* __restrict__ fkb,
    float* __restrict__ mkb, float* __restrict__ smk, double* featd){
  int hq = blockIdx.x; int h = hq>>4, q = hq&15;
  int t = threadIdx.x; int d = t&63; int g = t>>6;  // 16 n-groups
  __shared__ float cq[16][64], ck[16][64];
  float aq=0.f, ak=0.f;
  for(int n=g; n<512; n+=16){
    size_t base = (size_t)(q*512+n)*512 + h*64 + d;
    aq += b2f(fqb[base]);
    ak += b2f(fkb[base]);
  }
  cq[g][d]=aq; ck[g][d]=ak;
  __syncthreads();
  if(t<64){
    float sq=0.f, sk2=0.f;
    #pragma unroll
    for(int i=0;i<16;i++){ sq+=cq[i][t]; sk2+=ck[i][t]; }
    atomicAdd(&featd[h*128+t], (double)sq);
    atomicAdd(&featd[h*128+64+t], (double)sk2);
    float mk = sk2*(1.f/512.f);
    mkb[hq*64+t]=mk;
    cq[0][t]=mk;
  }
  __syncthreads();
  if(t<64){
    float s = wred64(cq[0][t]);
    if(t==0) smk[hq]=s;
  }
}

// ---------------- row stats: one thread per row ----------------
__global__ __launch_bounds__(256) void k_rowstats(const unsigned short* __restrict__ fqb,
    const unsigned short* __restrict__ fkb, const float* __restrict__ mkb,
    float* __restrict__ ri1, float* __restrict__ rmx1, float* __restrict__ mq,
    float* __restrict__ qdm, float* __restrict__ ri2, float* __restrict__ rmx2,
    float* __restrict__ sk){
  int b = blockIdx.x; int hq = b>>1; int h = hq>>4, q = hq&15;
  int n = (b&1)*256 + threadIdx.x;
  __shared__ float mk[64];
  if(threadIdx.x<64) mk[threadIdx.x] = mkb[hq*64+threadIdx.x];
  __syncthreads();
  const unsigned short* fr = fqb + (size_t)(q*512+n)*512 + h*64;
  const unsigned short* kr = fkb + (size_t)(q*512+n)*512 + h*64;
  float sq=0.f, ssq=0.f, dq=0.f, sks=0.f, ssk=0.f;
  #pragma unroll
  for(int j=0;j<8;j++){
    s16x8 vq = *(const s16x8*)(fr + j*8);
    s16x8 vk = *(const s16x8*)(kr + j*8);
    #pragma unroll
    for(int e=0;e<8;e++){
      float a = b2f((unsigned short)vq[e]);
      float c = b2f((unsigned short)vk[e]);
      sq += a; ssq += a*a; dq += a*mk[j*8+e];
      sks += c; ssk += c*c;
    }
  }
  int idx = hq*512 + n;
  float nq = sqrtf(ssq);
  ri1[idx]  = 1.f/(nq+1e-6f);
  rmx1[idx] = 1.f/fmaxf(nq,1e-6f);
  mq[idx]   = sq*(1.f/64.f);
  qdm[idx]  = dq;
  float nk = sqrtf(ssk);
  ri2[idx]  = 1.f/(nk+1e-6f);
  rmx2[idx] = 1.f/fmaxf(nk,1e-6f);
  sk[idx]   = sks;
}

// ---------------- fv transpose -> fvT[hq][d][n] bf16 ----------------
__global__ __launch_bounds__(256) void k_vt(const unsigned short* __restrict__ fvb,
    unsigned short* __restrict__ fvT){
  int bx = blockIdx.x; int hq = bx>>2, nc = bx&3;
  int h = hq>>4, q = hq&15; int n0 = nc*128;
  __shared__ float tile[128][65];
  int t = threadIdx.x;
  #pragma unroll
  for(int i=0;i<4;i++){
    int c = t + i*256; int row = c>>3, k8 = c&7;
    s16x8 v = *(const s16x8*)(fvb + (size_t)(q*512 + n0 + row)*512 + h*64 + k8*8);
    #pragma unroll
    for(int j=0;j<8;j++) tile[row][k8*8+j] = b2f((unsigned short)v[j]);
  }
  __syncthreads();
  #pragma unroll
  for(int i=0;i<4;i++){
    int c = t + i*256; int d = c>>4, n8 = c&15;
    s16x8 o;
    #pragma unroll
    for(int j=0;j<8;j++) o[j] = (short)f2b(tile[n8*8+j][d]);
    *(s16x8*)(fvT + (size_t)(hq*64 + d)*512 + n0 + n8*8) = o;
  }
}

// ---------------- component sums pass (MFMA QK) ----------------
__global__ __launch_bounds__(256) void k_comp(const unsigned short* __restrict__ fqb,
    const unsigned short* __restrict__ fkb,
    const float* __restrict__ ri1, const float* __restrict__ rmx1,
    const float* __restrict__ mq, const float* __restrict__ qdm,
    const float* __restrict__ ri2, const float* __restrict__ rmx2,
    const float* __restrict__ sk, const float* __restrict__ smk,
    float* __restrict__ mxcg, float* __restrict__ mxvg, double* headsum){
  int bx = blockIdx.x; int hq = bx>>3; int rt = bx&7;
  int h = hq>>4, q = hq&15; int n0 = rt*64;
  __shared__ __align__(16) unsigned short Qs[64*64];
  __shared__ __align__(16) unsigned short Ks[128*64];
  __shared__ float ri2f[512], rmx2f[512], skf[512];
  __shared__ float red[4][9];
  int t = threadIdx.x; int w = t>>6; int l = t&63; int g = l>>4, lc = l&15;
  for(int i=t; i<512; i+=256){
    ri2f[i]=ri2[hq*NS+i]; rmx2f[i]=rmx2[hq*NS+i]; skf[i]=sk[hq*NS+i];
  }
  #pragma unroll
  for(int i=0;i<2;i++){
    int c = t + i*256; int row = c>>3, k8 = c&7;
    s16x8 v = *(const s16x8*)(fqb + (size_t)(q*512 + n0 + row)*512 + h*64 + k8*8);
    *(s16x8*)((char*)Qs + row*128 + ((k8*16) ^ ((row&7)<<4))) = v;
  }
  float ri1r[4], rmx1r[4], mqr[4], qdmr[4];
  #pragma unroll
  for(int r=0;r<4;r++){
    int n = hq*NS + n0 + w*16 + g*4 + r;
    ri1r[r]=ri1[n]; rmx1r[r]=rmx1[n]; mqr[r]=mq[n]; qdmr[r]=qdm[n];
  }
  float smkv = smk[hq];
  __syncthreads();
  bf16x8 aq[2];
  #pragma unroll
  for(int ks=0;ks<2;ks++){
    int row = 16*w + lc;
    aq[ks] = *(const bf16x8*)((const char*)Qs + row*128 + (((ks*4+g)*16) ^ ((row&7)<<4)));
  }
  float p0=0,p1=0,p2=0,p3=0,p4=0;
  float rm_m[4]={0,0,0,0}, rm_c[4]={0,0,0,0}, rm_v[4]={0,0,0,0};
  float mxc[4]={-1e30f,-1e30f,-1e30f,-1e30f}, mxv[4]={-1e30f,-1e30f,-1e30f,-1e30f};
  for(int mc=0; mc<4; mc++){
    __syncthreads();
    #pragma unroll
    for(int i=0;i<4;i++){
      int c = t + i*256; int row = c>>3, k8 = c&7;
      s16x8 v = *(const s16x8*)(fkb + (size_t)(q*512 + mc*128 + row)*512 + h*64 + k8*8);
      *(s16x8*)((char*)Ks + row*128 + ((k8*16) ^ ((row&7)<<4))) = v;
    }
    __syncthreads();
    #pragma unroll 2
    for(int mt=0; mt<8; mt++){
      f32x4 dacc = (f32x4){0.f,0.f,0.f,0.f};
      #pragma unroll
      for(int ks=0;ks<2;ks++){
        int row = mt*16 + lc;
        bf16x8 bk = *(const bf16x8*)((const char*)Ks + row*128 + (((ks*4+g)*16) ^ ((row&7)<<4)));
        dacc = mfma16(aq[ks], bk, dacc);
      }
      int m = mc*128 + mt*16 + lc;
      float r2 = ri2f[m], rx2 = rmx2f[m], skc = skf[m];
      #pragma unroll
      for(int r=0;r<4;r++){
        float dv = dacc[r];
        float cosv = fminf(fmaxf(dv*ri1r[r]*r2, -0.9f), 0.9f);
        float inner = dv - qdmr[r] - mqr[r]*skc + mqr[r]*smkv;
        float covv = fminf(fmaxf(CS2*inner, -10.f), 10.f);
        float csv = fminf(fmaxf(dv*rmx1r[r]*rx2, -0.9f), 0.9f);
        float marg = fminf(fmaxf(0.01f - csv, 0.f), 5.f);
        p0 += cosv; p1 += cosv*cosv; p2 += covv; p3 += covv*covv; p4 += cosv*covv;
        rm_m[r]+=marg; rm_c[r]+=cosv; rm_v[r]+=covv;
        mxc[r]=fmaxf(mxc[r],cosv); mxv[r]=fmaxf(mxv[r],covv);
      }
    }
  }
  #pragma unroll
  for(int off=1; off<16; off<<=1){
    #pragma unroll
    for(int r=0;r<4;r++){
      rm_m[r]+=__shfl_xor(rm_m[r],off,64);
      rm_c[r]+=__shfl_xor(rm_c[r],off,64);
      rm_v[r]+=__shfl_xor(rm_v[r],off,64);
      mxc[r]=fmaxf(mxc[r],__shfl_xor(mxc[r],off,64));
      mxv[r]=fmaxf(mxv[r],__shfl_xor(mxv[r],off,64));
    }
  }
  float q0=0,q1=0,q2=0,q3=0;
  if(lc==0){
    #pragma unroll
    for(int r=0;r<4;r++){
      float vmv = rm_m[r]*(1.f/512.f);
      q0+=vmv; q1+=vmv*vmv; q2+=vmv*rm_c[r]; q3+=vmv*rm_v[r];
      int n = n0 + w*16 + g*4 + r;
      mxcg[hq*NS+n]=mxc[r]; mxvg[hq*NS+n]=mxv[r];
    }
  }
  float all9[9] = {p0,p1,p2,p3,p4,q0,q1,q2,q3};
  #pragma unroll
  for(int j=0;j<9;j++){
    float vv = wred64(all9[j]);
    if(l==0) red[w][j]=vv;
  }
  __syncthreads();
  if(t<9){
    double s = (double)red[0][t]+(double)red[1][t]+(double)red[2][t]+(double)red[3][t];
    atomicAdd(&headsum[h*9+t], s);
  }
}

// ---------------- finalize: fully parallel (1024 threads, all heads at once) ----------------
__global__ __launch_bounds__(1024) void k_finalize(const double* headsum, const double* featd,
    const float* __restrict__ w1, const float* __restrict__ b1,
    const float* __restrict__ lng, const float* __restrict__ lnb,
    const float* __restrict__ w2, const float* __restrict__ b2,
    const float* __restrict__ w3, const float* __restrict__ b3,
    const float* __restrict__ wtemp, float* coef){
  __shared__ float featS[8][128];
  __shared__ float x1S[8][128];
  __shared__ float x2S[8][64];
  __shared__ float redS[8][4];
  __shared__ float oS[8][3];
  __shared__ float whS[8][3];
  int t = threadIdx.x;
  int h = t>>7, j = t&127;
  featS[h][j] = (float)(featd[t] * (1.0/8192.0));
  __syncthreads();
  // fc1: one thread per (h, j)
  float a = 0.f;
  #pragma unroll 16
  for(int i=0;i<128;i++) a += featS[h][i]*w1[(size_t)i*128+j];
  a += b1[j];
  // LN over j within head: wave reduce + 2-wave combine
  {
    float s = a, ss = a*a;
    #pragma unroll
    for(int m=32;m>0;m>>=1){ s += __shfl_xor(s,m,64); ss += __shfl_xor(ss,m,64); }
    int wv = (t>>6)&1;
    if((t&63)==0){ redS[h][wv*2]=s; redS[h][wv*2+1]=ss; }
  }
  __syncthreads();
  {
    float sum = redS[h][0]+redS[h][2], sumsq = redS[h][1]+redS[h][3];
    float mu = sum*(1.f/128.f);
    float var = sumsq*(1.f/128.f)-mu*mu;
    float rstd = rsqrtf(var+1e-5f);
    x1S[h][j] = fmaxf((a-mu)*rstd*lng[j]+lnb[j], 0.f);
  }
  __syncthreads();
  if(t < 512){
    int h2 = t>>6, j2 = t&63;
    float s2 = 0.f;
    #pragma unroll 16
    for(int i=0;i<128;i++) s2 += x1S[h2][i]*w2[(size_t)i*64+j2];
    x2S[h2][j2] = fmaxf(s2+b2[j2], 0.f);
  }
  __syncthreads();
  if(t < 24){
    int h3 = t/3, j3 = t-h3*3;
    float s3=0.f;
    #pragma unroll 16
    for(int i=0;i<64;i++) s3 += x2S[h3][i]*w3[i*3+j3];
    oS[h3][j3] = s3 + b3[j3];
  }
  __syncthreads();
  if(t < 8){
    float o0=oS[t][0], o1=oS[t][1], o2=oS[t][2];
    float mx=fmaxf(o0,fmaxf(o1,o2));
    float e0=expf(o0-mx), e1=expf(o1-mx), e2=expf(o2-mx), se=e0+e1+e2;
    float l0=e0/se, l1=e1/se, l2=e2/se;
    float wt=fminf(fmaxf(wtemp[0],0.1f),2.0f);
    l0/=wt; l1/=wt; l2/=wt;
    mx=fmaxf(l0,fmaxf(l1,l2));
    e0=expf(l0-mx); e1=expf(l1-mx); e2=expf(l2-mx); se=e0+e1+e2;
    float u0=fminf(fmaxf(e0/se,0.05f),0.8f);
    float u1=fminf(fmaxf(e1/se,0.05f),0.8f);
    float u2=fminf(fmaxf(e2/se,0.05f),0.8f);
    float su=u0+u1+u2;
    whS[t][0]=u0/su; whS[t][1]=u1/su; whS[t][2]=u2/su;
  }
  __syncthreads();
  if(t==0){
    const double N = 33554432.0;
    double gs[9];
    for(int jj=0;jj<9;jj++){ double s=0; for(int hh=0;hh<8;hh++) s+=headsum[hh*9+jj]; gs[jj]=s; }
    auto sd = [&](double s, double ss)->double{
      double v=(ss - s*s/N)/(N-1.0); return v>0.0 ? sqrt(v) : 0.0;
    };
    double std_cos = sd(gs[0],gs[1]);
    double std_cov = sd(gs[2],gs[3]);
    double std_vm  = sd(512.0*gs[5], 512.0*gs[6]);
    double sdot=0.0, sdot2=0.0;
    double Af[8], Bf[8];
    for(int hh=0;hh<8;hh++){
      const double* hs = headsum + hh*9;
      double A = (double)whS[hh][0]/(std_cos+1e-6);
      double B = (double)whS[hh][1]/(std_cov+1e-6)*0.5;
      double C = (double)whS[hh][2]/(std_vm +1e-6)*0.5;
      sdot  += A*hs[0] + B*hs[2] + C*512.0*hs[5];
      sdot2 += A*A*hs[1] + B*B*hs[3] + C*C*512.0*hs[6]
             + 2.0*A*B*hs[4] + 2.0*A*C*hs[7] + 2.0*B*C*hs[8];
      Af[hh]=A; Bf[hh]=B;
    }
    double dstd = sd(sdot, sdot2);
    double temp = dstd < 1e-4 ? 0.1 : (dstd < 0.01 ? 0.3 : 0.5 + dstd);
    temp = fmin(fmax(temp, 0.1), 3.0);
    for(int hh=0;hh<8;hh++){
      coef[hh]   = (float)(Af[hh]/temp);
      coef[8+hh] = (float)(Bf[hh]/temp);
    }
    coef[16] = (float)temp;
  }
}

// ---------------- flash softmax + PV (MFMA), oh -> bf16 hi/lo ----------------
__global__ __launch_bounds__(256) void k_flash(const unsigned short* __restrict__ fqb,
    const unsigned short* __restrict__ fkb, const unsigned short* __restrict__ fvT,
    const float* __restrict__ ri1, const float* __restrict__ mq,
    const float* __restrict__ qdm, const float* __restrict__ ri2,
    const float* __restrict__ sk, const float* __restrict__ smk,
    const float* __restrict__ mxcg, const float* __restrict__ mxvg,
    const float* __restrict__ coef,
    unsigned short* __restrict__ ohh, unsigned short* __restrict__ ohl){
  int bx = blockIdx.x; int hq = bx>>3; int rt = bx&7;
  int h = hq>>4, q = hq&15; int n0 = rt*64;
  __shared__ __align__(16) unsigned short Qs[64*64];
  __shared__ __align__(16) unsigned short Ks[128*64];
  __shared__ __align__(16) unsigned short Vt[64*128];
  __shared__ __align__(16) unsigned short Ps[4][16*40];
  __shared__ float ri2f[512], skf[512];
  int t = threadIdx.x; int w = t>>6; int l = t&63; int g = l>>4, lc = l&15;
  for(int i=t; i<512; i+=256){ ri2f[i]=ri2[hq*NS+i]; skf[i]=sk[hq*NS+i]; }
  #pragma unroll
  for(int i=0;i<2;i++){
    int c = t + i*256; int row = c>>3, k8 = c&7;
    s16x8 v = *(const s16x8*)(fqb + (size_t)(q*512 + n0 + row)*512 + h*64 + k8*8);
    *(s16x8*)((char*)Qs + row*128 + ((k8*16) ^ ((row&7)<<4))) = v;
  }
  float Ah = coef[h], Bh = coef[8+h];
  float ri1r[4], mqr[4], qdmr[4], Mr[4];
  #pragma unroll
  for(int r=0;r<4;r++){
    int n = hq*NS + n0 + w*16 + g*4 + r;
    ri1r[r]=ri1[n]; mqr[r]=mq[n]; qdmr[r]=qdm[n];
    Mr[r] = Ah*mxcg[n] + Bh*mxvg[n];
  }
  float smkv = smk[hq];
  __syncthreads();
  bf16x8 aq[2];
  #pragma unroll
  for(int ks=0;ks<2;ks++){
    int row = 16*w + lc;
    aq[ks] = *(const bf16x8*)((const char*)Qs + row*128 + (((ks*4+g)*16) ^ ((row&7)<<4)));
  }
  f32x4 acc[4];
  #pragma unroll
  for(int dt=0;dt<4;dt++) acc[dt] = (f32x4){0.f,0.f,0.f,0.f};
  float lsum[4]={0.f,0.f,0.f,0.f};
  unsigned short* Pw = &Ps[w][0];
  for(int mc=0; mc<4; mc++){
    __syncthreads();
    #pragma unroll
    for(int i=0;i<4;i++){
      int c = t + i*256; int row = c>>3, k8 = c&7;
      s16x8 v = *(const s16x8*)(fkb + (size_t)(q*512 + mc*128 + row)*512 + h*64 + k8*8);
      *(s16x8*)((char*)Ks + row*128 + ((k8*16) ^ ((row&7)<<4))) = v;
    }
    #pragma unroll
    for(int i=0;i<4;i++){
      int c = t + i*256; int d = c>>4, m8 = c&15;
      s16x8 v = *(const s16x8*)(fvT + (size_t)(hq*64 + d)*512 + mc*128 + m8*8);
      *(s16x8*)((char*)Vt + d*256 + ((m8*16) ^ ((d&7)<<4))) = v;
    }
    __syncthreads();
    #pragma unroll 1
    for(int mt2=0; mt2<4; mt2++){
      #pragma unroll
      for(int half=0; half<2; half++){
        int mt = mt2*2 + half;
        f32x4 dacc = (f32x4){0.f,0.f,0.f,0.f};
        #pragma unroll
        for(int ks=0;ks<2;ks++){
          int row = mt*16 + lc;
          bf16x8 bk = *(const bf16x8*)((const char*)Ks + row*128 + (((ks*4+g)*16) ^ ((row&7)<<4)));
          dacc = mfma16(aq[ks], bk, dacc);
        }
        int m = mc*128 + mt*16 + lc;
        float r2 = ri2f[m], skc = skf[m];
        #pragma unroll
        for(int r=0;r<4;r++){
          float dv = dacc[r];
          float cosv = fminf(fmaxf(dv*ri1r[r]*r2, -0.9f), 0.9f);
          float inner = dv - qdmr[r] - mqr[r]*skc + mqr[r]*smkv;
          float covv = fminf(fmaxf(CS2*inner, -10.f), 10.f);
          float sv = Ah*cosv + Bh*covv;
          float pe = __expf(fmaxf(sv - Mr[r], -60.f));
          lsum[r] += pe;
          Pw[(g*4+r)*40 + lc + half*16] = f2b(pe);
        }
      }
      asm volatile("s_waitcnt lgkmcnt(0)" ::: "memory");
      bf16x8 ap = *(const bf16x8*)((const char*)Pw + lc*80 + g*16);
      #pragma unroll
      for(int dt=0;dt<4;dt++){
        int drow = dt*16 + lc;
        bf16x8 bv = *(const bf16x8*)((const char*)Vt + drow*256 + (((mt2*4+g)*16) ^ ((drow&7)<<4)));
        acc[dt] = mfma16(ap, bv, acc[dt]);
      }
    }
  }
  #pragma unroll
  for(int off=1; off<16; off<<=1){
    #pragma unroll
    for(int r=0;r<4;r++) lsum[r] += __shfl_xor(lsum[r], off, 64);
  }
  #pragma unroll
  for(int r=0;r<4;r++){
    float inv = 1.f/lsum[r];
    int n = n0 + w*16 + g*4 + r;
    #pragma unroll
    for(int dt=0;dt<4;dt++){
      size_t idx = (size_t)(q*512 + n)*512 + h*64 + dt*16 + lc;
      float val = acc[dt][r]*inv;
      unsigned short hi = f2b(val);
      ohh[idx] = hi;
      ohl[idx] = f2b(val - b2f(hi));
    }
  }
}

// ---------------- output GEMM: split-bf16 3-term MFMA + bias ----------------
__global__ __launch_bounds__(256) void k_gout2(const unsigned short* __restrict__ Ahp,
    const unsigned short* __restrict__ Alp,
    const unsigned short* __restrict__ Bhp, const unsigned short* __restrict__ Blp,
    const float* __restrict__ bias, float* __restrict__ Cout){
  __shared__ __align__(16) unsigned short AsH[128*64];
  __shared__ __align__(16) unsigned short AsL[128*64];
  __shared__ __align__(16) unsigned short BsH[128*64];
  __shared__ __align__(16) unsigned short BsL[128*64];
  int t = threadIdx.x; int w = t>>6; int l = t&63; int g = l>>4, lc = l&15;
  int Rb = blockIdx.x*128, cb = blockIdx.y*128;
  int wr = (w>>1)*64, wc = (w&1)*64;
  f32x4 acc[4][4];
  #pragma unroll
  for(int i=0;i<4;i++)
    #pragma unroll
    for(int j=0;j<4;j++) acc[i][j] = (f32x4){0.f,0.f,0.f,0.f};
  for(int k0=0; k0<512; k0+=64){
    __syncthreads();
    #pragma unroll
    for(int i=0;i<4;i++){
      int c = t + i*256; int row = c>>3, k8 = c&7;
      int sw = (k8*16) ^ ((row&7)<<4);
      *(s16x8*)((char*)AsH + row*128 + sw) = *(const s16x8*)(Ahp + (size_t)(Rb+row)*512 + k0 + k8*8);
      *(s16x8*)((char*)AsL + row*128 + sw) = *(const s16x8*)(Alp + (size_t)(Rb+row)*512 + k0 + k8*8);
      *(s16x8*)((char*)BsH + row*128 + sw) = *(const s16x8*)(Bhp + (size_t)(cb+row)*512 + k0 + k8*8);
      *(s16x8*)((char*)BsL + row*128 + sw) = *(const s16x8*)(Blp + (size_t)(cb+row)*512 + k0 + k8*8);
    }
    __syncthreads();
    #pragma unroll
    for(int ks=0; ks<2; ks++){
      bf16x8 arh[4], arl[4], brh[4], brl[4];
      #pragma unroll
      for(int rt=0; rt<4; rt++){
        int row = wr + rt*16 + lc;
        int off = row*128 + (((ks*4+g)*16) ^ ((row&7)<<4));
        arh[rt] = *(const bf16x8*)((const char*)AsH + off);
        arl[rt] = *(const bf16x8*)((const char*)AsL + off);
      }
      #pragma unroll
      for(int ct=0; ct<4; ct++){
        int row = wc + ct*16 + lc;
        int off = row*128 + (((ks*4+g)*16) ^ ((row&7)<<4));
        brh[ct] = *(const bf16x8*)((const char*)BsH + off);
        brl[ct] = *(const bf16x8*)((const char*)BsL + off);
      }
      #pragma unroll
      for(int rt=0; rt<4; rt++)
        #pragma unroll
        for(int ct=0; ct<4; ct++){
          acc[rt][ct] = mfma16(arh[rt], brh[ct], acc[rt][ct]);
          acc[rt][ct] = mfma16(arh[rt], brl[ct], acc[rt][ct]);
          acc[rt][ct] = mfma16(arl[rt], brh[ct], acc[rt][ct]);
        }
    }
  }
  #pragma unroll
  for(int rt=0; rt<4; rt++){
    #pragma unroll
    for(int r=0; r<4; r++){
      int R = Rb + wr + rt*16 + g*4 + r;
      #pragma unroll
      for(int ct=0; ct<4; ct++){
        int c = cb + wc + ct*16 + lc;
        Cout[(size_t)R*512 + c] = acc[rt][ct][r] + bias[c];
      }
    }
  }
}

extern "C" void kernel_launch(void* const* d_in, const int* in_sizes, int n_in,
                              void* d_out, int out_size, void* d_ws, size_t ws_size,
                              hipStream_t stream){
  const float* q    = (const float*)d_in[0];
  const float* k    = (const float*)d_in[1];
  const float* v    = (const float*)d_in[2];
  const float* ln1g = (const float*)d_in[3];
  const float* ln1b = (const float*)d_in[4];
  const float* Win  = (const float*)d_in[5];
  const float* w1   = (const float*)d_in[6];
  const float* b1   = (const float*)d_in[7];
  const float* lng  = (const float*)d_in[8];
  const float* lnb  = (const float*)d_in[9];
  const float* w2   = (const float*)d_in[10];
  const float* b2   = (const float*)d_in[11];
  const float* w3   = (const float*)d_in[12];
  const float* b3   = (const float*)d_in[13];
  const float* wtemp= (const float*)d_in[14];
  const float* Wout = (const float*)d_in[15];
  const float* bout = (const float*)d_in[16];

  float* w = (float*)d_ws;
  unsigned short* xnb = (unsigned short*)(w + OFF_XNB);
  unsigned short* fqb = (unsigned short*)(w + OFF_FQB);
  unsigned short* fkb = (unsigned short*)(w + OFF_FKB);
  unsigned short* fvb = (unsigned short*)(w + OFF_FVB);
  unsigned short* fvT = (unsigned short*)(w + OFF_FVT);
  unsigned short* wtb = (unsigned short*)(w + OFF_WT);
  unsigned short* woh = (unsigned short*)(w + OFF_WOH);
  unsigned short* wol = (unsigned short*)(w + OFF_WOL);
  unsigned short* ohh = (unsigned short*)(w + OFF_OHH);
  unsigned short* ohl = (unsigned short*)(w + OFF_OHL);
  float* ri1  = w + OFF_ARR + 0*65536;
  float* rmx1 = w + OFF_ARR + 1*65536;
  float* mq_  = w + OFF_ARR + 2*65536;
  float* qdm  = w + OFF_ARR + 3*65536;
  float* ri2  = w + OFF_ARR + 4*65536;
  float* rmx2 = w + OFF_ARR + 5*65536;
  float* sk_  = w + OFF_ARR + 6*65536;
  float* mxc  = w + OFF_ARR + 7*65536;
  float* mxv  = w + OFF_ARR + 8*65536;
  float* mkb  = w + OFF_MKB;
  float* smk_ = w + OFF_SMK;
  float* coef = w + OFF_COEF;
  double* dbl = (double*)(w + OFF_DBL);
  double* headsum = dbl;
  double* featd   = dbl + 72;

  hipMemsetAsync(dbl, 0, NDBL*sizeof(double), stream);
  k_tw<<<64, 256, 0, stream>>>(Win, wtb);
  k_two<<<64, 256, 0, stream>>>(Wout, woh, wol);
  k_ln<<<6144, 256, 0, stream>>>(q, k, v, ln1g, ln1b, xnb);
  k_mm1<<<dim3(192,4), 256, 0, stream>>>(xnb, wtb, fqb, fkb, fvb);
  k_colstats<<<128, 1024, 0, stream>>>(fqb, fkb, mkb, smk_, featd);
  k_rowstats<<<256, 256, 0, stream>>>(fqb, fkb, mkb, ri1, rmx1, mq_, qdm, ri2, rmx2, sk_);
  k_vt<<<512, 256, 0, stream>>>(fvb, fvT);
  k_comp<<<1024, 256, 0, stream>>>(fqb, fkb, ri1, rmx1, mq_, qdm, ri2, rmx2, sk_, smk_, mxc, mxv, headsum);
  k_finalize<<<1, 1024, 0, stream>>>(headsum, featd, w1, b1, lng, lnb, w2, b2, w3, b3, wtemp, coef);
  k_flash<<<1024, 256, 0, stream>>>(fqb, fkb, fvT, ri1, mq_, qdm, ri2, sk_, smk_, mxc, mxv, coef, ohh, ohl);
  k_gout2<<<dim3(64,4), 256, 0, stream>>>(ohh, ohl, woh, wol, bout, (float*)d_out);
}

// Round 5
// 174.272 us; speedup vs baseline: 4.6197x; 1.0269x over previous
//
#include <hip/hip_runtime.h>
#include <math.h>

#define H 8
#define NS 512
#define D 64

typedef __bf16 bf16x8 __attribute__((ext_vector_type(8)));
typedef float f32x4 __attribute__((ext_vector_type(4)));
typedef short s16x8 __attribute__((ext_vector_type(8)));
typedef short s16x4 __attribute__((ext_vector_type(4)));

#define CS2 ((1e-3f/512.f)/(8.f+1e-6f))

static __device__ __forceinline__ f32x4 mfma16(bf16x8 a, bf16x8 b, f32x4 c){
  return __builtin_amdgcn_mfma_f32_16x16x32_bf16(a,b,c,0,0,0);
}
static __device__ __forceinline__ float b2f(unsigned short s){
  union { unsigned u; float f; } v; v.u = ((unsigned)s)<<16; return v.f;
}
static __device__ __forceinline__ unsigned short f2b(float f){
  union { float f; unsigned u; } v; v.f = f;
  unsigned r = v.u + 0x7FFFu + ((v.u>>16)&1u);
  return (unsigned short)(r>>16);
}
static __device__ __forceinline__ float wred64(float v){
  #pragma unroll
  for(int m=32; m>0; m>>=1) v += __shfl_xor(v, m, 64);
  return v;
}

// ---- workspace layout (float element offsets) ----
constexpr size_t OFF_XNB = 0;                       // 24576x512 bf16
constexpr size_t OFF_FQB = 6291456;                 // 8192x512 bf16
constexpr size_t OFF_FKB = 8388608;
constexpr size_t OFF_FVB = 10485760;
constexpr size_t OFF_FVT = 12582912;                // [128][64][512] bf16
constexpr size_t OFF_WT  = 14680064;                // 512x512 bf16 (WinT)
constexpr size_t OFF_WOH = 14811136;                // 512x512 bf16 WoutT hi
constexpr size_t OFF_WOL = 14942208;                // 512x512 bf16 WoutT lo
constexpr size_t OFF_OHH = 15073280;                // 8192x512 bf16 oh hi
constexpr size_t OFF_OHL = 17170432;                // 8192x512 bf16 oh lo
constexpr size_t OFF_ARR = 19267584;                // arrays x 65536 f32
constexpr size_t OFF_MKB = OFF_ARR + 9*65536;       // [128][64]
constexpr size_t OFF_SMK = OFF_MKB + 8192;
constexpr size_t OFF_COEF= OFF_SMK + 128;
constexpr size_t OFF_DBL = OFF_COEF + 32;           // 8B aligned (even)
constexpr size_t NDBL    = 72 + 1024;               // headsum[8][9], featd[8][128]

// ---------------- W_in transpose -> bf16 [n][k]; block 0 also zeroes accumulators ----------------
__global__ __launch_bounds__(256) void k_tw(const float* __restrict__ W, unsigned short* __restrict__ WT,
    double* __restrict__ dbl){
  int bx = blockIdx.x; int kt = bx>>3, nt = bx&7;
  int t = threadIdx.x;
  if(bx==0){
    for(int i=t;i<(int)NDBL;i+=256) dbl[i]=0.0;
  }
  __shared__ float tile[64][65];
  #pragma unroll
  for(int i=0;i<4;i++){
    int row = (t>>4) + i*16; int col = (t&15)*4;
    float4 v = *(const float4*)(W + (size_t)(kt*64+row)*512 + nt*64 + col);
    tile[row][col]=v.x; tile[row][col+1]=v.y; tile[row][col+2]=v.z; tile[row][col+3]=v.w;
  }
  __syncthreads();
  #pragma unroll
  for(int i=0;i<4;i++){
    int n = (t>>4) + i*16; int ck = (t&15)*4;
    s16x4 o;
    #pragma unroll
    for(int j=0;j<4;j++) o[j] = (short)f2b(tile[ck+j][n]);
    *(s16x4*)(WT + (size_t)(nt*64+n)*512 + kt*64 + ck) = o;
  }
}

// ---------------- W_out transpose -> bf16 hi/lo [c][k] ----------------
__global__ __launch_bounds__(256) void k_two(const float* __restrict__ W,
    unsigned short* __restrict__ WTh, unsigned short* __restrict__ WTl){
  int bx = blockIdx.x; int kt = bx>>3, nt = bx&7;
  __shared__ float tile[64][65];
  int t = threadIdx.x;
  #pragma unroll
  for(int i=0;i<4;i++){
    int row = (t>>4) + i*16; int col = (t&15)*4;
    float4 v = *(const float4*)(W + (size_t)(kt*64+row)*512 + nt*64 + col);
    tile[row][col]=v.x; tile[row][col+1]=v.y; tile[row][col+2]=v.z; tile[row][col+3]=v.w;
  }
  __syncthreads();
  #pragma unroll
  for(int i=0;i<4;i++){
    int n = (t>>4) + i*16; int ck = (t&15)*4;
    s16x4 oh_, ol_;
    #pragma unroll
    for(int j=0;j<4;j++){
      float x = tile[ck+j][n];
      unsigned short hi = f2b(x);
      oh_[j] = (short)hi;
      ol_[j] = (short)f2b(x - b2f(hi));
    }
    *(s16x4*)(WTh + (size_t)(nt*64+n)*512 + kt*64 + ck) = oh_;
    *(s16x4*)(WTl + (size_t)(nt*64+n)*512 + kt*64 + ck) = ol_;
  }
}

// ---------------- LayerNorm -> bf16 (4 rows / block) ----------------
__global__ __launch_bounds__(256) void k_ln(const float* __restrict__ q,
    const float* __restrict__ k, const float* __restrict__ v,
    const float* __restrict__ g, const float* __restrict__ b,
    unsigned short* __restrict__ xnb){
  int row = blockIdx.x*4 + (threadIdx.x>>6); int t = threadIdx.x & 63;
  const float* src = (row < 8192) ? q : ((row < 16384) ? k : v);
  int r = row & 8191;
  const float4* sp = (const float4*)(src + (size_t)r*512);
  float4 v1 = sp[t*2], v2 = sp[t*2+1];
  float s  = v1.x+v1.y+v1.z+v1.w + v2.x+v2.y+v2.z+v2.w;
  float ss = v1.x*v1.x+v1.y*v1.y+v1.z*v1.z+v1.w*v1.w
           + v2.x*v2.x+v2.y*v2.y+v2.z*v2.z+v2.w*v2.w;
  s = wred64(s); ss = wred64(ss);
  float mu = s*(1.f/512.f);
  float var = ss*(1.f/512.f) - mu*mu;
  float rstd = rsqrtf(var + 1e-5f);
  const float4* gp = (const float4*)g; const float4* bp = (const float4*)b;
  float4 g1 = gp[t*2], g2 = gp[t*2+1], b1 = bp[t*2], b2 = bp[t*2+1];
  s16x8 o;
  o[0]=(short)f2b((v1.x-mu)*rstd*g1.x+b1.x); o[1]=(short)f2b((v1.y-mu)*rstd*g1.y+b1.y);
  o[2]=(short)f2b((v1.z-mu)*rstd*g1.z+b1.z); o[3]=(short)f2b((v1.w-mu)*rstd*g1.w+b1.w);
  o[4]=(short)f2b((v2.x-mu)*rstd*g2.x+b2.x); o[5]=(short)f2b((v2.y-mu)*rstd*g2.y+b2.y);
  o[6]=(short)f2b((v2.z-mu)*rstd*g2.z+b2.z); o[7]=(short)f2b((v2.w-mu)*rstd*g2.w+b2.w);
  *(s16x8*)(xnb + (size_t)row*512 + t*8) = o;
}

// ---------------- proj GEMM bf16 MFMA ----------------
__global__ __launch_bounds__(256) void k_mm1(const unsigned short* __restrict__ xnb,
    const unsigned short* __restrict__ WT,
    unsigned short* __restrict__ fqb, unsigned short* __restrict__ fkb,
    unsigned short* __restrict__ fvb){
  __shared__ __align__(16) unsigned short As[128*64];
  __shared__ __align__(16) unsigned short Bs[128*64];
  int t = threadIdx.x; int w = t>>6; int l = t&63; int g = l>>4, lc = l&15;
  int Rb = blockIdx.x*128, cb = blockIdx.y*128;
  int wr = (w>>1)*64, wc = (w&1)*64;
  f32x4 acc[4][4];
  #pragma unroll
  for(int i=0;i<4;i++)
    #pragma unroll
    for(int j=0;j<4;j++) acc[i][j] = (f32x4){0.f,0.f,0.f,0.f};
  for(int k0=0; k0<512; k0+=64){
    __syncthreads();
    #pragma unroll
    for(int i=0;i<4;i++){
      int c = t + i*256; int row = c>>3, k8 = c&7;
      s16x8 va = *(const s16x8*)(xnb + (size_t)(Rb+row)*512 + k0 + k8*8);
      *(s16x8*)((char*)As + row*128 + ((k8*16) ^ ((row&7)<<4))) = va;
      s16x8 vb = *(const s16x8*)(WT + (size_t)(cb+row)*512 + k0 + k8*8);
      *(s16x8*)((char*)Bs + row*128 + ((k8*16) ^ ((row&7)<<4))) = vb;
    }
    __syncthreads();
    #pragma unroll
    for(int ks=0; ks<2; ks++){
      bf16x8 ar[4], br[4];
      #pragma unroll
      for(int rt=0; rt<4; rt++){
        int row = wr + rt*16 + lc;
        ar[rt] = *(const bf16x8*)((const char*)As + row*128 + (((ks*4+g)*16) ^ ((row&7)<<4)));
      }
      #pragma unroll
      for(int ct=0; ct<4; ct++){
        int row = wc + ct*16 + lc;
        br[ct] = *(const bf16x8*)((const char*)Bs + row*128 + (((ks*4+g)*16) ^ ((row&7)<<4)));
      }
      #pragma unroll
      for(int rt=0; rt<4; rt++)
        #pragma unroll
        for(int ct=0; ct<4; ct++)
          acc[rt][ct] = mfma16(ar[rt], br[ct], acc[rt][ct]);
    }
  }
  #pragma unroll
  for(int rt=0; rt<4; rt++){
    #pragma unroll
    for(int r=0; r<4; r++){
      int R = Rb + wr + rt*16 + g*4 + r;
      int tsel = R>>13; int rr = R&8191;
      unsigned short* dst = (tsel==0)?fqb:((tsel==1)?fkb:fvb);
      #pragma unroll
      for(int ct=0; ct<4; ct++){
        int c = cb + wc + ct*16 + lc;
        dst[(size_t)rr*512 + c] = f2b(acc[rt][ct][r]);
      }
    }
  }
}

// ---------------- column stats: mkb, smk, featd ----------------
__global__ __launch_bounds__(1024) void k_colstats(const unsigned short* __restrict__ fqb,
    const unsigned short* __restrict__ fkb,
    float* __restrict__ mkb, float* __restrict__ smk, double* featd){
  int hq = blockIdx.x; int h = hq>>4, q = hq&15;
  int t = threadIdx.x; int d = t&63; int g = t>>6;  // 16 n-groups
  __shared__ float cq[16][64], ck[16][64];
  float aq=0.f, ak=0.f;
  for(int n=g; n<512; n+=16){
    size_t base = (size_t)(q*512+n)*512 + h*64 + d;
    aq += b2f(fqb[base]);
    ak += b2f(fkb[base]);
  }
  cq[g][d]=aq; ck[g][d]=ak;
  __syncthreads();
  if(t<64){
    float sq=0.f, sk2=0.f;
    #pragma unroll
    for(int i=0;i<16;i++){ sq+=cq[i][t]; sk2+=ck[i][t]; }
    atomicAdd(&featd[h*128+t], (double)sq);
    atomicAdd(&featd[h*128+64+t], (double)sk2);
    float mk = sk2*(1.f/512.f);
    mkb[hq*64+t]=mk;
    cq[0][t]=mk;
  }
  __syncthreads();
  if(t<64){
    float s = wred64(cq[0][t]);
    if(t==0) smk[hq]=s;
  }
}

// ---------------- row stats: one thread per row ----------------
__global__ __launch_bounds__(256) void k_rowstats(const unsigned short* __restrict__ fqb,
    const unsigned short* __restrict__ fkb, const float* __restrict__ mkb,
    float* __restrict__ ri1, float* __restrict__ mq,
    float* __restrict__ qdm, float* __restrict__ ri2,
    float* __restrict__ sk){
  int b = blockIdx.x; int hq = b>>1; int h = hq>>4, q = hq&15;
  int n = (b&1)*256 + threadIdx.x;
  __shared__ float mk[64];
  if(threadIdx.x<64) mk[threadIdx.x] = mkb[hq*64+threadIdx.x];
  __syncthreads();
  const unsigned short* fr = fqb + (size_t)(q*512+n)*512 + h*64;
  const unsigned short* kr = fkb + (size_t)(q*512+n)*512 + h*64;
  float sq=0.f, ssq=0.f, dq=0.f, sks=0.f, ssk=0.f;
  #pragma unroll
  for(int j=0;j<8;j++){
    s16x8 vq = *(const s16x8*)(fr + j*8);
    s16x8 vk = *(const s16x8*)(kr + j*8);
    #pragma unroll
    for(int e=0;e<8;e++){
      float a = b2f((unsigned short)vq[e]);
      float c = b2f((unsigned short)vk[e]);
      sq += a; ssq += a*a; dq += a*mk[j*8+e];
      sks += c; ssk += c*c;
    }
  }
  int idx = hq*512 + n;
  float nq = sqrtf(ssq);
  ri1[idx]  = 1.f/(nq+1e-6f);
  mq[idx]   = sq*(1.f/64.f);
  qdm[idx]  = dq;
  float nk = sqrtf(ssk);
  ri2[idx]  = 1.f/(nk+1e-6f);
  sk[idx]   = sks;
}

// ---------------- fv transpose -> fvT[hq][d][n] bf16 ----------------
__global__ __launch_bounds__(256) void k_vt(const unsigned short* __restrict__ fvb,
    unsigned short* __restrict__ fvT){
  int bx = blockIdx.x; int hq = bx>>2, nc = bx&3;
  int h = hq>>4, q = hq&15; int n0 = nc*128;
  __shared__ float tile[128][65];
  int t = threadIdx.x;
  #pragma unroll
  for(int i=0;i<4;i++){
    int c = t + i*256; int row = c>>3, k8 = c&7;
    s16x8 v = *(const s16x8*)(fvb + (size_t)(q*512 + n0 + row)*512 + h*64 + k8*8);
    #pragma unroll
    for(int j=0;j<8;j++) tile[row][k8*8+j] = b2f((unsigned short)v[j]);
  }
  __syncthreads();
  #pragma unroll
  for(int i=0;i<4;i++){
    int c = t + i*256; int d = c>>4, n8 = c&15;
    s16x8 o;
    #pragma unroll
    for(int j=0;j<8;j++) o[j] = (short)f2b(tile[n8*8+j][d]);
    *(s16x8*)(fvT + (size_t)(hq*64 + d)*512 + n0 + n8*8) = o;
  }
}

// ---------------- component sums pass (MFMA QK) ----------------
__global__ __launch_bounds__(256) void k_comp(const unsigned short* __restrict__ fqb,
    const unsigned short* __restrict__ fkb,
    const float* __restrict__ ri1,
    const float* __restrict__ mq, const float* __restrict__ qdm,
    const float* __restrict__ ri2,
    const float* __restrict__ sk, const float* __restrict__ smk,
    float* __restrict__ mxcg, float* __restrict__ mxvg, double* headsum){
  int bx = blockIdx.x; int hq = bx>>3; int rt = bx&7;
  int h = hq>>4, q = hq&15; int n0 = rt*64;
  __shared__ __align__(16) unsigned short Qs[64*64];
  __shared__ __align__(16) unsigned short Ks[128*64];
  __shared__ float ri2f[512], skf[512];
  __shared__ float red[4][9];
  int t = threadIdx.x; int w = t>>6; int l = t&63; int g = l>>4, lc = l&15;
  for(int i=t; i<512; i+=256){
    ri2f[i]=ri2[hq*NS+i]; skf[i]=sk[hq*NS+i];
  }
  #pragma unroll
  for(int i=0;i<2;i++){
    int c = t + i*256; int row = c>>3, k8 = c&7;
    s16x8 v = *(const s16x8*)(fqb + (size_t)(q*512 + n0 + row)*512 + h*64 + k8*8);
    *(s16x8*)((char*)Qs + row*128 + ((k8*16) ^ ((row&7)<<4))) = v;
  }
  float ri1r[4], mqr[4], qdmr[4];
  #pragma unroll
  for(int r=0;r<4;r++){
    int n = hq*NS + n0 + w*16 + g*4 + r;
    ri1r[r]=ri1[n]; mqr[r]=mq[n]; qdmr[r]=qdm[n];
  }
  float smkv = smk[hq];
  __syncthreads();
  bf16x8 aq[2];
  #pragma unroll
  for(int ks=0;ks<2;ks++){
    int row = 16*w + lc;
    aq[ks] = *(const bf16x8*)((const char*)Qs + row*128 + (((ks*4+g)*16) ^ ((row&7)<<4)));
  }
  float p0=0,p1=0,p2=0,p3=0,p4=0;
  float rm_m[4]={0,0,0,0}, rm_c[4]={0,0,0,0}, rm_v[4]={0,0,0,0};
  float mxc[4]={-1e30f,-1e30f,-1e30f,-1e30f}, mxv[4]={-1e30f,-1e30f,-1e30f,-1e30f};
  for(int mc=0; mc<4; mc++){
    __syncthreads();
    #pragma unroll
    for(int i=0;i<4;i++){
      int c = t + i*256; int row = c>>3, k8 = c&7;
      s16x8 v = *(const s16x8*)(fkb + (size_t)(q*512 + mc*128 + row)*512 + h*64 + k8*8);
      *(s16x8*)((char*)Ks + row*128 + ((k8*16) ^ ((row&7)<<4))) = v;
    }
    __syncthreads();
    #pragma unroll 2
    for(int mt=0; mt<8; mt++){
      f32x4 dacc = (f32x4){0.f,0.f,0.f,0.f};
      #pragma unroll
      for(int ks=0;ks<2;ks++){
        int row = mt*16 + lc;
        bf16x8 bk = *(const bf16x8*)((const char*)Ks + row*128 + (((ks*4+g)*16) ^ ((row&7)<<4)));
        dacc = mfma16(aq[ks], bk, dacc);
      }
      int m = mc*128 + mt*16 + lc;
      float r2 = ri2f[m], skc = skf[m];
      #pragma unroll
      for(int r=0;r<4;r++){
        float dv = dacc[r];
        float cosv = fminf(fmaxf(dv*ri1r[r]*r2, -0.9f), 0.9f);
        float inner = dv - qdmr[r] - mqr[r]*skc + mqr[r]*smkv;
        float covv = fminf(fmaxf(CS2*inner, -10.f), 10.f);
        float marg = fmaxf(0.01f - cosv, 0.f);
        p0 += cosv; p1 += cosv*cosv; p2 += covv; p3 += covv*covv; p4 += cosv*covv;
        rm_m[r]+=marg; rm_c[r]+=cosv; rm_v[r]+=covv;
        mxc[r]=fmaxf(mxc[r],cosv); mxv[r]=fmaxf(mxv[r],covv);
      }
    }
  }
  #pragma unroll
  for(int off=1; off<16; off<<=1){
    #pragma unroll
    for(int r=0;r<4;r++){
      rm_m[r]+=__shfl_xor(rm_m[r],off,64);
      rm_c[r]+=__shfl_xor(rm_c[r],off,64);
      rm_v[r]+=__shfl_xor(rm_v[r],off,64);
      mxc[r]=fmaxf(mxc[r],__shfl_xor(mxc[r],off,64));
      mxv[r]=fmaxf(mxv[r],__shfl_xor(mxv[r],off,64));
    }
  }
  float q0=0,q1=0,q2=0,q3=0;
  if(lc==0){
    #pragma unroll
    for(int r=0;r<4;r++){
      float vmv = rm_m[r]*(1.f/512.f);
      q0+=vmv; q1+=vmv*vmv; q2+=vmv*rm_c[r]; q3+=vmv*rm_v[r];
      int n = n0 + w*16 + g*4 + r;
      mxcg[hq*NS+n]=mxc[r]; mxvg[hq*NS+n]=mxv[r];
    }
  }
  float all9[9] = {p0,p1,p2,p3,p4,q0,q1,q2,q3};
  #pragma unroll
  for(int j=0;j<9;j++){
    float vv = wred64(all9[j]);
    if(l==0) red[w][j]=vv;
  }
  __syncthreads();
  if(t<9){
    double s = (double)red[0][t]+(double)red[1][t]+(double)red[2][t]+(double)red[3][t];
    atomicAdd(&headsum[h*9+t], s);
  }
}

// ---------------- finalize: fully parallel (1024 threads, all heads at once) ----------------
__global__ __launch_bounds__(1024) void k_finalize(const double* headsum, const double* featd,
    const float* __restrict__ w1, const float* __restrict__ b1,
    const float* __restrict__ lng, const float* __restrict__ lnb,
    const float* __restrict__ w2, const float* __restrict__ b2,
    const float* __restrict__ w3, const float* __restrict__ b3,
    const float* __restrict__ wtemp, float* coef){
  __shared__ float featS[8][128];
  __shared__ float x1S[8][128];
  __shared__ float x2S[8][64];
  __shared__ float redS[8][4];
  __shared__ float oS[8][3];
  __shared__ float whS[8][3];
  int t = threadIdx.x;
  int h = t>>7, j = t&127;
  featS[h][j] = (float)(featd[t] * (1.0/8192.0));
  __syncthreads();
  float a = 0.f;
  #pragma unroll 16
  for(int i=0;i<128;i++) a += featS[h][i]*w1[(size_t)i*128+j];
  a += b1[j];
  {
    float s = a, ss = a*a;
    #pragma unroll
    for(int m=32;m>0;m>>=1){ s += __shfl_xor(s,m,64); ss += __shfl_xor(ss,m,64); }
    int wv = (t>>6)&1;
    if((t&63)==0){ redS[h][wv*2]=s; redS[h][wv*2+1]=ss; }
  }
  __syncthreads();
  {
    float sum = redS[h][0]+redS[h][2], sumsq = redS[h][1]+redS[h][3];
    float mu = sum*(1.f/128.f);
    float var = sumsq*(1.f/128.f)-mu*mu;
    float rstd = rsqrtf(var+1e-5f);
    x1S[h][j] = fmaxf((a-mu)*rstd*lng[j]+lnb[j], 0.f);
  }
  __syncthreads();
  if(t < 512){
    int h2 = t>>6, j2 = t&63;
    float s2 = 0.f;
    #pragma unroll 16
    for(int i=0;i<128;i++) s2 += x1S[h2][i]*w2[(size_t)i*64+j2];
    x2S[h2][j2] = fmaxf(s2+b2[j2], 0.f);
  }
  __syncthreads();
  if(t < 24){
    int h3 = t/3, j3 = t-h3*3;
    float s3=0.f;
    #pragma unroll 16
    for(int i=0;i<64;i++) s3 += x2S[h3][i]*w3[i*3+j3];
    oS[h3][j3] = s3 + b3[j3];
  }
  __syncthreads();
  if(t < 8){
    float o0=oS[t][0], o1=oS[t][1], o2=oS[t][2];
    float mx=fmaxf(o0,fmaxf(o1,o2));
    float e0=expf(o0-mx), e1=expf(o1-mx), e2=expf(o2-mx), se=e0+e1+e2;
    float l0=e0/se, l1=e1/se, l2=e2/se;
    float wt=fminf(fmaxf(wtemp[0],0.1f),2.0f);
    l0/=wt; l1/=wt; l2/=wt;
    mx=fmaxf(l0,fmaxf(l1,l2));
    e0=expf(l0-mx); e1=expf(l1-mx); e2=expf(l2-mx); se=e0+e1+e2;
    float u0=fminf(fmaxf(e0/se,0.05f),0.8f);
    float u1=fminf(fmaxf(e1/se,0.05f),0.8f);
    float u2=fminf(fmaxf(e2/se,0.05f),0.8f);
    float su=u0+u1+u2;
    whS[t][0]=u0/su; whS[t][1]=u1/su; whS[t][2]=u2/su;
  }
  __syncthreads();
  if(t==0){
    const double N = 33554432.0;
    double gs[9];
    for(int jj=0;jj<9;jj++){ double s=0; for(int hh=0;hh<8;hh++) s+=headsum[hh*9+jj]; gs[jj]=s; }
    auto sd = [&](double s, double ss)->double{
      double v=(ss - s*s/N)/(N-1.0); return v>0.0 ? sqrt(v) : 0.0;
    };
    double std_cos = sd(gs[0],gs[1]);
    double std_cov = sd(gs[2],gs[3]);
    double std_vm  = sd(512.0*gs[5], 512.0*gs[6]);
    double sdot=0.0, sdot2=0.0;
    double Af[8], Bf[8];
    for(int hh=0;hh<8;hh++){
      const double* hs = headsum + hh*9;
      double A = (double)whS[hh][0]/(std_cos+1e-6);
      double B = (double)whS[hh][1]/(std_cov+1e-6)*0.5;
      double C = (double)whS[hh][2]/(std_vm +1e-6)*0.5;
      sdot  += A*hs[0] + B*hs[2] + C*512.0*hs[5];
      sdot2 += A*A*hs[1] + B*B*hs[3] + C*C*512.0*hs[6]
             + 2.0*A*B*hs[4] + 2.0*A*C*hs[7] + 2.0*B*C*hs[8];
      Af[hh]=A; Bf[hh]=B;
    }
    double dstd = sd(sdot, sdot2);
    double temp = dstd < 1e-4 ? 0.1 : (dstd < 0.01 ? 0.3 : 0.5 + dstd);
    temp = fmin(fmax(temp, 0.1), 3.0);
    for(int hh=0;hh<8;hh++){
      coef[hh]   = (float)(Af[hh]/temp);
      coef[8+hh] = (float)(Bf[hh]/temp);
    }
    coef[16] = (float)temp;
  }
}

// ---------------- flash softmax + PV (MFMA), oh -> bf16 hi/lo ----------------
__global__ __launch_bounds__(256) void k_flash(const unsigned short* __restrict__ fqb,
    const unsigned short* __restrict__ fkb, const unsigned short* __restrict__ fvT,
    const float* __restrict__ ri1, const float* __restrict__ mq,
    const float* __restrict__ qdm, const float* __restrict__ ri2,
    const float* __restrict__ sk, const float* __restrict__ smk,
    const float* __restrict__ mxcg, const float* __restrict__ mxvg,
    const float* __restrict__ coef,
    unsigned short* __restrict__ ohh, unsigned short* __restrict__ ohl){
  int bx = blockIdx.x; int hq = bx>>3; int rt = bx&7;
  int h = hq>>4, q = hq&15; int n0 = rt*64;
  __shared__ __align__(16) unsigned short Qs[64*64];
  __shared__ __align__(16) unsigned short Ks[128*64];
  __shared__ __align__(16) unsigned short Vt[64*128];
  __shared__ __align__(16) unsigned short Ps[4][16*40];
  __shared__ float ri2f[512], skf[512];
  int t = threadIdx.x; int w = t>>6; int l = t&63; int g = l>>4, lc = l&15;
  for(int i=t; i<512; i+=256){ ri2f[i]=ri2[hq*NS+i]; skf[i]=sk[hq*NS+i]; }
  #pragma unroll
  for(int i=0;i<2;i++){
    int c = t + i*256; int row = c>>3, k8 = c&7;
    s16x8 v = *(const s16x8*)(fqb + (size_t)(q*512 + n0 + row)*512 + h*64 + k8*8);
    *(s16x8*)((char*)Qs + row*128 + ((k8*16) ^ ((row&7)<<4))) = v;
  }
  float Ah = coef[h], Bh = coef[8+h];
  float ri1r[4], mqr[4], qdmr[4], Mr[4];
  #pragma unroll
  for(int r=0;r<4;r++){
    int n = hq*NS + n0 + w*16 + g*4 + r;
    ri1r[r]=ri1[n]; mqr[r]=mq[n]; qdmr[r]=qdm[n];
    Mr[r] = Ah*mxcg[n] + Bh*mxvg[n];
  }
  float smkv = smk[hq];
  __syncthreads();
  bf16x8 aq[2];
  #pragma unroll
  for(int ks=0;ks<2;ks++){
    int row = 16*w + lc;
    aq[ks] = *(const bf16x8*)((const char*)Qs + row*128 + (((ks*4+g)*16) ^ ((row&7)<<4)));
  }
  f32x4 acc[4];
  #pragma unroll
  for(int dt=0;dt<4;dt++) acc[dt] = (f32x4){0.f,0.f,0.f,0.f};
  float lsum[4]={0.f,0.f,0.f,0.f};
  unsigned short* Pw = &Ps[w][0];
  for(int mc=0; mc<4; mc++){
    __syncthreads();
    #pragma unroll
    for(int i=0;i<4;i++){
      int c = t + i*256; int row = c>>3, k8 = c&7;
      s16x8 v = *(const s16x8*)(fkb + (size_t)(q*512 + mc*128 + row)*512 + h*64 + k8*8);
      *(s16x8*)((char*)Ks + row*128 + ((k8*16) ^ ((row&7)<<4))) = v;
    }
    #pragma unroll
    for(int i=0;i<4;i++){
      int c = t + i*256; int d = c>>4, m8 = c&15;
      s16x8 v = *(const s16x8*)(fvT + (size_t)(hq*64 + d)*512 + mc*128 + m8*8);
      *(s16x8*)((char*)Vt + d*256 + ((m8*16) ^ ((d&7)<<4))) = v;
    }
    __syncthreads();
    #pragma unroll 1
    for(int mt2=0; mt2<4; mt2++){
      #pragma unroll
      for(int half=0; half<2; half++){
        int mt = mt2*2 + half;
        f32x4 dacc = (f32x4){0.f,0.f,0.f,0.f};
        #pragma unroll
        for(int ks=0;ks<2;ks++){
          int row = mt*16 + lc;
          bf16x8 bk = *(const bf16x8*)((const char*)Ks + row*128 + (((ks*4+g)*16) ^ ((row&7)<<4)));
          dacc = mfma16(aq[ks], bk, dacc);
        }
        int m = mc*128 + mt*16 + lc;
        float r2 = ri2f[m], skc = skf[m];
        #pragma unroll
        for(int r=0;r<4;r++){
          float dv = dacc[r];
          float cosv = fminf(fmaxf(dv*ri1r[r]*r2, -0.9f), 0.9f);
          float inner = dv - qdmr[r] - mqr[r]*skc + mqr[r]*smkv;
          float covv = fminf(fmaxf(CS2*inner, -10.f), 10.f);
          float sv = Ah*cosv + Bh*covv;
          float pe = __expf(fmaxf(sv - Mr[r], -60.f));
          lsum[r] += pe;
          Pw[(g*4+r)*40 + lc + half*16] = f2b(pe);
        }
      }
      asm volatile("s_waitcnt lgkmcnt(0)" ::: "memory");
      bf16x8 ap = *(const bf16x8*)((const char*)Pw + lc*80 + g*16);
      #pragma unroll
      for(int dt=0;dt<4;dt++){
        int drow = dt*16 + lc;
        bf16x8 bv = *(const bf16x8*)((const char*)Vt + drow*256 + (((mt2*4+g)*16) ^ ((drow&7)<<4)));
        acc[dt] = mfma16(ap, bv, acc[dt]);
      }
    }
  }
  #pragma unroll
  for(int off=1; off<16; off<<=1){
    #pragma unroll
    for(int r=0;r<4;r++) lsum[r] += __shfl_xor(lsum[r], off, 64);
  }
  #pragma unroll
  for(int r=0;r<4;r++){
    float inv = 1.f/lsum[r];
    int n = n0 + w*16 + g*4 + r;
    #pragma unroll
    for(int dt=0;dt<4;dt++){
      size_t idx = (size_t)(q*512 + n)*512 + h*64 + dt*16 + lc;
      float val = acc[dt][r]*inv;
      unsigned short hi = f2b(val);
      ohh[idx] = hi;
      ohl[idx] = f2b(val - b2f(hi));
    }
  }
}

// ---------------- output GEMM: split-bf16 3-term MFMA + bias ----------------
__global__ __launch_bounds__(256) void k_gout2(const unsigned short* __restrict__ Ahp,
    const unsigned short* __restrict__ Alp,
    const unsigned short* __restrict__ Bhp, const unsigned short* __restrict__ Blp,
    const float* __restrict__ bias, float* __restrict__ Cout){
  __shared__ __align__(16) unsigned short AsH[128*64];
  __shared__ __align__(16) unsigned short AsL[128*64];
  __shared__ __align__(16) unsigned short BsH[128*64];
  __shared__ __align__(16) unsigned short BsL[128*64];
  int t = threadIdx.x; int w = t>>6; int l = t&63; int g = l>>4, lc = l&15;
  int Rb = blockIdx.x*128, cb = blockIdx.y*128;
  int wr = (w>>1)*64, wc = (w&1)*64;
  f32x4 acc[4][4];
  #pragma unroll
  for(int i=0;i<4;i++)
    #pragma unroll
    for(int j=0;j<4;j++) acc[i][j] = (f32x4){0.f,0.f,0.f,0.f};
  for(int k0=0; k0<512; k0+=64){
    __syncthreads();
    #pragma unroll
    for(int i=0;i<4;i++){
      int c = t + i*256; int row = c>>3, k8 = c&7;
      int sw = (k8*16) ^ ((row&7)<<4);
      *(s16x8*)((char*)AsH + row*128 + sw) = *(const s16x8*)(Ahp + (size_t)(Rb+row)*512 + k0 + k8*8);
      *(s16x8*)((char*)AsL + row*128 + sw) = *(const s16x8*)(Alp + (size_t)(Rb+row)*512 + k0 + k8*8);
      *(s16x8*)((char*)BsH + row*128 + sw) = *(const s16x8*)(Bhp + (size_t)(cb+row)*512 + k0 + k8*8);
      *(s16x8*)((char*)BsL + row*128 + sw) = *(const s16x8*)(Blp + (size_t)(cb+row)*512 + k0 + k8*8);
    }
    __syncthreads();
    #pragma unroll
    for(int ks=0; ks<2; ks++){
      bf16x8 arh[4], arl[4], brh[4], brl[4];
      #pragma unroll
      for(int rt=0; rt<4; rt++){
        int row = wr + rt*16 + lc;
        int off = row*128 + (((ks*4+g)*16) ^ ((row&7)<<4));
        arh[rt] = *(const bf16x8*)((const char*)AsH + off);
        arl[rt] = *(const bf16x8*)((const char*)AsL + off);
      }
      #pragma unroll
      for(int ct=0; ct<4; ct++){
        int row = wc + ct*16 + lc;
        int off = row*128 + (((ks*4+g)*16) ^ ((row&7)<<4));
        brh[ct] = *(const bf16x8*)((const char*)BsH + off);
        brl[ct] = *(const bf16x8*)((const char*)BsL + off);
      }
      #pragma unroll
      for(int rt=0; rt<4; rt++)
        #pragma unroll
        for(int ct=0; ct<4; ct++){
          acc[rt][ct] = mfma16(arh[rt], brh[ct], acc[rt][ct]);
          acc[rt][ct] = mfma16(arh[rt], brl[ct], acc[rt][ct]);
          acc[rt][ct] = mfma16(arl[rt], brh[ct], acc[rt][ct]);
        }
    }
  }
  #pragma unroll
  for(int rt=0; rt<4; rt++){
    #pragma unroll
    for(int r=0; r<4; r++){
      int R = Rb + wr + rt*16 + g*4 + r;
      #pragma unroll
      for(int ct=0; ct<4; ct++){
        int c = cb + wc + ct*16 + lc;
        Cout[(size_t)R*512 + c] = acc[rt][ct][r] + bias[c];
      }
    }
  }
}

extern "C" void kernel_launch(void* const* d_in, const int* in_sizes, int n_in,
                              void* d_out, int out_size, void* d_ws, size_t ws_size,
                              hipStream_t stream){
  const float* q    = (const float*)d_in[0];
  const float* k    = (const float*)d_in[1];
  const float* v    = (const float*)d_in[2];
  const float* ln1g = (const float*)d_in[3];
  const float* ln1b = (const float*)d_in[4];
  const float* Win  = (const float*)d_in[5];
  const float* w1   = (const float*)d_in[6];
  const float* b1   = (const float*)d_in[7];
  const float* lng  = (const float*)d_in[8];
  const float* lnb  = (const float*)d_in[9];
  const float* w2   = (const float*)d_in[10];
  const float* b2   = (const float*)d_in[11];
  const float* w3   = (const float*)d_in[12];
  const float* b3   = (const float*)d_in[13];
  const float* wtemp= (const float*)d_in[14];
  const float* Wout = (const float*)d_in[15];
  const float* bout = (const float*)d_in[16];

  float* w = (float*)d_ws;
  unsigned short* xnb = (unsigned short*)(w + OFF_XNB);
  unsigned short* fqb = (unsigned short*)(w + OFF_FQB);
  unsigned short* fkb = (unsigned short*)(w + OFF_FKB);
  unsigned short* fvb = (unsigned short*)(w + OFF_FVB);
  unsigned short* fvT = (unsigned short*)(w + OFF_FVT);
  unsigned short* wtb = (unsigned short*)(w + OFF_WT);
  unsigned short* woh = (unsigned short*)(w + OFF_WOH);
  unsigned short* wol = (unsigned short*)(w + OFF_WOL);
  unsigned short* ohh = (unsigned short*)(w + OFF_OHH);
  unsigned short* ohl = (unsigned short*)(w + OFF_OHL);
  float* ri1  = w + OFF_ARR + 0*65536;
  float* mq_  = w + OFF_ARR + 2*65536;
  float* qdm  = w + OFF_ARR + 3*65536;
  float* ri2  = w + OFF_ARR + 4*65536;
  float* sk_  = w + OFF_ARR + 6*65536;
  float* mxc  = w + OFF_ARR + 7*65536;
  float* mxv  = w + OFF_ARR + 8*65536;
  float* mkb  = w + OFF_MKB;
  float* smk_ = w + OFF_SMK;
  float* coef = w + OFF_COEF;
  double* dbl = (double*)(w + OFF_DBL);
  double* headsum = dbl;
  double* featd   = dbl + 72;

  k_tw<<<64, 256, 0, stream>>>(Win, wtb, dbl);
  k_two<<<64, 256, 0, stream>>>(Wout, woh, wol);
  k_ln<<<6144, 256, 0, stream>>>(q, k, v, ln1g, ln1b, xnb);
  k_mm1<<<dim3(192,4), 256, 0, stream>>>(xnb, wtb, fqb, fkb, fvb);
  k_colstats<<<128, 1024, 0, stream>>>(fqb, fkb, mkb, smk_, featd);
  k_rowstats<<<256, 256, 0, stream>>>(fqb, fkb, mkb, ri1, mq_, qdm, ri2, sk_);
  k_vt<<<512, 256, 0, stream>>>(fvb, fvT);
  k_comp<<<1024, 256, 0, stream>>>(fqb, fkb, ri1, mq_, qdm, ri2, sk_, smk_, mxc, mxv, headsum);
  k_finalize<<<1, 1024, 0, stream>>>(headsum, featd, w1, b1, lng, lnb, w2, b2, w3, b3, wtemp, coef);
  k_flash<<<1024, 256, 0, stream>>>(fqb, fkb, fvT, ri1, mq_, qdm, ri2, sk_, smk_, mxc, mxv, coef, ohh, ohl);
  k_gout2<<<dim3(64,4), 256, 0, stream>>>(ohh, ohl, woh, wol, bout, (float*)d_out);
}

// Round 8
// 168.591 us; speedup vs baseline: 4.7753x; 1.0337x over previous
//
#include <hip/hip_runtime.h>
#include <math.h>

#define H 8
#define NS 512
#define D 64

typedef __bf16 bf16x8 __attribute__((ext_vector_type(8)));
typedef float f32x4 __attribute__((ext_vector_type(4)));
typedef short s16x8 __attribute__((ext_vector_type(8)));
typedef short s16x4 __attribute__((ext_vector_type(4)));

#define CS2 ((1e-3f/512.f)/(8.f+1e-6f))
#define LOG2E 1.4426950408889634

static __device__ __forceinline__ f32x4 mfma16(bf16x8 a, bf16x8 b, f32x4 c){
  return __builtin_amdgcn_mfma_f32_16x16x32_bf16(a,b,c,0,0,0);
}
static __device__ __forceinline__ float b2f(unsigned short s){
  union { unsigned u; float f; } v; v.u = ((unsigned)s)<<16; return v.f;
}
static __device__ __forceinline__ unsigned short f2b(float f){
  union { float f; unsigned u; } v; v.f = f;
  unsigned r = v.u + 0x7FFFu + ((v.u>>16)&1u);
  return (unsigned short)(r>>16);
}
static __device__ __forceinline__ float wred64(float v){
  #pragma unroll
  for(int m=32; m>0; m>>=1) v += __shfl_xor(v, m, 64);
  return v;
}

// ---- workspace layout (float element offsets) ----
constexpr size_t OFF_XNB = 0;                       // 24576x512 bf16
constexpr size_t OFF_FQB = 6291456;                 // 8192x512 bf16
constexpr size_t OFF_FKB = 8388608;
constexpr size_t OFF_FVB = 10485760;
constexpr size_t OFF_FVT = 12582912;                // [128][64][512] bf16 (m-interleaved per 32-chunk)
constexpr size_t OFF_WT  = 14680064;                // 512x512 bf16 (WinT)
constexpr size_t OFF_WOH = 14811136;                // 512x512 bf16 WoutT hi
constexpr size_t OFF_WOL = 14942208;                // 512x512 bf16 WoutT lo
constexpr size_t OFF_OHH = 15073280;                // 8192x512 bf16 oh hi
constexpr size_t OFF_OHL = 17170432;                // 8192x512 bf16 oh lo
constexpr size_t OFF_ARR = 19267584;                // arrays x 65536 f32
constexpr size_t OFF_MKB = OFF_ARR + 9*65536;       // [128][64]
constexpr size_t OFF_SMK = OFF_MKB + 8192;
constexpr size_t OFF_COEF= OFF_SMK + 128;
constexpr size_t OFF_DBL = OFF_COEF + 32;           // 8B aligned (even)
constexpr size_t NDBL    = 72 + 1024;               // headsum[8][9], featd[8][128]

// ---------------- W_in transpose -> bf16 [n][k]; block 0 also zeroes accumulators ----------------
__global__ __launch_bounds__(256) void k_tw(const float* __restrict__ W, unsigned short* __restrict__ WT,
    double* __restrict__ dbl){
  int bx = blockIdx.x; int kt = bx>>3, nt = bx&7;
  int t = threadIdx.x;
  if(bx==0){
    for(int i=t;i<(int)NDBL;i+=256) dbl[i]=0.0;
  }
  __shared__ float tile[64][65];
  #pragma unroll
  for(int i=0;i<4;i++){
    int row = (t>>4) + i*16; int col = (t&15)*4;
    float4 v = *(const float4*)(W + (size_t)(kt*64+row)*512 + nt*64 + col);
    tile[row][col]=v.x; tile[row][col+1]=v.y; tile[row][col+2]=v.z; tile[row][col+3]=v.w;
  }
  __syncthreads();
  #pragma unroll
  for(int i=0;i<4;i++){
    int n = (t>>4) + i*16; int ck = (t&15)*4;
    s16x4 o;
    #pragma unroll
    for(int j=0;j<4;j++) o[j] = (short)f2b(tile[ck+j][n]);
    *(s16x4*)(WT + (size_t)(nt*64+n)*512 + kt*64 + ck) = o;
  }
}

// ---------------- W_out transpose -> bf16 hi/lo [c][k] ----------------
__global__ __launch_bounds__(256) void k_two(const float* __restrict__ W,
    unsigned short* __restrict__ WTh, unsigned short* __restrict__ WTl){
  int bx = blockIdx.x; int kt = bx>>3, nt = bx&7;
  __shared__ float tile[64][65];
  int t = threadIdx.x;
  #pragma unroll
  for(int i=0;i<4;i++){
    int row = (t>>4) + i*16; int col = (t&15)*4;
    float4 v = *(const float4*)(W + (size_t)(kt*64+row)*512 + nt*64 + col);
    tile[row][col]=v.x; tile[row][col+1]=v.y; tile[row][col+2]=v.z; tile[row][col+3]=v.w;
  }
  __syncthreads();
  #pragma unroll
  for(int i=0;i<4;i++){
    int n = (t>>4) + i*16; int ck = (t&15)*4;
    s16x4 oh_, ol_;
    #pragma unroll
    for(int j=0;j<4;j++){
      float x = tile[ck+j][n];
      unsigned short hi = f2b(x);
      oh_[j] = (short)hi;
      ol_[j] = (short)f2b(x - b2f(hi));
    }
    *(s16x4*)(WTh + (size_t)(nt*64+n)*512 + kt*64 + ck) = oh_;
    *(s16x4*)(WTl + (size_t)(nt*64+n)*512 + kt*64 + ck) = ol_;
  }
}

// ---------------- LayerNorm -> bf16 (4 rows / block) ----------------
__global__ __launch_bounds__(256) void k_ln(const float* __restrict__ q,
    const float* __restrict__ k, const float* __restrict__ v,
    const float* __restrict__ g, const float* __restrict__ b,
    unsigned short* __restrict__ xnb){
  int row = blockIdx.x*4 + (threadIdx.x>>6); int t = threadIdx.x & 63;
  const float* src = (row < 8192) ? q : ((row < 16384) ? k : v);
  int r = row & 8191;
  const float4* sp = (const float4*)(src + (size_t)r*512);
  float4 v1 = sp[t*2], v2 = sp[t*2+1];
  float s  = v1.x+v1.y+v1.z+v1.w + v2.x+v2.y+v2.z+v2.w;
  float ss = v1.x*v1.x+v1.y*v1.y+v1.z*v1.z+v1.w*v1.w
           + v2.x*v2.x+v2.y*v2.y+v2.z*v2.z+v2.w*v2.w;
  s = wred64(s); ss = wred64(ss);
  float mu = s*(1.f/512.f);
  float var = ss*(1.f/512.f) - mu*mu;
  float rstd = rsqrtf(var + 1e-5f);
  const float4* gp = (const float4*)g; const float4* bp = (const float4*)b;
  float4 g1 = gp[t*2], g2 = gp[t*2+1], b1 = bp[t*2], b2 = bp[t*2+1];
  s16x8 o;
  o[0]=(short)f2b((v1.x-mu)*rstd*g1.x+b1.x); o[1]=(short)f2b((v1.y-mu)*rstd*g1.y+b1.y);
  o[2]=(short)f2b((v1.z-mu)*rstd*g1.z+b1.z); o[3]=(short)f2b((v1.w-mu)*rstd*g1.w+b1.w);
  o[4]=(short)f2b((v2.x-mu)*rstd*g2.x+b2.x); o[5]=(short)f2b((v2.y-mu)*rstd*g2.y+b2.y);
  o[6]=(short)f2b((v2.z-mu)*rstd*g2.z+b2.z); o[7]=(short)f2b((v2.w-mu)*rstd*g2.w+b2.w);
  *(s16x8*)(xnb + (size_t)row*512 + t*8) = o;
}

// ---------------- proj GEMM bf16 MFMA ----------------
__global__ __launch_bounds__(256) void k_mm1(const unsigned short* __restrict__ xnb,
    const unsigned short* __restrict__ WT,
    unsigned short* __restrict__ fqb, unsigned short* __restrict__ fkb,
    unsigned short* __restrict__ fvb){
  __shared__ __align__(16) unsigned short As[128*64];
  __shared__ __align__(16) unsigned short Bs[128*64];
  int t = threadIdx.x; int w = t>>6; int l = t&63; int g = l>>4, lc = l&15;
  int Rb = blockIdx.x*128, cb = blockIdx.y*128;
  int wr = (w>>1)*64, wc = (w&1)*64;
  f32x4 acc[4][4];
  #pragma unroll
  for(int i=0;i<4;i++)
    #pragma unroll
    for(int j=0;j<4;j++) acc[i][j] = (f32x4){0.f,0.f,0.f,0.f};
  for(int k0=0; k0<512; k0+=64){
    __syncthreads();
    #pragma unroll
    for(int i=0;i<4;i++){
      int c = t + i*256; int row = c>>3, k8 = c&7;
      s16x8 va = *(const s16x8*)(xnb + (size_t)(Rb+row)*512 + k0 + k8*8);
      *(s16x8*)((char*)As + row*128 + ((k8*16) ^ ((row&7)<<4))) = va;
      s16x8 vb = *(const s16x8*)(WT + (size_t)(cb+row)*512 + k0 + k8*8);
      *(s16x8*)((char*)Bs + row*128 + ((k8*16) ^ ((row&7)<<4))) = vb;
    }
    __syncthreads();
    #pragma unroll
    for(int ks=0; ks<2; ks++){
      bf16x8 ar[4], br[4];
      #pragma unroll
      for(int rt=0; rt<4; rt++){
        int row = wr + rt*16 + lc;
        ar[rt] = *(const bf16x8*)((const char*)As + row*128 + (((ks*4+g)*16) ^ ((row&7)<<4)));
      }
      #pragma unroll
      for(int ct=0; ct<4; ct++){
        int row = wc + ct*16 + lc;
        br[ct] = *(const bf16x8*)((const char*)Bs + row*128 + (((ks*4+g)*16) ^ ((row&7)<<4)));
      }
      #pragma unroll
      for(int rt=0; rt<4; rt++)
        #pragma unroll
        for(int ct=0; ct<4; ct++)
          acc[rt][ct] = mfma16(ar[rt], br[ct], acc[rt][ct]);
    }
  }
  #pragma unroll
  for(int rt=0; rt<4; rt++){
    #pragma unroll
    for(int r=0; r<4; r++){
      int R = Rb + wr + rt*16 + g*4 + r;
      int tsel = R>>13; int rr = R&8191;
      unsigned short* dst = (tsel==0)?fqb:((tsel==1)?fkb:fvb);
      #pragma unroll
      for(int ct=0; ct<4; ct++){
        int c = cb + wc + ct*16 + lc;
        dst[(size_t)rr*512 + c] = f2b(acc[rt][ct][r]);
      }
    }
  }
}

// ---------------- column stats: mkb, smk, featd ----------------
__global__ __launch_bounds__(1024) void k_colstats(const unsigned short* __restrict__ fqb,
    const unsigned short* __restrict__ fkb,
    float* __restrict__ mkb, float* __restrict__ smk, double* featd){
  int hq = blockIdx.x; int h = hq>>4, q = hq&15;
  int t = threadIdx.x; int d = t&63; int g = t>>6;  // 16 n-groups
  __shared__ float cq[16][64], ck[16][64];
  float aq=0.f, ak=0.f;
  for(int n=g; n<512; n+=16){
    size_t base = (size_t)(q*512+n)*512 + h*64 + d;
    aq += b2f(fqb[base]);
    ak += b2f(fkb[base]);
  }
  cq[g][d]=aq; ck[g][d]=ak;
  __syncthreads();
  if(t<64){
    float sq=0.f, sk2=0.f;
    #pragma unroll
    for(int i=0;i<16;i++){ sq+=cq[i][t]; sk2+=ck[i][t]; }
    atomicAdd(&featd[h*128+t], (double)sq);
    atomicAdd(&featd[h*128+64+t], (double)sk2);
    float mk = sk2*(1.f/512.f);
    mkb[hq*64+t]=mk;
    cq[0][t]=mk;
  }
  __syncthreads();
  if(t<64){
    float s = wred64(cq[0][t]);
    if(t==0) smk[hq]=s;
  }
}

// ---------------- row stats: one thread per row (sk stores skp = sk - smk) ----------------
__global__ __launch_bounds__(256) void k_rowstats(const unsigned short* __restrict__ fqb,
    const unsigned short* __restrict__ fkb, const float* __restrict__ mkb,
    const float* __restrict__ smk,
    float* __restrict__ ri1, float* __restrict__ mq,
    float* __restrict__ qdm, float* __restrict__ ri2,
    float* __restrict__ sk){
  int b = blockIdx.x; int hq = b>>1; int h = hq>>4, q = hq&15;
  int n = (b&1)*256 + threadIdx.x;
  __shared__ float mk[64];
  if(threadIdx.x<64) mk[threadIdx.x] = mkb[hq*64+threadIdx.x];
  __syncthreads();
  float smkv = smk[hq];
  const unsigned short* fr = fqb + (size_t)(q*512+n)*512 + h*64;
  const unsigned short* kr = fkb + (size_t)(q*512+n)*512 + h*64;
  float sq=0.f, ssq=0.f, dq=0.f, sks=0.f, ssk=0.f;
  #pragma unroll
  for(int j=0;j<8;j++){
    s16x8 vq = *(const s16x8*)(fr + j*8);
    s16x8 vk = *(const s16x8*)(kr + j*8);
    #pragma unroll
    for(int e=0;e<8;e++){
      float a = b2f((unsigned short)vq[e]);
      float c = b2f((unsigned short)vk[e]);
      sq += a; ssq += a*a; dq += a*mk[j*8+e];
      sks += c; ssk += c*c;
    }
  }
  int idx = hq*512 + n;
  float nq = sqrtf(ssq);
  ri1[idx]  = 1.f/(nq+1e-6f);
  mq[idx]   = sq*(1.f/64.f);
  qdm[idx]  = dq;
  float nk = sqrtf(ssk);
  ri2[idx]  = 1.f/(nk+1e-6f);
  sk[idx]   = sks - smkv;
}

// ---------------- fv transpose -> fvT[hq][d][n'] bf16, n' interleaved within 32-chunks ----------------
// position p (within 32-chunk): holds source n = 16*(p&1) + (p>>1)  [matches P pack order: low short = m, high = m+16]
__global__ __launch_bounds__(256) void k_vt(const unsigned short* __restrict__ fvb,
    unsigned short* __restrict__ fvT){
  int bx = blockIdx.x; int hq = bx>>2, nc = bx&3;
  int h = hq>>4, q = hq&15; int n0 = nc*128;
  __shared__ float tile[128][65];
  int t = threadIdx.x;
  #pragma unroll
  for(int i=0;i<4;i++){
    int c = t + i*256; int row = c>>3, k8 = c&7;
    s16x8 v = *(const s16x8*)(fvb + (size_t)(q*512 + n0 + row)*512 + h*64 + k8*8);
    #pragma unroll
    for(int j=0;j<8;j++) tile[row][k8*8+j] = b2f((unsigned short)v[j]);
  }
  __syncthreads();
  #pragma unroll
  for(int i=0;i<4;i++){
    int c = t + i*256; int d = c>>4, n8 = c&15;
    s16x8 o;
    #pragma unroll
    for(int j=0;j<8;j++){
      int p = n8*8+j;
      int pl = p & 31;
      int src = (p & ~31) | (16*(pl&1) + (pl>>1));
      o[j] = (short)f2b(tile[src][d]);
    }
    *(s16x8*)(fvT + (size_t)(hq*64 + d)*512 + n0 + n8*8) = o;
  }
}

// ---------------- component sums pass (MFMA QK) ----------------
__global__ __launch_bounds__(256) void k_comp(const unsigned short* __restrict__ fqb,
    const unsigned short* __restrict__ fkb,
    const float* __restrict__ ri1,
    const float* __restrict__ mq, const float* __restrict__ qdm,
    const float* __restrict__ ri2,
    const float* __restrict__ skp,
    float* __restrict__ mxcg, float* __restrict__ mxvg, double* headsum){
  int bx = blockIdx.x; int hq = bx>>3; int rt = bx&7;
  int h = hq>>4, q = hq&15; int n0 = rt*64;
  __shared__ __align__(16) unsigned short Qs[64*64];
  __shared__ __align__(16) unsigned short Ks[128*64];
  __shared__ float ri2f[512], skf[512];
  __shared__ float red[4][9];
  int t = threadIdx.x; int w = t>>6; int l = t&63; int g = l>>4, lc = l&15;
  for(int i=t; i<512; i+=256){
    ri2f[i]=ri2[hq*NS+i]; skf[i]=skp[hq*NS+i];
  }
  #pragma unroll
  for(int i=0;i<2;i++){
    int c = t + i*256; int row = c>>3, k8 = c&7;
    s16x8 v = *(const s16x8*)(fqb + (size_t)(q*512 + n0 + row)*512 + h*64 + k8*8);
    *(s16x8*)((char*)Qs + row*128 + ((k8*16) ^ ((row&7)<<4))) = v;
  }
  float ri1r[4], mqr[4], qdmr[4];
  #pragma unroll
  for(int r=0;r<4;r++){
    int n = hq*NS + n0 + w*16 + g*4 + r;
    ri1r[r]=ri1[n]; mqr[r]=mq[n]; qdmr[r]=qdm[n];
  }
  __syncthreads();
  bf16x8 aq[2];
  #pragma unroll
  for(int ks=0;ks<2;ks++){
    int row = 16*w + lc;
    aq[ks] = *(const bf16x8*)((const char*)Qs + row*128 + (((ks*4+g)*16) ^ ((row&7)<<4)));
  }
  float p1=0,p3=0,p4=0;
  float rm_m[4]={0,0,0,0}, rm_c[4]={0,0,0,0}, rm_v[4]={0,0,0,0};
  float mxc[4]={-1e30f,-1e30f,-1e30f,-1e30f}, mxv[4]={-1e30f,-1e30f,-1e30f,-1e30f};
  for(int mc=0; mc<4; mc++){
    __syncthreads();
    #pragma unroll
    for(int i=0;i<4;i++){
      int c = t + i*256; int row = c>>3, k8 = c&7;
      s16x8 v = *(const s16x8*)(fkb + (size_t)(q*512 + mc*128 + row)*512 + h*64 + k8*8);
      *(s16x8*)((char*)Ks + row*128 + ((k8*16) ^ ((row&7)<<4))) = v;
    }
    __syncthreads();
    #pragma unroll 2
    for(int mt=0; mt<8; mt++){
      f32x4 dacc = (f32x4){0.f,0.f,0.f,0.f};
      #pragma unroll
      for(int ks=0;ks<2;ks++){
        int row = mt*16 + lc;
        bf16x8 bk = *(const bf16x8*)((const char*)Ks + row*128 + (((ks*4+g)*16) ^ ((row&7)<<4)));
        dacc = mfma16(aq[ks], bk, dacc);
      }
      int m = mc*128 + mt*16 + lc;
      float r2 = ri2f[m], sc = skf[m];
      #pragma unroll
      for(int r=0;r<4;r++){
        float dv = dacc[r];
        float cosv = fminf(fmaxf(dv*ri1r[r]*r2, -0.9f), 0.9f);
        float inner = (dv - qdmr[r]) - mqr[r]*sc;
        float marg = fmaxf(0.01f - cosv, 0.f);
        p1 += cosv*cosv; p3 += inner*inner; p4 += cosv*inner;
        rm_m[r]+=marg; rm_c[r]+=cosv; rm_v[r]+=inner;
        mxc[r]=fmaxf(mxc[r],cosv); mxv[r]=fmaxf(mxv[r],inner);
      }
    }
  }
  float p0 = rm_c[0]+rm_c[1]+rm_c[2]+rm_c[3];
  float p2 = rm_v[0]+rm_v[1]+rm_v[2]+rm_v[3];
  #pragma unroll
  for(int off=1; off<16; off<<=1){
    #pragma unroll
    for(int r=0;r<4;r++){
      rm_m[r]+=__shfl_xor(rm_m[r],off,64);
      rm_c[r]+=__shfl_xor(rm_c[r],off,64);
      rm_v[r]+=__shfl_xor(rm_v[r],off,64);
      mxc[r]=fmaxf(mxc[r],__shfl_xor(mxc[r],off,64));
      mxv[r]=fmaxf(mxv[r],__shfl_xor(mxv[r],off,64));
    }
  }
  float q0=0,q1=0,q2=0,q3=0;
  if(lc==0){
    #pragma unroll
    for(int r=0;r<4;r++){
      float vmv = rm_m[r]*(1.f/512.f);
      q0+=vmv; q1+=vmv*vmv; q2+=vmv*rm_c[r]; q3+=vmv*rm_v[r];
      int n = n0 + w*16 + g*4 + r;
      mxcg[hq*NS+n]=mxc[r]; mxvg[hq*NS+n]=mxv[r];
    }
  }
  float all9[9] = {p0,p1,p2,p3,p4,q0,q1,q2,q3};
  #pragma unroll
  for(int j=0;j<9;j++){
    float vv = wred64(all9[j]);
    if(l==0) red[w][j]=vv;
  }
  __syncthreads();
  if(t<9){
    double s = (double)red[0][t]+(double)red[1][t]+(double)red[2][t]+(double)red[3][t];
    atomicAdd(&headsum[h*9+t], s);
  }
}

// ---------------- finalize (inner-scaled sums; coef includes /temp and log2e) ----------------
__global__ __launch_bounds__(1024) void k_finalize(const double* headsum, const double* featd,
    const float* __restrict__ w1, const float* __restrict__ b1,
    const float* __restrict__ lng, const float* __restrict__ lnb,
    const float* __restrict__ w2, const float* __restrict__ b2,
    const float* __restrict__ w3, const float* __restrict__ b3,
    const float* __restrict__ wtemp, float* coef){
  __shared__ float featS[8][128];
  __shared__ float x1S[8][128];
  __shared__ float x2S[8][64];
  __shared__ float redS[8][4];
  __shared__ float oS[8][3];
  __shared__ float whS[8][3];
  int t = threadIdx.x;
  int h = t>>7, j = t&127;
  featS[h][j] = (float)(featd[t] * (1.0/8192.0));
  __syncthreads();
  float a = 0.f;
  #pragma unroll 16
  for(int i=0;i<128;i++) a += featS[h][i]*w1[(size_t)i*128+j];
  a += b1[j];
  {
    float s = a, ss = a*a;
    #pragma unroll
    for(int m=32;m>0;m>>=1){ s += __shfl_xor(s,m,64); ss += __shfl_xor(ss,m,64); }
    int wv = (t>>6)&1;
    if((t&63)==0){ redS[h][wv*2]=s; redS[h][wv*2+1]=ss; }
  }
  __syncthreads();
  {
    float sum = redS[h][0]+redS[h][2], sumsq = redS[h][1]+redS[h][3];
    float mu = sum*(1.f/128.f);
    float var = sumsq*(1.f/128.f)-mu*mu;
    float rstd = rsqrtf(var+1e-5f);
    x1S[h][j] = fmaxf((a-mu)*rstd*lng[j]+lnb[j], 0.f);
  }
  __syncthreads();
  if(t < 512){
    int h2 = t>>6, j2 = t&63;
    float s2 = 0.f;
    #pragma unroll 16
    for(int i=0;i<128;i++) s2 += x1S[h2][i]*w2[(size_t)i*64+j2];
    x2S[h2][j2] = fmaxf(s2+b2[j2], 0.f);
  }
  __syncthreads();
  if(t < 24){
    int h3 = t/3, j3 = t-h3*3;
    float s3=0.f;
    #pragma unroll 16
    for(int i=0;i<64;i++) s3 += x2S[h3][i]*w3[i*3+j3];
    oS[h3][j3] = s3 + b3[j3];
  }
  __syncthreads();
  if(t < 8){
    float o0=oS[t][0], o1=oS[t][1], o2=oS[t][2];
    float mx=fmaxf(o0,fmaxf(o1,o2));
    float e0=expf(o0-mx), e1=expf(o1-mx), e2=expf(o2-mx), se=e0+e1+e2;
    float l0=e0/se, l1=e1/se, l2=e2/se;
    float wt=fminf(fmaxf(wtemp[0],0.1f),2.0f);
    l0/=wt; l1/=wt; l2/=wt;
    mx=fmaxf(l0,fmaxf(l1,l2));
    e0=expf(l0-mx); e1=expf(l1-mx); e2=expf(l2-mx); se=e0+e1+e2;
    float u0=fminf(fmaxf(e0/se,0.05f),0.8f);
    float u1=fminf(fmaxf(e1/se,0.05f),0.8f);
    float u2=fminf(fmaxf(e2/se,0.05f),0.8f);
    float su=u0+u1+u2;
    whS[t][0]=u0/su; whS[t][1]=u1/su; whS[t][2]=u2/su;
  }
  __syncthreads();
  if(t==0){
    const double N = 33554432.0;
    const double CS2d = (double)CS2;
    double gs[9];
    for(int jj=0;jj<9;jj++){ double s=0; for(int hh=0;hh<8;hh++) s+=headsum[hh*9+jj]; gs[jj]=s; }
    auto sd = [&](double s, double ss)->double{
      double v=(ss - s*s/N)/(N-1.0); return v>0.0 ? sqrt(v) : 0.0;
    };
    double std_cos = sd(gs[0],gs[1]);
    double std_cov = sd(CS2d*gs[2], CS2d*CS2d*gs[3]);
    double std_vm  = sd(512.0*gs[5], 512.0*gs[6]);
    double sdot=0.0, sdot2=0.0;
    double Af[8], Bf[8];
    for(int hh=0;hh<8;hh++){
      const double* hs = headsum + hh*9;
      double A = (double)whS[hh][0]/(std_cos+1e-6);
      double Bi = (double)whS[hh][1]/(std_cov+1e-6)*0.5*CS2d;  // per-inner coefficient
      double C = (double)whS[hh][2]/(std_vm +1e-6)*0.5;
      sdot  += A*hs[0] + Bi*hs[2] + C*512.0*hs[5];
      sdot2 += A*A*hs[1] + Bi*Bi*hs[3] + C*C*512.0*hs[6]
             + 2.0*A*Bi*hs[4] + 2.0*A*C*hs[7] + 2.0*Bi*C*hs[8];
      Af[hh]=A; Bf[hh]=Bi;
    }
    double dstd = sd(sdot, sdot2);
    double temp = dstd < 1e-4 ? 0.1 : (dstd < 0.01 ? 0.3 : 0.5 + dstd);
    temp = fmin(fmax(temp, 0.1), 3.0);
    for(int hh=0;hh<8;hh++){
      coef[hh]   = (float)(Af[hh]/temp*LOG2E);
      coef[8+hh] = (float)(Bf[hh]/temp*LOG2E);
    }
    coef[16] = (float)temp;
  }
}

// ---------------- flash softmax + PV (MFMA), packed P (manual f2b pack), oh -> bf16 hi/lo ----------------
__global__ __launch_bounds__(256) void k_flash(const unsigned short* __restrict__ fqb,
    const unsigned short* __restrict__ fkb, const unsigned short* __restrict__ fvT,
    const float* __restrict__ ri1, const float* __restrict__ mq,
    const float* __restrict__ qdm, const float* __restrict__ ri2,
    const float* __restrict__ skp,
    const float* __restrict__ mxcg, const float* __restrict__ mxvg,
    const float* __restrict__ coef,
    unsigned short* __restrict__ ohh, unsigned short* __restrict__ ohl){
  int bx = blockIdx.x; int hq = bx>>3; int rt = bx&7;
  int h = hq>>4, q = hq&15; int n0 = rt*64;
  __shared__ __align__(16) unsigned short Qs[64*64];
  __shared__ __align__(16) unsigned short Ks[128*64];
  __shared__ __align__(16) unsigned short Vt[64*128];
  __shared__ __align__(16) unsigned short Ps[4][16*40];
  __shared__ float ri2f[512], skf[512];
  int t = threadIdx.x; int w = t>>6; int l = t&63; int g = l>>4, lc = l&15;
  for(int i=t; i<512; i+=256){ ri2f[i]=ri2[hq*NS+i]; skf[i]=skp[hq*NS+i]; }
  #pragma unroll
  for(int i=0;i<2;i++){
    int c = t + i*256; int row = c>>3, k8 = c&7;
    s16x8 v = *(const s16x8*)(fqb + (size_t)(q*512 + n0 + row)*512 + h*64 + k8*8);
    *(s16x8*)((char*)Qs + row*128 + ((k8*16) ^ ((row&7)<<4))) = v;
  }
  float Ah = coef[h], Bh = coef[8+h];
  float ri1r[4], mqr[4], qdmr[4], Mr[4];
  #pragma unroll
  for(int r=0;r<4;r++){
    int n = hq*NS + n0 + w*16 + g*4 + r;
    ri1r[r]=ri1[n]; mqr[r]=mq[n]; qdmr[r]=qdm[n];
    Mr[r] = Ah*mxcg[n] + Bh*mxvg[n];
  }
  __syncthreads();
  bf16x8 aq[2];
  #pragma unroll
  for(int ks=0;ks<2;ks++){
    int row = 16*w + lc;
    aq[ks] = *(const bf16x8*)((const char*)Qs + row*128 + (((ks*4+g)*16) ^ ((row&7)<<4)));
  }
  f32x4 acc[4];
  #pragma unroll
  for(int dt=0;dt<4;dt++) acc[dt] = (f32x4){0.f,0.f,0.f,0.f};
  float lsum[4]={0.f,0.f,0.f,0.f};
  unsigned short* Pw = &Ps[w][0];
  unsigned* Pu = (unsigned*)Pw;
  for(int mc=0; mc<4; mc++){
    __syncthreads();
    #pragma unroll
    for(int i=0;i<4;i++){
      int c = t + i*256; int row = c>>3, k8 = c&7;
      s16x8 v = *(const s16x8*)(fkb + (size_t)(q*512 + mc*128 + row)*512 + h*64 + k8*8);
      *(s16x8*)((char*)Ks + row*128 + ((k8*16) ^ ((row&7)<<4))) = v;
    }
    #pragma unroll
    for(int i=0;i<4;i++){
      int c = t + i*256; int d = c>>4, m8 = c&15;
      s16x8 v = *(const s16x8*)(fvT + (size_t)(hq*64 + d)*512 + mc*128 + m8*8);
      *(s16x8*)((char*)Vt + d*256 + ((m8*16) ^ ((d&7)<<4))) = v;
    }
    __syncthreads();
    #pragma unroll 1
    for(int mt2=0; mt2<4; mt2++){
      f32x4 d0 = (f32x4){0.f,0.f,0.f,0.f};
      f32x4 d1 = (f32x4){0.f,0.f,0.f,0.f};
      #pragma unroll
      for(int ks=0;ks<2;ks++){
        int row0 = (mt2*2)*16 + lc;
        bf16x8 bk0 = *(const bf16x8*)((const char*)Ks + row0*128 + (((ks*4+g)*16) ^ ((row0&7)<<4)));
        d0 = mfma16(aq[ks], bk0, d0);
        int row1 = (mt2*2+1)*16 + lc;
        bf16x8 bk1 = *(const bf16x8*)((const char*)Ks + row1*128 + (((ks*4+g)*16) ^ ((row1&7)<<4)));
        d1 = mfma16(aq[ks], bk1, d1);
      }
      int m0 = mc*128 + mt2*32 + lc;
      float r20 = ri2f[m0],    sc0 = skf[m0];
      float r21 = ri2f[m0+16], sc1 = skf[m0+16];
      #pragma unroll
      for(int r=0;r<4;r++){
        float dv0 = d0[r], dv1 = d1[r];
        float c0 = fminf(fmaxf(dv0*ri1r[r]*r20, -0.9f), 0.9f);
        float c1 = fminf(fmaxf(dv1*ri1r[r]*r21, -0.9f), 0.9f);
        float i0 = (dv0 - qdmr[r]) - mqr[r]*sc0;
        float i1 = (dv1 - qdmr[r]) - mqr[r]*sc1;
        float pe0 = __builtin_amdgcn_exp2f(fmaxf(Ah*c0 + Bh*i0 - Mr[r], -120.f));
        float pe1 = __builtin_amdgcn_exp2f(fmaxf(Ah*c1 + Bh*i1 - Mr[r], -120.f));
        lsum[r] += pe0 + pe1;
        // pack: low short = pe0 (m), high short = pe1 (m+16) — matches k_vt permutation
        unsigned pk = ((unsigned)f2b(pe1) << 16) | (unsigned)f2b(pe0);
        Pu[(g*4+r)*20 + lc] = pk;
      }
      asm volatile("s_waitcnt lgkmcnt(0)" ::: "memory");
      bf16x8 ap = *(const bf16x8*)((const char*)Pw + lc*80 + g*16);
      #pragma unroll
      for(int dt=0;dt<4;dt++){
        int drow = dt*16 + lc;
        bf16x8 bv = *(const bf16x8*)((const char*)Vt + drow*256 + (((mt2*4+g)*16) ^ ((drow&7)<<4)));
        acc[dt] = mfma16(ap, bv, acc[dt]);
      }
    }
  }
  #pragma unroll
  for(int off=1; off<16; off<<=1){
    #pragma unroll
    for(int r=0;r<4;r++) lsum[r] += __shfl_xor(lsum[r], off, 64);
  }
  #pragma unroll
  for(int r=0;r<4;r++){
    float inv = 1.f/lsum[r];
    int n = n0 + w*16 + g*4 + r;
    #pragma unroll
    for(int dt=0;dt<4;dt++){
      size_t idx = (size_t)(q*512 + n)*512 + h*64 + dt*16 + lc;
      float val = acc[dt][r]*inv;
      unsigned short hi = f2b(val);
      ohh[idx] = hi;
      ohl[idx] = f2b(val - b2f(hi));
    }
  }
}

// ---------------- output GEMM: split-bf16 3-term MFMA + bias ----------------
__global__ __launch_bounds__(256) void k_gout2(const unsigned short* __restrict__ Ahp,
    const unsigned short* __restrict__ Alp,
    const unsigned short* __restrict__ Bhp, const unsigned short* __restrict__ Blp,
    const float* __restrict__ bias, float* __restrict__ Cout){
  __shared__ __align__(16) unsigned short AsH[128*64];
  __shared__ __align__(16) unsigned short AsL[128*64];
  __shared__ __align__(16) unsigned short BsH[128*64];
  __shared__ __align__(16) unsigned short BsL[128*64];
  int t = threadIdx.x; int w = t>>6; int l = t&63; int g = l>>4, lc = l&15;
  int Rb = blockIdx.x*128, cb = blockIdx.y*128;
  int wr = (w>>1)*64, wc = (w&1)*64;
  f32x4 acc[4][4];
  #pragma unroll
  for(int i=0;i<4;i++)
    #pragma unroll
    for(int j=0;j<4;j++) acc[i][j] = (f32x4){0.f,0.f,0.f,0.f};
  for(int k0=0; k0<512; k0+=64){
    __syncthreads();
    #pragma unroll
    for(int i=0;i<4;i++){
      int c = t + i*256; int row = c>>3, k8 = c&7;
      int sw = (k8*16) ^ ((row&7)<<4);
      *(s16x8*)((char*)AsH + row*128 + sw) = *(const s16x8*)(Ahp + (size_t)(Rb+row)*512 + k0 + k8*8);
      *(s16x8*)((char*)AsL + row*128 + sw) = *(const s16x8*)(Alp + (size_t)(Rb+row)*512 + k0 + k8*8);
      *(s16x8*)((char*)BsH + row*128 + sw) = *(const s16x8*)(Bhp + (size_t)(cb+row)*512 + k0 + k8*8);
      *(s16x8*)((char*)BsL + row*128 + sw) = *(const s16x8*)(Blp + (size_t)(cb+row)*512 + k0 + k8*8);
    }
    __syncthreads();
    #pragma unroll
    for(int ks=0; ks<2; ks++){
      bf16x8 arh[4], arl[4], brh[4], brl[4];
      #pragma unroll
      for(int rt=0; rt<4; rt++){
        int row = wr + rt*16 + lc;
        int off = row*128 + (((ks*4+g)*16) ^ ((row&7)<<4));
        arh[rt] = *(const bf16x8*)((const char*)AsH + off);
        arl[rt] = *(const bf16x8*)((const char*)AsL + off);
      }
      #pragma unroll
      for(int ct=0; ct<4; ct++){
        int row = wc + ct*16 + lc;
        int off = row*128 + (((ks*4+g)*16) ^ ((row&7)<<4));
        brh[ct] = *(const bf16x8*)((const char*)BsH + off);
        brl[ct] = *(const bf16x8*)((const char*)BsL + off);
      }
      #pragma unroll
      for(int rt=0; rt<4; rt++)
        #pragma unroll
        for(int ct=0; ct<4; ct++){
          acc[rt][ct] = mfma16(arh[rt], brh[ct], acc[rt][ct]);
          acc[rt][ct] = mfma16(arh[rt], brl[ct], acc[rt][ct]);
          acc[rt][ct] = mfma16(arl[rt], brh[ct], acc[rt][ct]);
        }
    }
  }
  #pragma unroll
  for(int rt=0; rt<4; rt++){
    #pragma unroll
    for(int r=0; r<4; r++){
      int R = Rb + wr + rt*16 + g*4 + r;
      #pragma unroll
      for(int ct=0; ct<4; ct++){
        int c = cb + wc + ct*16 + lc;
        Cout[(size_t)R*512 + c] = acc[rt][ct][r] + bias[c];
      }
    }
  }
}

extern "C" void kernel_launch(void* const* d_in, const int* in_sizes, int n_in,
                              void* d_out, int out_size, void* d_ws, size_t ws_size,
                              hipStream_t stream){
  const float* q    = (const float*)d_in[0];
  const float* k    = (const float*)d_in[1];
  const float* v    = (const float*)d_in[2];
  const float* ln1g = (const float*)d_in[3];
  const float* ln1b = (const float*)d_in[4];
  const float* Win  = (const float*)d_in[5];
  const float* w1   = (const float*)d_in[6];
  const float* b1   = (const float*)d_in[7];
  const float* lng  = (const float*)d_in[8];
  const float* lnb  = (const float*)d_in[9];
  const float* w2   = (const float*)d_in[10];
  const float* b2   = (const float*)d_in[11];
  const float* w3   = (const float*)d_in[12];
  const float* b3   = (const float*)d_in[13];
  const float* wtemp= (const float*)d_in[14];
  const float* Wout = (const float*)d_in[15];
  const float* bout = (const float*)d_in[16];

  float* w = (float*)d_ws;
  unsigned short* xnb = (unsigned short*)(w + OFF_XNB);
  unsigned short* fqb = (unsigned short*)(w + OFF_FQB);
  unsigned short* fkb = (unsigned short*)(w + OFF_FKB);
  unsigned short* fvb = (unsigned short*)(w + OFF_FVB);
  unsigned short* fvT = (unsigned short*)(w + OFF_FVT);
  unsigned short* wtb = (unsigned short*)(w + OFF_WT);
  unsigned short* woh = (unsigned short*)(w + OFF_WOH);
  unsigned short* wol = (unsigned short*)(w + OFF_WOL);
  unsigned short* ohh = (unsigned short*)(w + OFF_OHH);
  unsigned short* ohl = (unsigned short*)(w + OFF_OHL);
  float* ri1  = w + OFF_ARR + 0*65536;
  float* mq_  = w + OFF_ARR + 2*65536;
  float* qdm  = w + OFF_ARR + 3*65536;
  float* ri2  = w + OFF_ARR + 4*65536;
  float* sk_  = w + OFF_ARR + 6*65536;
  float* mxc  = w + OFF_ARR + 7*65536;
  float* mxv  = w + OFF_ARR + 8*65536;
  float* mkb  = w + OFF_MKB;
  float* smk_ = w + OFF_SMK;
  float* coef = w + OFF_COEF;
  double* dbl = (double*)(w + OFF_DBL);
  double* headsum = dbl;
  double* featd   = dbl + 72;

  k_tw<<<64, 256, 0, stream>>>(Win, wtb, dbl);
  k_two<<<64, 256, 0, stream>>>(Wout, woh, wol);
  k_ln<<<6144, 256, 0, stream>>>(q, k, v, ln1g, ln1b, xnb);
  k_mm1<<<dim3(192,4), 256, 0, stream>>>(xnb, wtb, fqb, fkb, fvb);
  k_colstats<<<128, 1024, 0, stream>>>(fqb, fkb, mkb, smk_, featd);
  k_rowstats<<<256, 256, 0, stream>>>(fqb, fkb, mkb, smk_, ri1, mq_, qdm, ri2, sk_);
  k_vt<<<512, 256, 0, stream>>>(fvb, fvT);
  k_comp<<<1024, 256, 0, stream>>>(fqb, fkb, ri1, mq_, qdm, ri2, sk_, mxc, mxv, headsum);
  k_finalize<<<1, 1024, 0, stream>>>(headsum, featd, w1, b1, lng, lnb, w2, b2, w3, b3, wtemp, coef);
  k_flash<<<1024, 256, 0, stream>>>(fqb, fkb, fvT, ri1, mq_, qdm, ri2, sk_, mxc, mxv, coef, ohh, ohl);
  k_gout2<<<dim3(64,4), 256, 0, stream>>>(ohh, ohl, woh, wol, bout, (float*)d_out);
}

// Round 9
// 159.243 us; speedup vs baseline: 5.0557x; 1.0587x over previous
//
#include <hip/hip_runtime.h>
#include <math.h>

#define H 8
#define NS 512
#define D 64

typedef __bf16 bf16x8 __attribute__((ext_vector_type(8)));
typedef _Float16 f16x8 __attribute__((ext_vector_type(8)));
typedef float f32x4 __attribute__((ext_vector_type(4)));
typedef short s16x8 __attribute__((ext_vector_type(8)));
typedef short s16x4 __attribute__((ext_vector_type(4)));

#define CS2 ((1e-3f/512.f)/(8.f+1e-6f))
#define LOG2E 1.4426950408889634

static __device__ __forceinline__ f32x4 mfma16(bf16x8 a, bf16x8 b, f32x4 c){
  return __builtin_amdgcn_mfma_f32_16x16x32_bf16(a,b,c,0,0,0);
}
static __device__ __forceinline__ f32x4 mfma16h(f16x8 a, f16x8 b, f32x4 c){
  return __builtin_amdgcn_mfma_f32_16x16x32_f16(a,b,c,0,0,0);
}
static __device__ __forceinline__ float b2f(unsigned short s){
  union { unsigned u; float f; } v; v.u = ((unsigned)s)<<16; return v.f;
}
static __device__ __forceinline__ unsigned short f2b(float f){
  union { float f; unsigned u; } v; v.f = f;
  unsigned r = v.u + 0x7FFFu + ((v.u>>16)&1u);
  return (unsigned short)(r>>16);
}
static __device__ __forceinline__ float wred64(float v){
  #pragma unroll
  for(int m=32; m>0; m>>=1) v += __shfl_xor(v, m, 64);
  return v;
}

// ---- workspace layout (float element offsets) ----
constexpr size_t OFF_XNB = 0;                       // 24576x512 bf16
constexpr size_t OFF_FQB = 6291456;                 // 8192x512 bf16
constexpr size_t OFF_FKB = 8388608;
constexpr size_t OFF_FVB = 10485760;
constexpr size_t OFF_FVT = 12582912;                // [128][64][512] fp16 (m-interleaved per 32-chunk)
constexpr size_t OFF_WT  = 14680064;                // 512x512 bf16 (WinT)
constexpr size_t OFF_WOH = 14811136;                // 512x512 bf16 WoutT hi
constexpr size_t OFF_WOL = 14942208;                // 512x512 bf16 WoutT lo
constexpr size_t OFF_OHH = 15073280;                // 8192x512 bf16 oh hi
constexpr size_t OFF_OHL = 17170432;                // 8192x512 bf16 oh lo
constexpr size_t OFF_ARR = 19267584;                // arrays x 65536 f32
constexpr size_t OFF_MKB = OFF_ARR + 9*65536;       // [128][64]
constexpr size_t OFF_SMK = OFF_MKB + 8192;
constexpr size_t OFF_COEF= OFF_SMK + 128;
constexpr size_t OFF_DBL = OFF_COEF + 32;           // 8B aligned (even)
constexpr size_t NDBL    = 72 + 1024;               // headsum[8][9], featd[8][128]

// ---------------- fused pre: LayerNorm (blocks<6144) + W_in T (64) + W_out T hi/lo (64) ----------------
__global__ __launch_bounds__(256) void k_pre(const float* __restrict__ q,
    const float* __restrict__ k, const float* __restrict__ v,
    const float* __restrict__ g, const float* __restrict__ b,
    const float* __restrict__ Win, const float* __restrict__ Wout,
    unsigned short* __restrict__ xnb, unsigned short* __restrict__ WT,
    unsigned short* __restrict__ WTh, unsigned short* __restrict__ WTl,
    double* __restrict__ dbl){
  int bx = blockIdx.x; int t = threadIdx.x;
  if(bx < 6144){
    int row = bx*4 + (t>>6); int l = t & 63;
    const float* src = (row < 8192) ? q : ((row < 16384) ? k : v);
    int r = row & 8191;
    const float4* sp = (const float4*)(src + (size_t)r*512);
    float4 v1 = sp[l*2], v2 = sp[l*2+1];
    float s  = v1.x+v1.y+v1.z+v1.w + v2.x+v2.y+v2.z+v2.w;
    float ss = v1.x*v1.x+v1.y*v1.y+v1.z*v1.z+v1.w*v1.w
             + v2.x*v2.x+v2.y*v2.y+v2.z*v2.z+v2.w*v2.w;
    s = wred64(s); ss = wred64(ss);
    float mu = s*(1.f/512.f);
    float var = ss*(1.f/512.f) - mu*mu;
    float rstd = rsqrtf(var + 1e-5f);
    const float4* gp = (const float4*)g; const float4* bp = (const float4*)b;
    float4 g1 = gp[l*2], g2 = gp[l*2+1], b1 = bp[l*2], b2 = bp[l*2+1];
    s16x8 o;
    o[0]=(short)f2b((v1.x-mu)*rstd*g1.x+b1.x); o[1]=(short)f2b((v1.y-mu)*rstd*g1.y+b1.y);
    o[2]=(short)f2b((v1.z-mu)*rstd*g1.z+b1.z); o[3]=(short)f2b((v1.w-mu)*rstd*g1.w+b1.w);
    o[4]=(short)f2b((v2.x-mu)*rstd*g2.x+b2.x); o[5]=(short)f2b((v2.y-mu)*rstd*g2.y+b2.y);
    o[6]=(short)f2b((v2.z-mu)*rstd*g2.z+b2.z); o[7]=(short)f2b((v2.w-mu)*rstd*g2.w+b2.w);
    *(s16x8*)(xnb + (size_t)row*512 + l*8) = o;
    return;
  }
  __shared__ float tile[64][65];
  if(bx < 6208){
    int bb = bx - 6144; int kt = bb>>3, nt = bb&7;
    if(bb==0){
      for(int i=t;i<(int)NDBL;i+=256) dbl[i]=0.0;
    }
    #pragma unroll
    for(int i=0;i<4;i++){
      int row = (t>>4) + i*16; int col = (t&15)*4;
      float4 vv = *(const float4*)(Win + (size_t)(kt*64+row)*512 + nt*64 + col);
      tile[row][col]=vv.x; tile[row][col+1]=vv.y; tile[row][col+2]=vv.z; tile[row][col+3]=vv.w;
    }
    __syncthreads();
    #pragma unroll
    for(int i=0;i<4;i++){
      int n = (t>>4) + i*16; int ck = (t&15)*4;
      s16x4 o;
      #pragma unroll
      for(int j=0;j<4;j++) o[j] = (short)f2b(tile[ck+j][n]);
      *(s16x4*)(WT + (size_t)(nt*64+n)*512 + kt*64 + ck) = o;
    }
  } else {
    int bb = bx - 6208; int kt = bb>>3, nt = bb&7;
    #pragma unroll
    for(int i=0;i<4;i++){
      int row = (t>>4) + i*16; int col = (t&15)*4;
      float4 vv = *(const float4*)(Wout + (size_t)(kt*64+row)*512 + nt*64 + col);
      tile[row][col]=vv.x; tile[row][col+1]=vv.y; tile[row][col+2]=vv.z; tile[row][col+3]=vv.w;
    }
    __syncthreads();
    #pragma unroll
    for(int i=0;i<4;i++){
      int n = (t>>4) + i*16; int ck = (t&15)*4;
      s16x4 oh_, ol_;
      #pragma unroll
      for(int j=0;j<4;j++){
        float x = tile[ck+j][n];
        unsigned short hi = f2b(x);
        oh_[j] = (short)hi;
        ol_[j] = (short)f2b(x - b2f(hi));
      }
      *(s16x4*)(WTh + (size_t)(nt*64+n)*512 + kt*64 + ck) = oh_;
      *(s16x4*)(WTl + (size_t)(nt*64+n)*512 + kt*64 + ck) = ol_;
    }
  }
}

// ---------------- proj GEMM bf16 MFMA ----------------
__global__ __launch_bounds__(256) void k_mm1(const unsigned short* __restrict__ xnb,
    const unsigned short* __restrict__ WT,
    unsigned short* __restrict__ fqb, unsigned short* __restrict__ fkb,
    unsigned short* __restrict__ fvb){
  __shared__ __align__(16) unsigned short As[128*64];
  __shared__ __align__(16) unsigned short Bs[128*64];
  int t = threadIdx.x; int w = t>>6; int l = t&63; int g = l>>4, lc = l&15;
  int Rb = blockIdx.x*128, cb = blockIdx.y*128;
  int wr = (w>>1)*64, wc = (w&1)*64;
  f32x4 acc[4][4];
  #pragma unroll
  for(int i=0;i<4;i++)
    #pragma unroll
    for(int j=0;j<4;j++) acc[i][j] = (f32x4){0.f,0.f,0.f,0.f};
  for(int k0=0; k0<512; k0+=64){
    __syncthreads();
    #pragma unroll
    for(int i=0;i<4;i++){
      int c = t + i*256; int row = c>>3, k8 = c&7;
      s16x8 va = *(const s16x8*)(xnb + (size_t)(Rb+row)*512 + k0 + k8*8);
      *(s16x8*)((char*)As + row*128 + ((k8*16) ^ ((row&7)<<4))) = va;
      s16x8 vb = *(const s16x8*)(WT + (size_t)(cb+row)*512 + k0 + k8*8);
      *(s16x8*)((char*)Bs + row*128 + ((k8*16) ^ ((row&7)<<4))) = vb;
    }
    __syncthreads();
    #pragma unroll
    for(int ks=0; ks<2; ks++){
      bf16x8 ar[4], br[4];
      #pragma unroll
      for(int rt=0; rt<4; rt++){
        int row = wr + rt*16 + lc;
        ar[rt] = *(const bf16x8*)((const char*)As + row*128 + (((ks*4+g)*16) ^ ((row&7)<<4)));
      }
      #pragma unroll
      for(int ct=0; ct<4; ct++){
        int row = wc + ct*16 + lc;
        br[ct] = *(const bf16x8*)((const char*)Bs + row*128 + (((ks*4+g)*16) ^ ((row&7)<<4)));
      }
      #pragma unroll
      for(int rt=0; rt<4; rt++)
        #pragma unroll
        for(int ct=0; ct<4; ct++)
          acc[rt][ct] = mfma16(ar[rt], br[ct], acc[rt][ct]);
    }
  }
  #pragma unroll
  for(int rt=0; rt<4; rt++){
    #pragma unroll
    for(int r=0; r<4; r++){
      int R = Rb + wr + rt*16 + g*4 + r;
      int tsel = R>>13; int rr = R&8191;
      unsigned short* dst = (tsel==0)?fqb:((tsel==1)?fkb:fvb);
      #pragma unroll
      for(int ct=0; ct<4; ct++){
        int c = cb + wc + ct*16 + lc;
        dst[(size_t)rr*512 + c] = f2b(acc[rt][ct][r]);
      }
    }
  }
}

// ---------------- fused mid: per-hq stats (blocks<128) + fv transpose->fp16 (512 blocks) ----------------
__global__ __launch_bounds__(512) void k_mid(const unsigned short* __restrict__ fqb,
    const unsigned short* __restrict__ fkb, const unsigned short* __restrict__ fvb,
    float* __restrict__ mkb, float* __restrict__ smk, double* featd,
    float* __restrict__ ri1, float* __restrict__ mq, float* __restrict__ qdm,
    float* __restrict__ ri2, float* __restrict__ sk,
    unsigned short* __restrict__ fvT){
  int bx = blockIdx.x; int t = threadIdx.x;
  if(bx < 128){
    int hq = bx; int h = hq>>4, q = hq&15;
    __shared__ float cq[8][64], ck[8][64], mkS[64];
    __shared__ float smkS;
    {
      int d = t&63; int g = t>>6;  // 8 n-groups
      float aq=0.f, ak=0.f;
      for(int n=g; n<512; n+=8){
        size_t base = (size_t)(q*512+n)*512 + h*64 + d;
        aq += b2f(fqb[base]);
        ak += b2f(fkb[base]);
      }
      cq[g][d]=aq; ck[g][d]=ak;
    }
    __syncthreads();
    if(t<64){
      float sq=0.f, sk2=0.f;
      #pragma unroll
      for(int i=0;i<8;i++){ sq+=cq[i][t]; sk2+=ck[i][t]; }
      atomicAdd(&featd[h*128+t], (double)sq);
      atomicAdd(&featd[h*128+64+t], (double)sk2);
      float mk = sk2*(1.f/512.f);
      mkb[hq*64+t]=mk; mkS[t]=mk;
      float s = wred64(mk);
      if(t==0){ smk[hq]=s; smkS=s; }
    }
    __syncthreads();
    {
      int n = t;
      float smkv = smkS;
      const unsigned short* fr = fqb + (size_t)(q*512+n)*512 + h*64;
      const unsigned short* kr = fkb + (size_t)(q*512+n)*512 + h*64;
      float sq=0.f, ssq=0.f, dq=0.f, sks=0.f, ssk=0.f;
      #pragma unroll
      for(int j=0;j<8;j++){
        s16x8 vq = *(const s16x8*)(fr + j*8);
        s16x8 vk = *(const s16x8*)(kr + j*8);
        #pragma unroll
        for(int e=0;e<8;e++){
          float a = b2f((unsigned short)vq[e]);
          float c = b2f((unsigned short)vk[e]);
          sq += a; ssq += a*a; dq += a*mkS[j*8+e];
          sks += c; ssk += c*c;
        }
      }
      int idx = hq*512 + n;
      float nq = sqrtf(ssq);
      ri1[idx]  = 1.f/(nq+1e-6f);
      mq[idx]   = sq*(1.f/64.f);
      qdm[idx]  = dq;
      float nk = sqrtf(ssk);
      ri2[idx]  = 1.f/(nk+1e-6f);
      sk[idx]   = sks - smkv;
    }
    return;
  }
  // V transpose -> fvT[hq][d][n'] fp16, n' interleaved per 32-chunk: pos p holds n = 16*(p&1)+(p>>1)
  {
    int bb = bx - 128; int hq = bb>>2, nc = bb&3;
    int h = hq>>4, q = hq&15; int n0 = nc*128;
    __shared__ float tile[128][65];
    #pragma unroll
    for(int i=0;i<2;i++){
      int c = t + i*512; int row = c>>3, k8 = c&7;
      s16x8 v = *(const s16x8*)(fvb + (size_t)(q*512 + n0 + row)*512 + h*64 + k8*8);
      #pragma unroll
      for(int j=0;j<8;j++) tile[row][k8*8+j] = b2f((unsigned short)v[j]);
    }
    __syncthreads();
    #pragma unroll
    for(int i=0;i<2;i++){
      int c = t + i*512; int d = c>>4, n8 = c&15;
      s16x8 o;
      #pragma unroll
      for(int j=0;j<8;j++){
        int p = n8*8+j;
        int pl = p & 31;
        int src = (p & ~31) | (16*(pl&1) + (pl>>1));
        union { _Float16 hl; short s; } cv; cv.hl = (_Float16)tile[src][d];
        o[j] = cv.s;
      }
      *(s16x8*)(fvT + (size_t)(hq*64 + d)*512 + n0 + n8*8) = o;
    }
  }
}

// ---------------- component sums pass (MFMA QK) ----------------
__global__ __launch_bounds__(256) void k_comp(const unsigned short* __restrict__ fqb,
    const unsigned short* __restrict__ fkb,
    const float* __restrict__ ri1,
    const float* __restrict__ mq, const float* __restrict__ qdm,
    const float* __restrict__ ri2,
    const float* __restrict__ skp,
    float* __restrict__ mxcg, float* __restrict__ mxvg, double* headsum){
  int bx = blockIdx.x; int hq = bx>>3; int rt = bx&7;
  int h = hq>>4, q = hq&15; int n0 = rt*64;
  __shared__ __align__(16) unsigned short Qs[64*64];
  __shared__ __align__(16) unsigned short Ks[128*64];
  __shared__ float ri2f[512], skf[512];
  __shared__ float red[4][9];
  int t = threadIdx.x; int w = t>>6; int l = t&63; int g = l>>4, lc = l&15;
  for(int i=t; i<512; i+=256){
    ri2f[i]=ri2[hq*NS+i]; skf[i]=skp[hq*NS+i];
  }
  #pragma unroll
  for(int i=0;i<2;i++){
    int c = t + i*256; int row = c>>3, k8 = c&7;
    s16x8 v = *(const s16x8*)(fqb + (size_t)(q*512 + n0 + row)*512 + h*64 + k8*8);
    *(s16x8*)((char*)Qs + row*128 + ((k8*16) ^ ((row&7)<<4))) = v;
  }
  float ri1r[4], mqr[4], qdmr[4];
  #pragma unroll
  for(int r=0;r<4;r++){
    int n = hq*NS + n0 + w*16 + g*4 + r;
    ri1r[r]=ri1[n]; mqr[r]=mq[n]; qdmr[r]=qdm[n];
  }
  __syncthreads();
  bf16x8 aq[2];
  #pragma unroll
  for(int ks=0;ks<2;ks++){
    int row = 16*w + lc;
    aq[ks] = *(const bf16x8*)((const char*)Qs + row*128 + (((ks*4+g)*16) ^ ((row&7)<<4)));
  }
  float p1=0,p3=0,p4=0;
  float rm_m[4]={0,0,0,0}, rm_c[4]={0,0,0,0}, rm_v[4]={0,0,0,0};
  float mxc[4]={-1e30f,-1e30f,-1e30f,-1e30f}, mxv[4]={-1e30f,-1e30f,-1e30f,-1e30f};
  for(int mc=0; mc<4; mc++){
    __syncthreads();
    #pragma unroll
    for(int i=0;i<4;i++){
      int c = t + i*256; int row = c>>3, k8 = c&7;
      s16x8 v = *(const s16x8*)(fkb + (size_t)(q*512 + mc*128 + row)*512 + h*64 + k8*8);
      *(s16x8*)((char*)Ks + row*128 + ((k8*16) ^ ((row&7)<<4))) = v;
    }
    __syncthreads();
    #pragma unroll 2
    for(int mt=0; mt<8; mt++){
      f32x4 dacc = (f32x4){0.f,0.f,0.f,0.f};
      #pragma unroll
      for(int ks=0;ks<2;ks++){
        int row = mt*16 + lc;
        bf16x8 bk = *(const bf16x8*)((const char*)Ks + row*128 + (((ks*4+g)*16) ^ ((row&7)<<4)));
        dacc = mfma16(aq[ks], bk, dacc);
      }
      int m = mc*128 + mt*16 + lc;
      float r2 = ri2f[m], sc = skf[m];
      #pragma unroll
      for(int r=0;r<4;r++){
        float dv = dacc[r];
        float cosv = fminf(fmaxf(dv*ri1r[r]*r2, -0.9f), 0.9f);
        float inner = (dv - qdmr[r]) - mqr[r]*sc;
        float marg = fmaxf(0.01f - cosv, 0.f);
        p1 += cosv*cosv; p3 += inner*inner; p4 += cosv*inner;
        rm_m[r]+=marg; rm_c[r]+=cosv; rm_v[r]+=inner;
        mxc[r]=fmaxf(mxc[r],cosv); mxv[r]=fmaxf(mxv[r],inner);
      }
    }
  }
  float p0 = rm_c[0]+rm_c[1]+rm_c[2]+rm_c[3];
  float p2 = rm_v[0]+rm_v[1]+rm_v[2]+rm_v[3];
  #pragma unroll
  for(int off=1; off<16; off<<=1){
    #pragma unroll
    for(int r=0;r<4;r++){
      rm_m[r]+=__shfl_xor(rm_m[r],off,64);
      rm_c[r]+=__shfl_xor(rm_c[r],off,64);
      rm_v[r]+=__shfl_xor(rm_v[r],off,64);
      mxc[r]=fmaxf(mxc[r],__shfl_xor(mxc[r],off,64));
      mxv[r]=fmaxf(mxv[r],__shfl_xor(mxv[r],off,64));
    }
  }
  float q0=0,q1=0,q2=0,q3=0;
  if(lc==0){
    #pragma unroll
    for(int r=0;r<4;r++){
      float vmv = rm_m[r]*(1.f/512.f);
      q0+=vmv; q1+=vmv*vmv; q2+=vmv*rm_c[r]; q3+=vmv*rm_v[r];
      int n = n0 + w*16 + g*4 + r;
      mxcg[hq*NS+n]=mxc[r]; mxvg[hq*NS+n]=mxv[r];
    }
  }
  float all9[9] = {p0,p1,p2,p3,p4,q0,q1,q2,q3};
  #pragma unroll
  for(int j=0;j<9;j++){
    float vv = wred64(all9[j]);
    if(l==0) red[w][j]=vv;
  }
  __syncthreads();
  if(t<9){
    double s = (double)red[0][t]+(double)red[1][t]+(double)red[2][t]+(double)red[3][t];
    atomicAdd(&headsum[h*9+t], s);
  }
}

// ---------------- finalize (inner-scaled sums; coef includes /temp and log2e) ----------------
__global__ __launch_bounds__(1024) void k_finalize(const double* headsum, const double* featd,
    const float* __restrict__ w1, const float* __restrict__ b1,
    const float* __restrict__ lng, const float* __restrict__ lnb,
    const float* __restrict__ w2, const float* __restrict__ b2,
    const float* __restrict__ w3, const float* __restrict__ b3,
    const float* __restrict__ wtemp, float* coef){
  __shared__ float featS[8][128];
  __shared__ float x1S[8][128];
  __shared__ float x2S[8][64];
  __shared__ float redS[8][4];
  __shared__ float oS[8][3];
  __shared__ float whS[8][3];
  int t = threadIdx.x;
  int h = t>>7, j = t&127;
  featS[h][j] = (float)(featd[t] * (1.0/8192.0));
  __syncthreads();
  float a = 0.f;
  #pragma unroll 16
  for(int i=0;i<128;i++) a += featS[h][i]*w1[(size_t)i*128+j];
  a += b1[j];
  {
    float s = a, ss = a*a;
    #pragma unroll
    for(int m=32;m>0;m>>=1){ s += __shfl_xor(s,m,64); ss += __shfl_xor(ss,m,64); }
    int wv = (t>>6)&1;
    if((t&63)==0){ redS[h][wv*2]=s; redS[h][wv*2+1]=ss; }
  }
  __syncthreads();
  {
    float sum = redS[h][0]+redS[h][2], sumsq = redS[h][1]+redS[h][3];
    float mu = sum*(1.f/128.f);
    float var = sumsq*(1.f/128.f)-mu*mu;
    float rstd = rsqrtf(var+1e-5f);
    x1S[h][j] = fmaxf((a-mu)*rstd*lng[j]+lnb[j], 0.f);
  }
  __syncthreads();
  if(t < 512){
    int h2 = t>>6, j2 = t&63;
    float s2 = 0.f;
    #pragma unroll 16
    for(int i=0;i<128;i++) s2 += x1S[h2][i]*w2[(size_t)i*64+j2];
    x2S[h2][j2] = fmaxf(s2+b2[j2], 0.f);
  }
  __syncthreads();
  if(t < 24){
    int h3 = t/3, j3 = t-h3*3;
    float s3=0.f;
    #pragma unroll 16
    for(int i=0;i<64;i++) s3 += x2S[h3][i]*w3[i*3+j3];
    oS[h3][j3] = s3 + b3[j3];
  }
  __syncthreads();
  if(t < 8){
    float o0=oS[t][0], o1=oS[t][1], o2=oS[t][2];
    float mx=fmaxf(o0,fmaxf(o1,o2));
    float e0=expf(o0-mx), e1=expf(o1-mx), e2=expf(o2-mx), se=e0+e1+e2;
    float l0=e0/se, l1=e1/se, l2=e2/se;
    float wt=fminf(fmaxf(wtemp[0],0.1f),2.0f);
    l0/=wt; l1/=wt; l2/=wt;
    mx=fmaxf(l0,fmaxf(l1,l2));
    e0=expf(l0-mx); e1=expf(l1-mx); e2=expf(l2-mx); se=e0+e1+e2;
    float u0=fminf(fmaxf(e0/se,0.05f),0.8f);
    float u1=fminf(fmaxf(e1/se,0.05f),0.8f);
    float u2=fminf(fmaxf(e2/se,0.05f),0.8f);
    float su=u0+u1+u2;
    whS[t][0]=u0/su; whS[t][1]=u1/su; whS[t][2]=u2/su;
  }
  __syncthreads();
  if(t==0){
    const double N = 33554432.0;
    const double CS2d = (double)CS2;
    double gs[9];
    for(int jj=0;jj<9;jj++){ double s=0; for(int hh=0;hh<8;hh++) s+=headsum[hh*9+jj]; gs[jj]=s; }
    auto sd = [&](double s, double ss)->double{
      double v=(ss - s*s/N)/(N-1.0); return v>0.0 ? sqrt(v) : 0.0;
    };
    double std_cos = sd(gs[0],gs[1]);
    double std_cov = sd(CS2d*gs[2], CS2d*CS2d*gs[3]);
    double std_vm  = sd(512.0*gs[5], 512.0*gs[6]);
    double sdot=0.0, sdot2=0.0;
    double Af[8], Bf[8];
    for(int hh=0;hh<8;hh++){
      const double* hs = headsum + hh*9;
      double A = (double)whS[hh][0]/(std_cos+1e-6);
      double Bi = (double)whS[hh][1]/(std_cov+1e-6)*0.5*CS2d;
      double C = (double)whS[hh][2]/(std_vm +1e-6)*0.5;
      sdot  += A*hs[0] + Bi*hs[2] + C*512.0*hs[5];
      sdot2 += A*A*hs[1] + Bi*Bi*hs[3] + C*C*512.0*hs[6]
             + 2.0*A*Bi*hs[4] + 2.0*A*C*hs[7] + 2.0*Bi*C*hs[8];
      Af[hh]=A; Bf[hh]=Bi;
    }
    double dstd = sd(sdot, sdot2);
    double temp = dstd < 1e-4 ? 0.1 : (dstd < 0.01 ? 0.3 : 0.5 + dstd);
    temp = fmin(fmax(temp, 0.1), 3.0);
    for(int hh=0;hh<8;hh++){
      coef[hh]   = (float)(Af[hh]/temp*LOG2E);
      coef[8+hh] = (float)(Bf[hh]/temp*LOG2E);
    }
    coef[16] = (float)temp;
  }
}

// ---------------- flash softmax + PV (fp16 P via cvt_pkrtz, fp16 V, f16 MFMA) ----------------
__global__ __launch_bounds__(256) void k_flash(const unsigned short* __restrict__ fqb,
    const unsigned short* __restrict__ fkb, const unsigned short* __restrict__ fvT,
    const float* __restrict__ ri1, const float* __restrict__ mq,
    const float* __restrict__ qdm, const float* __restrict__ ri2,
    const float* __restrict__ skp,
    const float* __restrict__ mxcg, const float* __restrict__ mxvg,
    const float* __restrict__ coef,
    unsigned short* __restrict__ ohh, unsigned short* __restrict__ ohl){
  int bx = blockIdx.x; int hq = bx>>3; int rt = bx&7;
  int h = hq>>4, q = hq&15; int n0 = rt*64;
  __shared__ __align__(16) unsigned short Qs[64*64];   // reused as Ps after aq extraction
  __shared__ __align__(16) unsigned short Ks[128*64];
  __shared__ __align__(16) unsigned short Vt[64*128];
  __shared__ float ri2f[512], skf[512];
  int t = threadIdx.x; int w = t>>6; int l = t&63; int g = l>>4, lc = l&15;
  for(int i=t; i<512; i+=256){ ri2f[i]=ri2[hq*NS+i]; skf[i]=skp[hq*NS+i]; }
  #pragma unroll
  for(int i=0;i<2;i++){
    int c = t + i*256; int row = c>>3, k8 = c&7;
    s16x8 v = *(const s16x8*)(fqb + (size_t)(q*512 + n0 + row)*512 + h*64 + k8*8);
    *(s16x8*)((char*)Qs + row*128 + ((k8*16) ^ ((row&7)<<4))) = v;
  }
  float Ah = coef[h], Bh = coef[8+h];
  float loA = -0.9f*Ah, hiA = 0.9f*Ah;
  float ri1A[4], R1[4], R2[4];
  #pragma unroll
  for(int r=0;r<4;r++){
    int n = hq*NS + n0 + w*16 + g*4 + r;
    float Mr = Ah*mxcg[n] + Bh*mxvg[n];
    ri1A[r] = ri1[n]*Ah;
    R1[r] = fmaf(Bh, qdm[n], Mr);
    R2[r] = Bh*mq[n];
  }
  __syncthreads();
  bf16x8 aq[2];
  #pragma unroll
  for(int ks=0;ks<2;ks++){
    int row = 16*w + lc;
    aq[ks] = *(const bf16x8*)((const char*)Qs + row*128 + (((ks*4+g)*16) ^ ((row&7)<<4)));
  }
  f32x4 acc[4];
  #pragma unroll
  for(int dt=0;dt<4;dt++) acc[dt] = (f32x4){0.f,0.f,0.f,0.f};
  float lsum[4]={0.f,0.f,0.f,0.f};
  unsigned short* Pw = Qs + w*640;        // 16 rows x 40 shorts per wave, inside Qs region
  unsigned* Pu = (unsigned*)Pw;
  for(int mc=0; mc<4; mc++){
    __syncthreads();
    #pragma unroll
    for(int i=0;i<4;i++){
      int c = t + i*256; int row = c>>3, k8 = c&7;
      s16x8 v = *(const s16x8*)(fkb + (size_t)(q*512 + mc*128 + row)*512 + h*64 + k8*8);
      *(s16x8*)((char*)Ks + row*128 + ((k8*16) ^ ((row&7)<<4))) = v;
    }
    #pragma unroll
    for(int i=0;i<4;i++){
      int c = t + i*256; int d = c>>4, m8 = c&15;
      s16x8 v = *(const s16x8*)(fvT + (size_t)(hq*64 + d)*512 + mc*128 + m8*8);
      *(s16x8*)((char*)Vt + d*256 + ((m8*16) ^ ((d&7)<<4))) = v;
    }
    __syncthreads();
    #pragma unroll 1
    for(int mt2=0; mt2<4; mt2++){
      f32x4 d0 = (f32x4){0.f,0.f,0.f,0.f};
      f32x4 d1 = (f32x4){0.f,0.f,0.f,0.f};
      #pragma unroll
      for(int ks=0;ks<2;ks++){
        int row0 = (mt2*2)*16 + lc;
        bf16x8 bk0 = *(const bf16x8*)((const char*)Ks + row0*128 + (((ks*4+g)*16) ^ ((row0&7)<<4)));
        d0 = mfma16(aq[ks], bk0, d0);
        int row1 = (mt2*2+1)*16 + lc;
        bf16x8 bk1 = *(const bf16x8*)((const char*)Ks + row1*128 + (((ks*4+g)*16) ^ ((row1&7)<<4)));
        d1 = mfma16(aq[ks], bk1, d1);
      }
      int m0 = mc*128 + mt2*32 + lc;
      float r20 = ri2f[m0],    sc0 = skf[m0];
      float r21 = ri2f[m0+16], sc1 = skf[m0+16];
      #pragma unroll
      for(int r=0;r<4;r++){
        float dv0 = d0[r], dv1 = d1[r];
        float cl0 = fminf(fmaxf(dv0*ri1A[r]*r20, loA), hiA);
        float cl1 = fminf(fmaxf(dv1*ri1A[r]*r21, loA), hiA);
        float e0 = fmaf(-R2[r], sc0, fmaf(Bh, dv0, -R1[r]));
        float e1 = fmaf(-R2[r], sc1, fmaf(Bh, dv1, -R1[r]));
        float pe0 = __builtin_amdgcn_exp2f(cl0 + e0);
        float pe1 = __builtin_amdgcn_exp2f(cl1 + e1);
        lsum[r] += pe0 + pe1;
        // packed fp16: low half = pe0 (m), high = pe1 (m+16) — matches fvT permutation
        auto ph = __builtin_amdgcn_cvt_pkrtz(pe0, pe1);
        unsigned pk; __builtin_memcpy(&pk, &ph, 4);
        Pu[(g*4+r)*20 + lc] = pk;
      }
      asm volatile("s_waitcnt lgkmcnt(0)" ::: "memory");
      f16x8 ap = *(const f16x8*)((const char*)Pw + lc*80 + g*16);
      #pragma unroll
      for(int dt=0;dt<4;dt++){
        int drow = dt*16 + lc;
        f16x8 bv = *(const f16x8*)((const char*)Vt + drow*256 + (((mt2*4+g)*16) ^ ((drow&7)<<4)));
        acc[dt] = mfma16h(ap, bv, acc[dt]);
      }
    }
  }
  #pragma unroll
  for(int off=1; off<16; off<<=1){
    #pragma unroll
    for(int r=0;r<4;r++) lsum[r] += __shfl_xor(lsum[r], off, 64);
  }
  #pragma unroll
  for(int r=0;r<4;r++){
    float inv = 1.f/lsum[r];
    int n = n0 + w*16 + g*4 + r;
    #pragma unroll
    for(int dt=0;dt<4;dt++){
      size_t idx = (size_t)(q*512 + n)*512 + h*64 + dt*16 + lc;
      float val = acc[dt][r]*inv;
      unsigned short hi = f2b(val);
      ohh[idx] = hi;
      ohl[idx] = f2b(val - b2f(hi));
    }
  }
}

// ---------------- output GEMM: split-bf16 3-term MFMA + bias ----------------
__global__ __launch_bounds__(256) void k_gout2(const unsigned short* __restrict__ Ahp,
    const unsigned short* __restrict__ Alp,
    const unsigned short* __restrict__ Bhp, const unsigned short* __restrict__ Blp,
    const float* __restrict__ bias, float* __restrict__ Cout){
  __shared__ __align__(16) unsigned short AsH[128*64];
  __shared__ __align__(16) unsigned short AsL[128*64];
  __shared__ __align__(16) unsigned short BsH[128*64];
  __shared__ __align__(16) unsigned short BsL[128*64];
  int t = threadIdx.x; int w = t>>6; int l = t&63; int g = l>>4, lc = l&15;
  int Rb = blockIdx.x*128, cb = blockIdx.y*128;
  int wr = (w>>1)*64, wc = (w&1)*64;
  f32x4 acc[4][4];
  #pragma unroll
  for(int i=0;i<4;i++)
    #pragma unroll
    for(int j=0;j<4;j++) acc[i][j] = (f32x4){0.f,0.f,0.f,0.f};
  for(int k0=0; k0<512; k0+=64){
    __syncthreads();
    #pragma unroll
    for(int i=0;i<4;i++){
      int c = t + i*256; int row = c>>3, k8 = c&7;
      int sw = (k8*16) ^ ((row&7)<<4);
      *(s16x8*)((char*)AsH + row*128 + sw) = *(const s16x8*)(Ahp + (size_t)(Rb+row)*512 + k0 + k8*8);
      *(s16x8*)((char*)AsL + row*128 + sw) = *(const s16x8*)(Alp + (size_t)(Rb+row)*512 + k0 + k8*8);
      *(s16x8*)((char*)BsH + row*128 + sw) = *(const s16x8*)(Bhp + (size_t)(cb+row)*512 + k0 + k8*8);
      *(s16x8*)((char*)BsL + row*128 + sw) = *(const s16x8*)(Blp + (size_t)(cb+row)*512 + k0 + k8*8);
    }
    __syncthreads();
    #pragma unroll
    for(int ks=0; ks<2; ks++){
      bf16x8 arh[4], arl[4], brh[4], brl[4];
      #pragma unroll
      for(int rt=0; rt<4; rt++){
        int row = wr + rt*16 + lc;
        int off = row*128 + (((ks*4+g)*16) ^ ((row&7)<<4));
        arh[rt] = *(const bf16x8*)((const char*)AsH + off);
        arl[rt] = *(const bf16x8*)((const char*)AsL + off);
      }
      #pragma unroll
      for(int ct=0; ct<4; ct++){
        int row = wc + ct*16 + lc;
        int off = row*128 + (((ks*4+g)*16) ^ ((row&7)<<4));
        brh[ct] = *(const bf16x8*)((const char*)BsH + off);
        brl[ct] = *(const bf16x8*)((const char*)BsL + off);
      }
      #pragma unroll
      for(int rt=0; rt<4; rt++)
        #pragma unroll
        for(int ct=0; ct<4; ct++){
          acc[rt][ct] = mfma16(arh[rt], brh[ct], acc[rt][ct]);
          acc[rt][ct] = mfma16(arh[rt], brl[ct], acc[rt][ct]);
          acc[rt][ct] = mfma16(arl[rt], brh[ct], acc[rt][ct]);
        }
    }
  }
  #pragma unroll
  for(int rt=0; rt<4; rt++){
    #pragma unroll
    for(int r=0; r<4; r++){
      int R = Rb + wr + rt*16 + g*4 + r;
      #pragma unroll
      for(int ct=0; ct<4; ct++){
        int c = cb + wc + ct*16 + lc;
        Cout[(size_t)R*512 + c] = acc[rt][ct][r] + bias[c];
      }
    }
  }
}

extern "C" void kernel_launch(void* const* d_in, const int* in_sizes, int n_in,
                              void* d_out, int out_size, void* d_ws, size_t ws_size,
                              hipStream_t stream){
  const float* q    = (const float*)d_in[0];
  const float* k    = (const float*)d_in[1];
  const float* v    = (const float*)d_in[2];
  const float* ln1g = (const float*)d_in[3];
  const float* ln1b = (const float*)d_in[4];
  const float* Win  = (const float*)d_in[5];
  const float* w1   = (const float*)d_in[6];
  const float* b1   = (const float*)d_in[7];
  const float* lng  = (const float*)d_in[8];
  const float* lnb  = (const float*)d_in[9];
  const float* w2   = (const float*)d_in[10];
  const float* b2   = (const float*)d_in[11];
  const float* w3   = (const float*)d_in[12];
  const float* b3   = (const float*)d_in[13];
  const float* wtemp= (const float*)d_in[14];
  const float* Wout = (const float*)d_in[15];
  const float* bout = (const float*)d_in[16];

  float* w = (float*)d_ws;
  unsigned short* xnb = (unsigned short*)(w + OFF_XNB);
  unsigned short* fqb = (unsigned short*)(w + OFF_FQB);
  unsigned short* fkb = (unsigned short*)(w + OFF_FKB);
  unsigned short* fvb = (unsigned short*)(w + OFF_FVB);
  unsigned short* fvT = (unsigned short*)(w + OFF_FVT);
  unsigned short* wtb = (unsigned short*)(w + OFF_WT);
  unsigned short* woh = (unsigned short*)(w + OFF_WOH);
  unsigned short* wol = (unsigned short*)(w + OFF_WOL);
  unsigned short* ohh = (unsigned short*)(w + OFF_OHH);
  unsigned short* ohl = (unsigned short*)(w + OFF_OHL);
  float* ri1  = w + OFF_ARR + 0*65536;
  float* mq_  = w + OFF_ARR + 2*65536;
  float* qdm  = w + OFF_ARR + 3*65536;
  float* ri2  = w + OFF_ARR + 4*65536;
  float* sk_  = w + OFF_ARR + 6*65536;
  float* mxc  = w + OFF_ARR + 7*65536;
  float* mxv  = w + OFF_ARR + 8*65536;
  float* mkb  = w + OFF_MKB;
  float* smk_ = w + OFF_SMK;
  float* coef = w + OFF_COEF;
  double* dbl = (double*)(w + OFF_DBL);
  double* headsum = dbl;
  double* featd   = dbl + 72;

  k_pre<<<6272, 256, 0, stream>>>(q, k, v, ln1g, ln1b, Win, Wout, xnb, wtb, woh, wol, dbl);
  k_mm1<<<dim3(192,4), 256, 0, stream>>>(xnb, wtb, fqb, fkb, fvb);
  k_mid<<<640, 512, 0, stream>>>(fqb, fkb, fvb, mkb, smk_, featd, ri1, mq_, qdm, ri2, sk_, fvT);
  k_comp<<<1024, 256, 0, stream>>>(fqb, fkb, ri1, mq_, qdm, ri2, sk_, mxc, mxv, headsum);
  k_finalize<<<1, 1024, 0, stream>>>(headsum, featd, w1, b1, lng, lnb, w2, b2, w3, b3, wtemp, coef);
  k_flash<<<1024, 256, 0, stream>>>(fqb, fkb, fvT, ri1, mq_, qdm, ri2, sk_, mxc, mxv, coef, ohh, ohl);
  k_gout2<<<dim3(64,4), 256, 0, stream>>>(ohh, ohl, woh, wol, bout, (float*)d_out);
}

// Round 10
// 148.655 us; speedup vs baseline: 5.4157x; 1.0712x over previous
//
#include <hip/hip_runtime.h>
#include <math.h>

#define H 8
#define NS 512
#define D 64

typedef __bf16 bf16x8 __attribute__((ext_vector_type(8)));
typedef _Float16 f16x8 __attribute__((ext_vector_type(8)));
typedef float f32x4 __attribute__((ext_vector_type(4)));
typedef short s16x8 __attribute__((ext_vector_type(8)));
typedef short s16x4 __attribute__((ext_vector_type(4)));

#define CS2 ((1e-3f/512.f)/(8.f+1e-6f))
#define LOG2E 1.4426950408889634

static __device__ __forceinline__ f32x4 mfma16(bf16x8 a, bf16x8 b, f32x4 c){
  return __builtin_amdgcn_mfma_f32_16x16x32_bf16(a,b,c,0,0,0);
}
static __device__ __forceinline__ f32x4 mfma16h(f16x8 a, f16x8 b, f32x4 c){
  return __builtin_amdgcn_mfma_f32_16x16x32_f16(a,b,c,0,0,0);
}
static __device__ __forceinline__ float b2f(unsigned short s){
  union { unsigned u; float f; } v; v.u = ((unsigned)s)<<16; return v.f;
}
static __device__ __forceinline__ unsigned short f2b(float f){
  union { float f; unsigned u; } v; v.f = f;
  unsigned r = v.u + 0x7FFFu + ((v.u>>16)&1u);
  return (unsigned short)(r>>16);
}
static __device__ __forceinline__ float wred64(float v){
  #pragma unroll
  for(int m=32; m>0; m>>=1) v += __shfl_xor(v, m, 64);
  return v;
}

// ---- workspace layout (float element offsets) ----
constexpr size_t OFF_XNB = 0;                       // 24576x512 bf16
constexpr size_t OFF_FQB = 6291456;                 // 8192x512 bf16
constexpr size_t OFF_FKB = 8388608;
constexpr size_t OFF_FVB = 10485760;
constexpr size_t OFF_FVT = 12582912;                // [128][64][512] fp16 (m-interleaved per 32-chunk)
constexpr size_t OFF_WT  = 14680064;                // 512x512 bf16 (WinT)
constexpr size_t OFF_WOH = 14811136;                // 512x512 bf16 WoutT hi
constexpr size_t OFF_WOL = 14942208;                // 512x512 bf16 WoutT lo
constexpr size_t OFF_OHH = 15073280;                // 8192x512 bf16 oh hi
constexpr size_t OFF_OHL = 17170432;                // 8192x512 bf16 oh lo
constexpr size_t OFF_ARR = 19267584;                // arrays x 65536 f32
constexpr size_t OFF_MKB = OFF_ARR + 9*65536;       // [128][64]
constexpr size_t OFF_SMK = OFF_MKB + 8192;
constexpr size_t OFF_COEF= OFF_SMK + 128;
constexpr size_t OFF_DBL = OFF_COEF + 32;           // 8B aligned (even)
constexpr size_t NDBL    = 72 + 1024;               // headsum[8][9], featd[8][128]

// ---------------- fused pre: LayerNorm (blocks<6144) + W_in T (64) + W_out T hi/lo (64) ----------------
__global__ __launch_bounds__(256) void k_pre(const float* __restrict__ q,
    const float* __restrict__ k, const float* __restrict__ v,
    const float* __restrict__ g, const float* __restrict__ b,
    const float* __restrict__ Win, const float* __restrict__ Wout,
    unsigned short* __restrict__ xnb, unsigned short* __restrict__ WT,
    unsigned short* __restrict__ WTh, unsigned short* __restrict__ WTl,
    double* __restrict__ dbl){
  int bx = blockIdx.x; int t = threadIdx.x;
  if(bx < 6144){
    int row = bx*4 + (t>>6); int l = t & 63;
    const float* src = (row < 8192) ? q : ((row < 16384) ? k : v);
    int r = row & 8191;
    const float4* sp = (const float4*)(src + (size_t)r*512);
    float4 v1 = sp[l*2], v2 = sp[l*2+1];
    float s  = v1.x+v1.y+v1.z+v1.w + v2.x+v2.y+v2.z+v2.w;
    float ss = v1.x*v1.x+v1.y*v1.y+v1.z*v1.z+v1.w*v1.w
             + v2.x*v2.x+v2.y*v2.y+v2.z*v2.z+v2.w*v2.w;
    s = wred64(s); ss = wred64(ss);
    float mu = s*(1.f/512.f);
    float var = ss*(1.f/512.f) - mu*mu;
    float rstd = rsqrtf(var + 1e-5f);
    const float4* gp = (const float4*)g; const float4* bp = (const float4*)b;
    float4 g1 = gp[l*2], g2 = gp[l*2+1], b1 = bp[l*2], b2 = bp[l*2+1];
    s16x8 o;
    o[0]=(short)f2b((v1.x-mu)*rstd*g1.x+b1.x); o[1]=(short)f2b((v1.y-mu)*rstd*g1.y+b1.y);
    o[2]=(short)f2b((v1.z-mu)*rstd*g1.z+b1.z); o[3]=(short)f2b((v1.w-mu)*rstd*g1.w+b1.w);
    o[4]=(short)f2b((v2.x-mu)*rstd*g2.x+b2.x); o[5]=(short)f2b((v2.y-mu)*rstd*g2.y+b2.y);
    o[6]=(short)f2b((v2.z-mu)*rstd*g2.z+b2.z); o[7]=(short)f2b((v2.w-mu)*rstd*g2.w+b2.w);
    *(s16x8*)(xnb + (size_t)row*512 + l*8) = o;
    return;
  }
  __shared__ float tile[64][65];
  if(bx < 6208){
    int bb = bx - 6144; int kt = bb>>3, nt = bb&7;
    if(bb==0){
      for(int i=t;i<(int)NDBL;i+=256) dbl[i]=0.0;
    }
    #pragma unroll
    for(int i=0;i<4;i++){
      int row = (t>>4) + i*16; int col = (t&15)*4;
      float4 vv = *(const float4*)(Win + (size_t)(kt*64+row)*512 + nt*64 + col);
      tile[row][col]=vv.x; tile[row][col+1]=vv.y; tile[row][col+2]=vv.z; tile[row][col+3]=vv.w;
    }
    __syncthreads();
    #pragma unroll
    for(int i=0;i<4;i++){
      int n = (t>>4) + i*16; int ck = (t&15)*4;
      s16x4 o;
      #pragma unroll
      for(int j=0;j<4;j++) o[j] = (short)f2b(tile[ck+j][n]);
      *(s16x4*)(WT + (size_t)(nt*64+n)*512 + kt*64 + ck) = o;
    }
  } else {
    int bb = bx - 6208; int kt = bb>>3, nt = bb&7;
    #pragma unroll
    for(int i=0;i<4;i++){
      int row = (t>>4) + i*16; int col = (t&15)*4;
      float4 vv = *(const float4*)(Wout + (size_t)(kt*64+row)*512 + nt*64 + col);
      tile[row][col]=vv.x; tile[row][col+1]=vv.y; tile[row][col+2]=vv.z; tile[row][col+3]=vv.w;
    }
    __syncthreads();
    #pragma unroll
    for(int i=0;i<4;i++){
      int n = (t>>4) + i*16; int ck = (t&15)*4;
      s16x4 oh_, ol_;
      #pragma unroll
      for(int j=0;j<4;j++){
        float x = tile[ck+j][n];
        unsigned short hi = f2b(x);
        oh_[j] = (short)hi;
        ol_[j] = (short)f2b(x - b2f(hi));
      }
      *(s16x4*)(WTh + (size_t)(nt*64+n)*512 + kt*64 + ck) = oh_;
      *(s16x4*)(WTl + (size_t)(nt*64+n)*512 + kt*64 + ck) = ol_;
    }
  }
}

// ---------------- proj GEMM bf16 MFMA ----------------
__global__ __launch_bounds__(256) void k_mm1(const unsigned short* __restrict__ xnb,
    const unsigned short* __restrict__ WT,
    unsigned short* __restrict__ fqb, unsigned short* __restrict__ fkb,
    unsigned short* __restrict__ fvb){
  __shared__ __align__(16) unsigned short As[128*64];
  __shared__ __align__(16) unsigned short Bs[128*64];
  int t = threadIdx.x; int w = t>>6; int l = t&63; int g = l>>4, lc = l&15;
  int Rb = blockIdx.x*128, cb = blockIdx.y*128;
  int wr = (w>>1)*64, wc = (w&1)*64;
  f32x4 acc[4][4];
  #pragma unroll
  for(int i=0;i<4;i++)
    #pragma unroll
    for(int j=0;j<4;j++) acc[i][j] = (f32x4){0.f,0.f,0.f,0.f};
  for(int k0=0; k0<512; k0+=64){
    __syncthreads();
    #pragma unroll
    for(int i=0;i<4;i++){
      int c = t + i*256; int row = c>>3, k8 = c&7;
      s16x8 va = *(const s16x8*)(xnb + (size_t)(Rb+row)*512 + k0 + k8*8);
      *(s16x8*)((char*)As + row*128 + ((k8*16) ^ ((row&7)<<4))) = va;
      s16x8 vb = *(const s16x8*)(WT + (size_t)(cb+row)*512 + k0 + k8*8);
      *(s16x8*)((char*)Bs + row*128 + ((k8*16) ^ ((row&7)<<4))) = vb;
    }
    __syncthreads();
    #pragma unroll
    for(int ks=0; ks<2; ks++){
      bf16x8 ar[4], br[4];
      #pragma unroll
      for(int rt=0; rt<4; rt++){
        int row = wr + rt*16 + lc;
        ar[rt] = *(const bf16x8*)((const char*)As + row*128 + (((ks*4+g)*16) ^ ((row&7)<<4)));
      }
      #pragma unroll
      for(int ct=0; ct<4; ct++){
        int row = wc + ct*16 + lc;
        br[ct] = *(const bf16x8*)((const char*)Bs + row*128 + (((ks*4+g)*16) ^ ((row&7)<<4)));
      }
      #pragma unroll
      for(int rt=0; rt<4; rt++)
        #pragma unroll
        for(int ct=0; ct<4; ct++)
          acc[rt][ct] = mfma16(ar[rt], br[ct], acc[rt][ct]);
    }
  }
  #pragma unroll
  for(int rt=0; rt<4; rt++){
    #pragma unroll
    for(int r=0; r<4; r++){
      int R = Rb + wr + rt*16 + g*4 + r;
      int tsel = R>>13; int rr = R&8191;
      unsigned short* dst = (tsel==0)?fqb:((tsel==1)?fkb:fvb);
      #pragma unroll
      for(int ct=0; ct<4; ct++){
        int c = cb + wc + ct*16 + lc;
        dst[(size_t)rr*512 + c] = f2b(acc[rt][ct][r]);
      }
    }
  }
}

// ---------------- fused mid: per-hq stats (blocks<128) + fv transpose->fp16 (512 blocks) ----------------
__global__ __launch_bounds__(512) void k_mid(const unsigned short* __restrict__ fqb,
    const unsigned short* __restrict__ fkb, const unsigned short* __restrict__ fvb,
    float* __restrict__ mkb, float* __restrict__ smk, double* featd,
    float* __restrict__ ri1, float* __restrict__ mq, float* __restrict__ qdm,
    float* __restrict__ ri2, float* __restrict__ sk,
    unsigned short* __restrict__ fvT){
  int bx = blockIdx.x; int t = threadIdx.x;
  if(bx < 128){
    int hq = bx; int h = hq>>4, q = hq&15;
    __shared__ float cq[8][64], ck[8][64], mkS[64];
    __shared__ float smkS;
    {
      int d = t&63; int g = t>>6;  // 8 n-groups
      float aq=0.f, ak=0.f;
      for(int n=g; n<512; n+=8){
        size_t base = (size_t)(q*512+n)*512 + h*64 + d;
        aq += b2f(fqb[base]);
        ak += b2f(fkb[base]);
      }
      cq[g][d]=aq; ck[g][d]=ak;
    }
    __syncthreads();
    if(t<64){
      float sq=0.f, sk2=0.f;
      #pragma unroll
      for(int i=0;i<8;i++){ sq+=cq[i][t]; sk2+=ck[i][t]; }
      atomicAdd(&featd[h*128+t], (double)sq);
      atomicAdd(&featd[h*128+64+t], (double)sk2);
      float mk = sk2*(1.f/512.f);
      mkb[hq*64+t]=mk; mkS[t]=mk;
      float s = wred64(mk);
      if(t==0){ smk[hq]=s; smkS=s; }
    }
    __syncthreads();
    {
      int n = t;
      float smkv = smkS;
      const unsigned short* fr = fqb + (size_t)(q*512+n)*512 + h*64;
      const unsigned short* kr = fkb + (size_t)(q*512+n)*512 + h*64;
      float sq=0.f, ssq=0.f, dq=0.f, sks=0.f, ssk=0.f;
      #pragma unroll
      for(int j=0;j<8;j++){
        s16x8 vq = *(const s16x8*)(fr + j*8);
        s16x8 vk = *(const s16x8*)(kr + j*8);
        #pragma unroll
        for(int e=0;e<8;e++){
          float a = b2f((unsigned short)vq[e]);
          float c = b2f((unsigned short)vk[e]);
          sq += a; ssq += a*a; dq += a*mkS[j*8+e];
          sks += c; ssk += c*c;
        }
      }
      int idx = hq*512 + n;
      float nq = sqrtf(ssq);
      ri1[idx]  = 1.f/(nq+1e-6f);
      mq[idx]   = sq*(1.f/64.f);
      qdm[idx]  = dq;
      float nk = sqrtf(ssk);
      ri2[idx]  = 1.f/(nk+1e-6f);
      sk[idx]   = sks - smkv;
    }
    return;
  }
  // V transpose -> fvT[hq][d][n'] fp16, n' interleaved per 32-chunk: pos p holds n = 16*(p&1)+(p>>1)
  {
    int bb = bx - 128; int hq = bb>>2, nc = bb&3;
    int h = hq>>4, q = hq&15; int n0 = nc*128;
    __shared__ float tile[128][65];
    #pragma unroll
    for(int i=0;i<2;i++){
      int c = t + i*512; int row = c>>3, k8 = c&7;
      s16x8 v = *(const s16x8*)(fvb + (size_t)(q*512 + n0 + row)*512 + h*64 + k8*8);
      #pragma unroll
      for(int j=0;j<8;j++) tile[row][k8*8+j] = b2f((unsigned short)v[j]);
    }
    __syncthreads();
    #pragma unroll
    for(int i=0;i<2;i++){
      int c = t + i*512; int d = c>>4, n8 = c&15;
      s16x8 o;
      #pragma unroll
      for(int j=0;j<8;j++){
        int p = n8*8+j;
        int pl = p & 31;
        int src = (p & ~31) | (16*(pl&1) + (pl>>1));
        union { _Float16 hl; short s; } cv; cv.hl = (_Float16)tile[src][d];
        o[j] = cv.s;
      }
      *(s16x8*)(fvT + (size_t)(hq*64 + d)*512 + n0 + n8*8) = o;
    }
  }
}

// ---------------- component sums pass (MFMA QK), 128 q-rows / 512 threads ----------------
__global__ __launch_bounds__(512) void k_comp(const unsigned short* __restrict__ fqb,
    const unsigned short* __restrict__ fkb,
    const float* __restrict__ ri1,
    const float* __restrict__ mq, const float* __restrict__ qdm,
    const float* __restrict__ ri2,
    const float* __restrict__ skp,
    float* __restrict__ mxcg, float* __restrict__ mxvg, double* headsum){
  int bx = blockIdx.x; int hq = bx>>2; int rt = bx&3;
  int h = hq>>4, q = hq&15; int n0 = rt*128;
  __shared__ __align__(16) unsigned short Qs[128*64];
  __shared__ __align__(16) unsigned short Ks[128*64];
  __shared__ float ri2f[512], skf[512];
  __shared__ float red[8][9];
  int t = threadIdx.x; int w = t>>6; int l = t&63; int g = l>>4, lc = l&15;
  for(int i=t; i<512; i+=512){
    ri2f[i]=ri2[hq*NS+i]; skf[i]=skp[hq*NS+i];
  }
  #pragma unroll
  for(int i=0;i<2;i++){
    int c = t + i*512; int row = c>>3, k8 = c&7;
    s16x8 v = *(const s16x8*)(fqb + (size_t)(q*512 + n0 + row)*512 + h*64 + k8*8);
    *(s16x8*)((char*)Qs + row*128 + ((k8*16) ^ ((row&7)<<4))) = v;
  }
  float ri1r[4], mqr[4], qdmr[4];
  #pragma unroll
  for(int r=0;r<4;r++){
    int n = hq*NS + n0 + w*16 + g*4 + r;
    ri1r[r]=ri1[n]; mqr[r]=mq[n]; qdmr[r]=qdm[n];
  }
  __syncthreads();
  bf16x8 aq[2];
  #pragma unroll
  for(int ks=0;ks<2;ks++){
    int row = 16*w + lc;
    aq[ks] = *(const bf16x8*)((const char*)Qs + row*128 + (((ks*4+g)*16) ^ ((row&7)<<4)));
  }
  float p1=0,p3=0,p4=0;
  float rm_m[4]={0,0,0,0}, rm_c[4]={0,0,0,0}, rm_v[4]={0,0,0,0};
  float mxc[4]={-1e30f,-1e30f,-1e30f,-1e30f}, mxv[4]={-1e30f,-1e30f,-1e30f,-1e30f};
  for(int mc=0; mc<4; mc++){
    __syncthreads();
    #pragma unroll
    for(int i=0;i<2;i++){
      int c = t + i*512; int row = c>>3, k8 = c&7;
      s16x8 v = *(const s16x8*)(fkb + (size_t)(q*512 + mc*128 + row)*512 + h*64 + k8*8);
      *(s16x8*)((char*)Ks + row*128 + ((k8*16) ^ ((row&7)<<4))) = v;
    }
    __syncthreads();
    #pragma unroll 2
    for(int mt=0; mt<8; mt++){
      f32x4 dacc = (f32x4){0.f,0.f,0.f,0.f};
      #pragma unroll
      for(int ks=0;ks<2;ks++){
        int row = mt*16 + lc;
        bf16x8 bk = *(const bf16x8*)((const char*)Ks + row*128 + (((ks*4+g)*16) ^ ((row&7)<<4)));
        dacc = mfma16(aq[ks], bk, dacc);
      }
      int m = mc*128 + mt*16 + lc;
      float r2 = ri2f[m], sc = skf[m];
      #pragma unroll
      for(int r=0;r<4;r++){
        float dv = dacc[r];
        float cosv = fminf(fmaxf(dv*ri1r[r]*r2, -0.9f), 0.9f);
        float inner = (dv - qdmr[r]) - mqr[r]*sc;
        float marg = fmaxf(0.01f - cosv, 0.f);
        p1 += cosv*cosv; p3 += inner*inner; p4 += cosv*inner;
        rm_m[r]+=marg; rm_c[r]+=cosv; rm_v[r]+=inner;
        mxc[r]=fmaxf(mxc[r],cosv); mxv[r]=fmaxf(mxv[r],inner);
      }
    }
  }
  float p0 = rm_c[0]+rm_c[1]+rm_c[2]+rm_c[3];
  float p2 = rm_v[0]+rm_v[1]+rm_v[2]+rm_v[3];
  #pragma unroll
  for(int off=1; off<16; off<<=1){
    #pragma unroll
    for(int r=0;r<4;r++){
      rm_m[r]+=__shfl_xor(rm_m[r],off,64);
      rm_c[r]+=__shfl_xor(rm_c[r],off,64);
      rm_v[r]+=__shfl_xor(rm_v[r],off,64);
      mxc[r]=fmaxf(mxc[r],__shfl_xor(mxc[r],off,64));
      mxv[r]=fmaxf(mxv[r],__shfl_xor(mxv[r],off,64));
    }
  }
  float q0=0,q1=0,q2=0,q3=0;
  if(lc==0){
    #pragma unroll
    for(int r=0;r<4;r++){
      float vmv = rm_m[r]*(1.f/512.f);
      q0+=vmv; q1+=vmv*vmv; q2+=vmv*rm_c[r]; q3+=vmv*rm_v[r];
      int n = n0 + w*16 + g*4 + r;
      mxcg[hq*NS+n]=mxc[r]; mxvg[hq*NS+n]=mxv[r];
    }
  }
  float all9[9] = {p0,p1,p2,p3,p4,q0,q1,q2,q3};
  #pragma unroll
  for(int j=0;j<9;j++){
    float vv = wred64(all9[j]);
    if(l==0) red[w][j]=vv;
  }
  __syncthreads();
  if(t<9){
    double s = 0.0;
    #pragma unroll
    for(int i=0;i<8;i++) s += (double)red[i][t];
    atomicAdd(&headsum[h*9+t], s);
  }
}

// ---------------- finalize (inner-scaled sums; coef includes /temp and log2e) ----------------
__global__ __launch_bounds__(1024) void k_finalize(const double* headsum, const double* featd,
    const float* __restrict__ w1, const float* __restrict__ b1,
    const float* __restrict__ lng, const float* __restrict__ lnb,
    const float* __restrict__ w2, const float* __restrict__ b2,
    const float* __restrict__ w3, const float* __restrict__ b3,
    const float* __restrict__ wtemp, float* coef){
  __shared__ float featS[8][128];
  __shared__ float x1S[8][128];
  __shared__ float x2S[8][64];
  __shared__ float redS[8][4];
  __shared__ float oS[8][3];
  __shared__ float whS[8][3];
  int t = threadIdx.x;
  int h = t>>7, j = t&127;
  featS[h][j] = (float)(featd[t] * (1.0/8192.0));
  __syncthreads();
  float a = 0.f;
  #pragma unroll 16
  for(int i=0;i<128;i++) a += featS[h][i]*w1[(size_t)i*128+j];
  a += b1[j];
  {
    float s = a, ss = a*a;
    #pragma unroll
    for(int m=32;m>0;m>>=1){ s += __shfl_xor(s,m,64); ss += __shfl_xor(ss,m,64); }
    int wv = (t>>6)&1;
    if((t&63)==0){ redS[h][wv*2]=s; redS[h][wv*2+1]=ss; }
  }
  __syncthreads();
  {
    float sum = redS[h][0]+redS[h][2], sumsq = redS[h][1]+redS[h][3];
    float mu = sum*(1.f/128.f);
    float var = sumsq*(1.f/128.f)-mu*mu;
    float rstd = rsqrtf(var+1e-5f);
    x1S[h][j] = fmaxf((a-mu)*rstd*lng[j]+lnb[j], 0.f);
  }
  __syncthreads();
  if(t < 512){
    int h2 = t>>6, j2 = t&63;
    float s2 = 0.f;
    #pragma unroll 16
    for(int i=0;i<128;i++) s2 += x1S[h2][i]*w2[(size_t)i*64+j2];
    x2S[h2][j2] = fmaxf(s2+b2[j2], 0.f);
  }
  __syncthreads();
  if(t < 24){
    int h3 = t/3, j3 = t-h3*3;
    float s3=0.f;
    #pragma unroll 16
    for(int i=0;i<64;i++) s3 += x2S[h3][i]*w3[i*3+j3];
    oS[h3][j3] = s3 + b3[j3];
  }
  __syncthreads();
  if(t < 8){
    float o0=oS[t][0], o1=oS[t][1], o2=oS[t][2];
    float mx=fmaxf(o0,fmaxf(o1,o2));
    float e0=expf(o0-mx), e1=expf(o1-mx), e2=expf(o2-mx), se=e0+e1+e2;
    float l0=e0/se, l1=e1/se, l2=e2/se;
    float wt=fminf(fmaxf(wtemp[0],0.1f),2.0f);
    l0/=wt; l1/=wt; l2/=wt;
    mx=fmaxf(l0,fmaxf(l1,l2));
    e0=expf(l0-mx); e1=expf(l1-mx); e2=expf(l2-mx); se=e0+e1+e2;
    float u0=fminf(fmaxf(e0/se,0.05f),0.8f);
    float u1=fminf(fmaxf(e1/se,0.05f),0.8f);
    float u2=fminf(fmaxf(e2/se,0.05f),0.8f);
    float su=u0+u1+u2;
    whS[t][0]=u0/su; whS[t][1]=u1/su; whS[t][2]=u2/su;
  }
  __syncthreads();
  if(t==0){
    const double N = 33554432.0;
    const double CS2d = (double)CS2;
    double gs[9];
    for(int jj=0;jj<9;jj++){ double s=0; for(int hh=0;hh<8;hh++) s+=headsum[hh*9+jj]; gs[jj]=s; }
    auto sd = [&](double s, double ss)->double{
      double v=(ss - s*s/N)/(N-1.0); return v>0.0 ? sqrt(v) : 0.0;
    };
    double std_cos = sd(gs[0],gs[1]);
    double std_cov = sd(CS2d*gs[2], CS2d*CS2d*gs[3]);
    double std_vm  = sd(512.0*gs[5], 512.0*gs[6]);
    double sdot=0.0, sdot2=0.0;
    double Af[8], Bf[8];
    for(int hh=0;hh<8;hh++){
      const double* hs = headsum + hh*9;
      double A = (double)whS[hh][0]/(std_cos+1e-6);
      double Bi = (double)whS[hh][1]/(std_cov+1e-6)*0.5*CS2d;
      double C = (double)whS[hh][2]/(std_vm +1e-6)*0.5;
      sdot  += A*hs[0] + Bi*hs[2] + C*512.0*hs[5];
      sdot2 += A*A*hs[1] + Bi*Bi*hs[3] + C*C*512.0*hs[6]
             + 2.0*A*Bi*hs[4] + 2.0*A*C*hs[7] + 2.0*Bi*C*hs[8];
      Af[hh]=A; Bf[hh]=Bi;
    }
    double dstd = sd(sdot, sdot2);
    double temp = dstd < 1e-4 ? 0.1 : (dstd < 0.01 ? 0.3 : 0.5 + dstd);
    temp = fmin(fmax(temp, 0.1), 3.0);
    for(int hh=0;hh<8;hh++){
      coef[hh]   = (float)(Af[hh]/temp*LOG2E);
      coef[8+hh] = (float)(Bf[hh]/temp*LOG2E);
    }
    coef[16] = (float)temp;
  }
}

// ---------------- flash softmax + PV (fp16 P/V), 128 q-rows / 512 threads ----------------
__global__ __launch_bounds__(512) void k_flash(const unsigned short* __restrict__ fqb,
    const unsigned short* __restrict__ fkb, const unsigned short* __restrict__ fvT,
    const float* __restrict__ ri1, const float* __restrict__ mq,
    const float* __restrict__ qdm, const float* __restrict__ ri2,
    const float* __restrict__ skp,
    const float* __restrict__ mxcg, const float* __restrict__ mxvg,
    const float* __restrict__ coef,
    unsigned short* __restrict__ ohh, unsigned short* __restrict__ ohl){
  int bx = blockIdx.x; int hq = bx>>2; int rt = bx&3;
  int h = hq>>4, q = hq&15; int n0 = rt*128;
  __shared__ __align__(16) unsigned short Qs[128*64];  // reused as P after aq extraction (8 waves x 640 shorts)
  __shared__ __align__(16) unsigned short Ks[128*64];
  __shared__ __align__(16) unsigned short Vt[64*128];
  __shared__ float ri2f[512], skf[512];
  int t = threadIdx.x; int w = t>>6; int l = t&63; int g = l>>4, lc = l&15;
  for(int i=t; i<512; i+=512){ ri2f[i]=ri2[hq*NS+i]; skf[i]=skp[hq*NS+i]; }
  #pragma unroll
  for(int i=0;i<2;i++){
    int c = t + i*512; int row = c>>3, k8 = c&7;
    s16x8 v = *(const s16x8*)(fqb + (size_t)(q*512 + n0 + row)*512 + h*64 + k8*8);
    *(s16x8*)((char*)Qs + row*128 + ((k8*16) ^ ((row&7)<<4))) = v;
  }
  float Ah = coef[h], Bh = coef[8+h];
  float loA = -0.9f*Ah, hiA = 0.9f*Ah;
  float ri1A[4], R1[4], R2[4];
  #pragma unroll
  for(int r=0;r<4;r++){
    int n = hq*NS + n0 + w*16 + g*4 + r;
    float Mr = Ah*mxcg[n] + Bh*mxvg[n];
    ri1A[r] = ri1[n]*Ah;
    R1[r] = fmaf(Bh, qdm[n], Mr);
    R2[r] = Bh*mq[n];
  }
  __syncthreads();
  bf16x8 aq[2];
  #pragma unroll
  for(int ks=0;ks<2;ks++){
    int row = 16*w + lc;
    aq[ks] = *(const bf16x8*)((const char*)Qs + row*128 + (((ks*4+g)*16) ^ ((row&7)<<4)));
  }
  f32x4 acc[4];
  #pragma unroll
  for(int dt=0;dt<4;dt++) acc[dt] = (f32x4){0.f,0.f,0.f,0.f};
  float lsum[4]={0.f,0.f,0.f,0.f};
  unsigned short* Pw = Qs + w*640;        // 16 rows x 40 shorts per wave
  unsigned* Pu = (unsigned*)Pw;
  for(int mc=0; mc<4; mc++){
    __syncthreads();
    #pragma unroll
    for(int i=0;i<2;i++){
      int c = t + i*512; int row = c>>3, k8 = c&7;
      s16x8 v = *(const s16x8*)(fkb + (size_t)(q*512 + mc*128 + row)*512 + h*64 + k8*8);
      *(s16x8*)((char*)Ks + row*128 + ((k8*16) ^ ((row&7)<<4))) = v;
    }
    #pragma unroll
    for(int i=0;i<2;i++){
      int c = t + i*512; int d = c>>4, m8 = c&15;
      s16x8 v = *(const s16x8*)(fvT + (size_t)(hq*64 + d)*512 + mc*128 + m8*8);
      *(s16x8*)((char*)Vt + d*256 + ((m8*16) ^ ((d&7)<<4))) = v;
    }
    __syncthreads();
    #pragma unroll 1
    for(int mt2=0; mt2<4; mt2++){
      f32x4 d0 = (f32x4){0.f,0.f,0.f,0.f};
      f32x4 d1 = (f32x4){0.f,0.f,0.f,0.f};
      #pragma unroll
      for(int ks=0;ks<2;ks++){
        int row0 = (mt2*2)*16 + lc;
        bf16x8 bk0 = *(const bf16x8*)((const char*)Ks + row0*128 + (((ks*4+g)*16) ^ ((row0&7)<<4)));
        d0 = mfma16(aq[ks], bk0, d0);
        int row1 = (mt2*2+1)*16 + lc;
        bf16x8 bk1 = *(const bf16x8*)((const char*)Ks + row1*128 + (((ks*4+g)*16) ^ ((row1&7)<<4)));
        d1 = mfma16(aq[ks], bk1, d1);
      }
      int m0 = mc*128 + mt2*32 + lc;
      float r20 = ri2f[m0],    sc0 = skf[m0];
      float r21 = ri2f[m0+16], sc1 = skf[m0+16];
      #pragma unroll
      for(int r=0;r<4;r++){
        float dv0 = d0[r], dv1 = d1[r];
        float cl0 = fminf(fmaxf(dv0*ri1A[r]*r20, loA), hiA);
        float cl1 = fminf(fmaxf(dv1*ri1A[r]*r21, loA), hiA);
        float e0 = fmaf(-R2[r], sc0, fmaf(Bh, dv0, -R1[r]));
        float e1 = fmaf(-R2[r], sc1, fmaf(Bh, dv1, -R1[r]));
        float pe0 = __builtin_amdgcn_exp2f(cl0 + e0);
        float pe1 = __builtin_amdgcn_exp2f(cl1 + e1);
        lsum[r] += pe0 + pe1;
        auto ph = __builtin_amdgcn_cvt_pkrtz(pe0, pe1);
        unsigned pk; __builtin_memcpy(&pk, &ph, 4);
        Pu[(g*4+r)*20 + lc] = pk;
      }
      asm volatile("s_waitcnt lgkmcnt(0)" ::: "memory");
      f16x8 ap = *(const f16x8*)((const char*)Pw + lc*80 + g*16);
      #pragma unroll
      for(int dt=0;dt<4;dt++){
        int drow = dt*16 + lc;
        f16x8 bv = *(const f16x8*)((const char*)Vt + drow*256 + (((mt2*4+g)*16) ^ ((drow&7)<<4)));
        acc[dt] = mfma16h(ap, bv, acc[dt]);
      }
    }
  }
  #pragma unroll
  for(int off=1; off<16; off<<=1){
    #pragma unroll
    for(int r=0;r<4;r++) lsum[r] += __shfl_xor(lsum[r], off, 64);
  }
  #pragma unroll
  for(int r=0;r<4;r++){
    float inv = 1.f/lsum[r];
    int n = n0 + w*16 + g*4 + r;
    #pragma unroll
    for(int dt=0;dt<4;dt++){
      size_t idx = (size_t)(q*512 + n)*512 + h*64 + dt*16 + lc;
      float val = acc[dt][r]*inv;
      unsigned short hi = f2b(val);
      ohh[idx] = hi;
      ohl[idx] = f2b(val - b2f(hi));
    }
  }
}

// ---------------- output GEMM: split-bf16 3-term MFMA + bias ----------------
__global__ __launch_bounds__(256) void k_gout2(const unsigned short* __restrict__ Ahp,
    const unsigned short* __restrict__ Alp,
    const unsigned short* __restrict__ Bhp, const unsigned short* __restrict__ Blp,
    const float* __restrict__ bias, float* __restrict__ Cout){
  __shared__ __align__(16) unsigned short AsH[128*64];
  __shared__ __align__(16) unsigned short AsL[128*64];
  __shared__ __align__(16) unsigned short BsH[128*64];
  __shared__ __align__(16) unsigned short BsL[128*64];
  int t = threadIdx.x; int w = t>>6; int l = t&63; int g = l>>4, lc = l&15;
  int Rb = blockIdx.x*128, cb = blockIdx.y*128;
  int wr = (w>>1)*64, wc = (w&1)*64;
  f32x4 acc[4][4];
  #pragma unroll
  for(int i=0;i<4;i++)
    #pragma unroll
    for(int j=0;j<4;j++) acc[i][j] = (f32x4){0.f,0.f,0.f,0.f};
  for(int k0=0; k0<512; k0+=64){
    __syncthreads();
    #pragma unroll
    for(int i=0;i<4;i++){
      int c = t + i*256; int row = c>>3, k8 = c&7;
      int sw = (k8*16) ^ ((row&7)<<4);
      *(s16x8*)((char*)AsH + row*128 + sw) = *(const s16x8*)(Ahp + (size_t)(Rb+row)*512 + k0 + k8*8);
      *(s16x8*)((char*)AsL + row*128 + sw) = *(const s16x8*)(Alp + (size_t)(Rb+row)*512 + k0 + k8*8);
      *(s16x8*)((char*)BsH + row*128 + sw) = *(const s16x8*)(Bhp + (size_t)(cb+row)*512 + k0 + k8*8);
      *(s16x8*)((char*)BsL + row*128 + sw) = *(const s16x8*)(Blp + (size_t)(cb+row)*512 + k0 + k8*8);
    }
    __syncthreads();
    #pragma unroll
    for(int ks=0; ks<2; ks++){
      bf16x8 arh[4], arl[4], brh[4], brl[4];
      #pragma unroll
      for(int rt=0; rt<4; rt++){
        int row = wr + rt*16 + lc;
        int off = row*128 + (((ks*4+g)*16) ^ ((row&7)<<4));
        arh[rt] = *(const bf16x8*)((const char*)AsH + off);
        arl[rt] = *(const bf16x8*)((const char*)AsL + off);
      }
      #pragma unroll
      for(int ct=0; ct<4; ct++){
        int row = wc + ct*16 + lc;
        int off = row*128 + (((ks*4+g)*16) ^ ((row&7)<<4));
        brh[ct] = *(const bf16x8*)((const char*)BsH + off);
        brl[ct] = *(const bf16x8*)((const char*)BsL + off);
      }
      #pragma unroll
      for(int rt=0; rt<4; rt++)
        #pragma unroll
        for(int ct=0; ct<4; ct++){
          acc[rt][ct] = mfma16(arh[rt], brh[ct], acc[rt][ct]);
          acc[rt][ct] = mfma16(arh[rt], brl[ct], acc[rt][ct]);
          acc[rt][ct] = mfma16(arl[rt], brh[ct], acc[rt][ct]);
        }
    }
  }
  #pragma unroll
  for(int rt=0; rt<4; rt++){
    #pragma unroll
    for(int r=0; r<4; r++){
      int R = Rb + wr + rt*16 + g*4 + r;
      #pragma unroll
      for(int ct=0; ct<4; ct++){
        int c = cb + wc + ct*16 + lc;
        Cout[(size_t)R*512 + c] = acc[rt][ct][r] + bias[c];
      }
    }
  }
}

extern "C" void kernel_launch(void* const* d_in, const int* in_sizes, int n_in,
                              void* d_out, int out_size, void* d_ws, size_t ws_size,
                              hipStream_t stream){
  const float* q    = (const float*)d_in[0];
  const float* k    = (const float*)d_in[1];
  const float* v    = (const float*)d_in[2];
  const float* ln1g = (const float*)d_in[3];
  const float* ln1b = (const float*)d_in[4];
  const float* Win  = (const float*)d_in[5];
  const float* w1   = (const float*)d_in[6];
  const float* b1   = (const float*)d_in[7];
  const float* lng  = (const float*)d_in[8];
  const float* lnb  = (const float*)d_in[9];
  const float* w2   = (const float*)d_in[10];
  const float* b2   = (const float*)d_in[11];
  const float* w3   = (const float*)d_in[12];
  const float* b3   = (const float*)d_in[13];
  const float* wtemp= (const float*)d_in[14];
  const float* Wout = (const float*)d_in[15];
  const float* bout = (const float*)d_in[16];

  float* w = (float*)d_ws;
  unsigned short* xnb = (unsigned short*)(w + OFF_XNB);
  unsigned short* fqb = (unsigned short*)(w + OFF_FQB);
  unsigned short* fkb = (unsigned short*)(w + OFF_FKB);
  unsigned short* fvb = (unsigned short*)(w + OFF_FVB);
  unsigned short* fvT = (unsigned short*)(w + OFF_FVT);
  unsigned short* wtb = (unsigned short*)(w + OFF_WT);
  unsigned short* woh = (unsigned short*)(w + OFF_WOH);
  unsigned short* wol = (unsigned short*)(w + OFF_WOL);
  unsigned short* ohh = (unsigned short*)(w + OFF_OHH);
  unsigned short* ohl = (unsigned short*)(w + OFF_OHL);
  float* ri1  = w + OFF_ARR + 0*65536;
  float* mq_  = w + OFF_ARR + 2*65536;
  float* qdm  = w + OFF_ARR + 3*65536;
  float* ri2  = w + OFF_ARR + 4*65536;
  float* sk_  = w + OFF_ARR + 6*65536;
  float* mxc  = w + OFF_ARR + 7*65536;
  float* mxv  = w + OFF_ARR + 8*65536;
  float* mkb  = w + OFF_MKB;
  float* smk_ = w + OFF_SMK;
  float* coef = w + OFF_COEF;
  double* dbl = (double*)(w + OFF_DBL);
  double* headsum = dbl;
  double* featd   = dbl + 72;

  k_pre<<<6272, 256, 0, stream>>>(q, k, v, ln1g, ln1b, Win, Wout, xnb, wtb, woh, wol, dbl);
  k_mm1<<<dim3(192,4), 256, 0, stream>>>(xnb, wtb, fqb, fkb, fvb);
  k_mid<<<640, 512, 0, stream>>>(fqb, fkb, fvb, mkb, smk_, featd, ri1, mq_, qdm, ri2, sk_, fvT);
  k_comp<<<512, 512, 0, stream>>>(fqb, fkb, ri1, mq_, qdm, ri2, sk_, mxc, mxv, headsum);
  k_finalize<<<1, 1024, 0, stream>>>(headsum, featd, w1, b1, lng, lnb, w2, b2, w3, b3, wtemp, coef);
  k_flash<<<512, 512, 0, stream>>>(fqb, fkb, fvT, ri1, mq_, qdm, ri2, sk_, mxc, mxv, coef, ohh, ohl);
  k_gout2<<<dim3(64,4), 256, 0, stream>>>(ohh, ohl, woh, wol, bout, (float*)d_out);
}